// Round 3
// baseline (4078.296 us; speedup 1.0000x reference)
//
#include <hip/hip_runtime.h>
#include <math.h>

#define EPS_F 1e-6f
#define ONE_M_EPS (1.0f - 1e-6f)

// ---------------------------------------------------------------------------
// Tiled fp32 GEMM:  C[M,N] = act(A[M,K] @ W[K,N] + bias[N])
// threads = 256 (tx = N dir 16, ty = M dir 16)
// ---------------------------------------------------------------------------
template<int BM, int BN, int BK, int TM, int TN, bool RELU>
__global__ __launch_bounds__(256) void gemm_bias(
    const float* __restrict__ A, const float* __restrict__ W,
    const float* __restrict__ bias, float* __restrict__ C,
    int M, int N, int K)
{
    constexpr int APAD = (BM == 128) ? 132 : 68;  // padded LDS stride (16B aligned)
    __shared__ float As[BK][APAD];
    __shared__ float Bs[BK][BN];

    const int tid = threadIdx.x;
    const int tx = tid & 15;
    const int ty = tid >> 4;
    const int bm = blockIdx.x * BM;
    const int bn = blockIdx.y * BN;

    constexpr int NG = TN / 4;          // number of 4-wide column groups per thread
    constexpr int GSTRIDE = BN / NG;    // spacing between groups

    float acc[TM][TN];
#pragma unroll
    for (int i = 0; i < TM; i++)
#pragma unroll
        for (int j = 0; j < TN; j++) acc[i][j] = 0.f;

    constexpr int A_F4 = BM * BK / 4 / 256;
    constexpr int B_F4 = BK * BN / 4 / 256;

    for (int k0 = 0; k0 < K; k0 += BK) {
        // ---- stage A tile (transposed into LDS) ----
#pragma unroll
        for (int p = 0; p < A_F4; p++) {
            int fi = tid + p * 256;
            int row = fi / (BK / 4);
            int kc = (fi % (BK / 4)) * 4;
            float4 v = *reinterpret_cast<const float4*>(
                &A[(size_t)(bm + row) * K + k0 + kc]);
            As[kc + 0][row] = v.x;
            As[kc + 1][row] = v.y;
            As[kc + 2][row] = v.z;
            As[kc + 3][row] = v.w;
        }
        // ---- stage B tile ----
#pragma unroll
        for (int p = 0; p < B_F4; p++) {
            int fi = tid + p * 256;
            int row = fi / (BN / 4);
            int c = (fi % (BN / 4)) * 4;
            float4 v = *reinterpret_cast<const float4*>(
                &W[(size_t)(k0 + row) * N + bn + c]);
            *reinterpret_cast<float4*>(&Bs[row][c]) = v;
        }
        __syncthreads();

#pragma unroll
        for (int kk = 0; kk < BK; kk++) {
            float a[TM];
#pragma unroll
            for (int i = 0; i < TM; i += 4) {
                float4 v = *reinterpret_cast<const float4*>(&As[kk][ty * TM + i]);
                a[i] = v.x; a[i + 1] = v.y; a[i + 2] = v.z; a[i + 3] = v.w;
            }
            float b[TN];
#pragma unroll
            for (int g = 0; g < NG; g++) {
                float4 v = *reinterpret_cast<const float4*>(&Bs[kk][g * GSTRIDE + tx * 4]);
                b[g * 4] = v.x; b[g * 4 + 1] = v.y; b[g * 4 + 2] = v.z; b[g * 4 + 3] = v.w;
            }
#pragma unroll
            for (int i = 0; i < TM; i++)
#pragma unroll
                for (int j = 0; j < TN; j++)
                    acc[i][j] += a[i] * b[j];
        }
        __syncthreads();
    }

    // ---- epilogue: bias + activation + store ----
#pragma unroll
    for (int g = 0; g < NG; g++) {
        int cn = bn + g * GSTRIDE + tx * 4;
        float4 bv = *reinterpret_cast<const float4*>(&bias[cn]);
#pragma unroll
        for (int i = 0; i < TM; i++) {
            int rm = bm + ty * TM + i;
            float4 o;
            o.x = acc[i][g * 4 + 0] + bv.x;
            o.y = acc[i][g * 4 + 1] + bv.y;
            o.z = acc[i][g * 4 + 2] + bv.z;
            o.w = acc[i][g * 4 + 3] + bv.w;
            if (RELU) {
                o.x = fmaxf(o.x, 0.f); o.y = fmaxf(o.y, 0.f);
                o.z = fmaxf(o.z, 0.f); o.w = fmaxf(o.w, 0.f);
            }
            *reinterpret_cast<float4*>(&C[(size_t)rm * N + cn]) = o;
        }
    }
}

// ---------------------------------------------------------------------------
// Codebook prep: transpose to cbT[l][d][c] and compute cnorm[l][c] = ||c||^2
// grid = 1024 blocks (l*256+c), 128 threads (d)
// ---------------------------------------------------------------------------
__global__ __launch_bounds__(128) void prep_cb_kernel(
    const float* __restrict__ cb, float* __restrict__ cbT, float* __restrict__ cnorm)
{
    int b = blockIdx.x;          // l*256 + c
    int d = threadIdx.x;         // 0..127
    float v = cb[(size_t)b * 128 + d];
    int l = b >> 8, c = b & 255;
    cbT[((size_t)l * 128 + d) * 256 + c] = v;
    float s = v * v;
#pragma unroll
    for (int off = 32; off > 0; off >>= 1) s += __shfl_down(s, off);
    __shared__ float ps[2];
    if ((d & 63) == 0) ps[d >> 6] = s;
    __syncthreads();
    if (d == 0) cnorm[b] = ps[0] + ps[1];
}

// ---------------------------------------------------------------------------
// Kuma params + zero loss accumulators
// ---------------------------------------------------------------------------
__device__ __forceinline__ float softplusf(float x) {
    return (x > 20.f) ? x : log1pf(expf(x));
}

__global__ void kuma_ab_init(const float* __restrict__ a_raw, const float* __restrict__ b_raw,
                             float* __restrict__ kp, float* __restrict__ sums)
{
    int t = threadIdx.x;
    if (t < 128) {
        float a = softplusf(a_raw[t]) + EPS_F;
        float b = softplusf(b_raw[t]) + EPS_F;
        kp[t] = a;
        kp[128 + t] = b;
        kp[256 + t] = 1.f / a;
        kp[384 + t] = 1.f / b;
    }
    if (t < 8) sums[t] = 0.f;
}

// ---------------------------------------------------------------------------
// kuma_h elementwise: z -> z_prime
// ---------------------------------------------------------------------------
__global__ __launch_bounds__(256) void kuma_h_kernel(
    const float* __restrict__ z, const float* __restrict__ kp,
    float* __restrict__ zp, int n)
{
    int i = blockIdx.x * 256 + threadIdx.x;
    if (i >= n) return;
    int col = i & 127;
    float a = kp[col], b = kp[128 + col];
    float zv = z[i];
    float x = 1.f / (1.f + expf(-zv));
    x = fminf(fmaxf(x, EPS_F), ONE_M_EPS);
    float inner = 1.f - powf(x, a);
    inner = fminf(fmaxf(inner, EPS_F), 1.f);
    float y = 1.f - powf(inner, b);
    y = fminf(fmaxf(y, EPS_F), ONE_M_EPS);
    zp[i] = y;
}

// ---------------------------------------------------------------------------
// Fused residual quantizer.
// 8 rows per block, 256 threads (thread t owns code t).
// Writes x_q, indices (as float), and per-level squared-error sums (atomic).
// ---------------------------------------------------------------------------
#define RQ_ROWS 8
__global__ __launch_bounds__(256) void rq_kernel(
    const float* __restrict__ zp, const float* __restrict__ cb,
    const float* __restrict__ cbT, const float* __restrict__ cnorm,
    float* __restrict__ xq, float* __restrict__ idx_out, float* __restrict__ sums)
{
    __shared__ float res[RQ_ROWS][128];
    __shared__ float rd[4][RQ_ROWS];
    __shared__ int   ri[4][RQ_ROWS];
    __shared__ int   bidx[RQ_ROWS];

    const int t = threadIdx.x;
    const int lane = t & 63;
    const int wv = t >> 6;
    const int row0 = blockIdx.x * RQ_ROWS;

#pragma unroll
    for (int j = 0; j < RQ_ROWS * 128 / 256; j++) {
        int e = t + j * 256;
        res[e >> 7][e & 127] = zp[(size_t)row0 * 128 + e];
    }
    __syncthreads();

    float lsum[4] = {0.f, 0.f, 0.f, 0.f};

#pragma unroll 1
    for (int l = 0; l < 4; l++) {
        const float* cT = cbT + (size_t)l * 128 * 256;
        float acc[RQ_ROWS];
#pragma unroll
        for (int r = 0; r < RQ_ROWS; r++) acc[r] = 0.f;

        for (int d = 0; d < 128; d += 4) {
            float c0 = cT[(d + 0) * 256 + t];
            float c1 = cT[(d + 1) * 256 + t];
            float c2 = cT[(d + 2) * 256 + t];
            float c3 = cT[(d + 3) * 256 + t];
#pragma unroll
            for (int r = 0; r < RQ_ROWS; r++) {
                float4 rv = *reinterpret_cast<const float4*>(&res[r][d]);
                acc[r] += rv.x * c0 + rv.y * c1 + rv.z * c2 + rv.w * c3;
            }
        }
        float cn = cnorm[l * 256 + t];

        // per-row argmin over 256 codes; tie-break lowest index (jnp.argmin)
#pragma unroll
        for (int r = 0; r < RQ_ROWS; r++) {
            float dmin = cn - 2.f * acc[r];
            int imin = t;
#pragma unroll
            for (int off = 32; off > 0; off >>= 1) {
                float d2 = __shfl_down(dmin, off);
                int i2 = __shfl_down(imin, off);
                if (d2 < dmin || (d2 == dmin && i2 < imin)) { dmin = d2; imin = i2; }
            }
            if (lane == 0) { rd[wv][r] = dmin; ri[wv][r] = imin; }
        }
        __syncthreads();
        if (t < RQ_ROWS) {
            float dm = rd[0][t]; int im = ri[0][t];
#pragma unroll
            for (int w = 1; w < 4; w++) {
                float d2 = rd[w][t]; int i2 = ri[w][t];
                if (d2 < dm || (d2 == dm && i2 < im)) { dm = d2; im = i2; }
            }
            bidx[t] = im;
            idx_out[(size_t)(row0 + t) * 4 + l] = (float)im;
        }
        __syncthreads();

        // residual update + loss sum: (q - r_pre)^2 == (r_post)^2 exactly
        float s = 0.f;
#pragma unroll
        for (int j = 0; j < RQ_ROWS * 128 / 256; j++) {
            int e = t + j * 256; int r = e >> 7; int d = e & 127;
            float q = cb[((size_t)l * 256 + bidx[r]) * 128 + d];
            float nr = res[r][d] - q;
            res[r][d] = nr;
            s += nr * nr;
        }
        lsum[l] = s;
        __syncthreads();
    }

    // x_q = z' - final residual
#pragma unroll
    for (int j = 0; j < RQ_ROWS * 128 / 256; j++) {
        int e = t + j * 256;
        xq[(size_t)row0 * 128 + e] = zp[(size_t)row0 * 128 + e] - res[e >> 7][e & 127];
    }

    // reduce per-level loss sums
#pragma unroll
    for (int l = 0; l < 4; l++) {
        float s = lsum[l];
#pragma unroll
        for (int off = 32; off > 0; off >>= 1) s += __shfl_down(s, off);
        if (lane == 0) atomicAdd(&sums[l], s);
    }
}

// ---------------------------------------------------------------------------
// z_q = h_inv(x_q) (in-place capable);  z_recon = h_inv(z_prime);  nvq sum
// ---------------------------------------------------------------------------
__device__ __forceinline__ float kuma_h_inv_f(float y, float ia, float ib) {
    y = fminf(fmaxf(y, EPS_F), ONE_M_EPS);
    float omy = fminf(fmaxf(1.f - y, EPS_F), 1.f);
    float inner = fminf(fmaxf(1.f - powf(omy, ib), EPS_F), ONE_M_EPS);
    float x = fminf(fmaxf(powf(inner, ia), EPS_F), ONE_M_EPS);
    return logf(x / (1.f - x));
}

__global__ __launch_bounds__(256) void zq_nvq_kernel(
    const float* __restrict__ xq, const float* __restrict__ zp,
    const float* __restrict__ z, const float* __restrict__ kp,
    float* __restrict__ zq, float* __restrict__ sums, int n)
{
    int i = blockIdx.x * 256 + threadIdx.x;
    float ds = 0.f;
    if (i < n) {
        int col = i & 127;
        float ia = kp[256 + col], ib = kp[384 + col];
        float xv = xq[i];
        float zpv = zp[i];
        float zv = z[i];
        float zr = kuma_h_inv_f(zpv, ia, ib);
        float d = zr - zv;
        ds = d * d;
        zq[i] = kuma_h_inv_f(xv, ia, ib);   // safe when zq aliases xq (same i)
    }
#pragma unroll
    for (int off = 32; off > 0; off >>= 1) ds += __shfl_down(ds, off);
    if ((threadIdx.x & 63) == 0) atomicAdd(&sums[4], ds);
}

__global__ void finalize_kernel(const float* __restrict__ sums, float* __restrict__ out_loss)
{
    if (threadIdx.x == 0) {
        const float inv = 1.f / (16384.f * 128.f);
        float rq = 0.f;
        for (int l = 0; l < 4; l++) rq += 1.25f * sums[l] * inv;
        rq *= 0.25f;
        out_loss[0] = rq + sums[4] * inv;
    }
}

// ---------------------------------------------------------------------------
// Launcher — row-chunked pipeline sized to ws_size.
// Per-chunk ws (floats): R*2048 + R*1024 + R*512 + 3*R*128 = R*3968
// plus codebook scratch 131072 + 1024 + 512 + 8 = 132616 floats.
// R=16384 -> 260.6 MB, 8192 -> 130.6, 4096 -> 65.5, 2048 -> 33.0,
// 1024 -> 16.8, 512 -> 8.7, 256 -> 4.6
// ---------------------------------------------------------------------------
extern "C" void kernel_launch(void* const* d_in, const int* in_sizes, int n_in,
                              void* d_out, int out_size, void* d_ws, size_t ws_size,
                              hipStream_t stream)
{
    constexpr int B = 16384;

    const float* x = (const float*)d_in[0];
    const float* enc_w[4]; const float* enc_b[4];
    const float* dec_w[4]; const float* dec_b[4];
    for (int i = 0; i < 4; i++) {
        enc_w[i] = (const float*)d_in[1 + 4 * i];
        enc_b[i] = (const float*)d_in[2 + 4 * i];
        dec_w[i] = (const float*)d_in[3 + 4 * i];
        dec_b[i] = (const float*)d_in[4 + 4 * i];
    }
    const float* cb    = (const float*)d_in[17];
    const float* a_raw = (const float*)d_in[18];
    const float* b_raw = (const float*)d_in[19];

    // pick largest chunk R that fits ws_size
    size_t avail = ws_size / 4;  // floats
    int R = 16384;
    while (R > 256 && (size_t)R * 3968 + 132616 > avail) R >>= 1;

    // workspace carve (floats)
    float* ws   = (float*)d_ws;
    float* a1   = ws;                        // R x 2048  (h0 / g2)
    float* a2   = a1 + (size_t)R * 2048;     // R x 1024  (h1 / g1)
    float* a3   = a2 + (size_t)R * 1024;     // R x 512   (h2 / g0)
    float* zb   = a3 + (size_t)R * 512;      // R x 128   (z)
    float* zpb  = zb + (size_t)R * 128;      // R x 128   (z')
    float* xqb  = zpb + (size_t)R * 128;     // R x 128   (x_q, then z_q in-place)
    float* cbT  = xqb + (size_t)R * 128;     // 4*128*256
    float* cnorm= cbT + 4 * 128 * 256;       // 4*256
    float* kp   = cnorm + 4 * 256;           // 512
    float* sums = kp + 512;                  // 8

    float* out      = (float*)d_out;
    float* out_loss = out + (size_t)B * 768;
    float* out_idx  = out_loss + 1;

    // prep (once)
    prep_cb_kernel<<<1024, 128, 0, stream>>>(cb, cbT, cnorm);
    kuma_ab_init<<<1, 128, 0, stream>>>(a_raw, b_raw, kp, sums);

    const int nc = B / R;
    for (int c = 0; c < nc; c++) {
        const size_t base = (size_t)c * R;
        const float* xc = x + base * 768;
        float* outc = out + base * 768;
        float* idxc = out_idx + base * 4;

        // encoder
        gemm_bias<128,128,16,8,8,true ><<<dim3(R/128, 2048/128), 256, 0, stream>>>(xc, enc_w[0], enc_b[0], a1, R, 2048, 768);
        gemm_bias<128,128,16,8,8,true ><<<dim3(R/128, 1024/128), 256, 0, stream>>>(a1, enc_w[1], enc_b[1], a2, R, 1024, 2048);
        gemm_bias<128,128,16,8,8,true ><<<dim3(R/128,  512/128), 256, 0, stream>>>(a2, enc_w[2], enc_b[2], a3, R,  512, 1024);
        gemm_bias< 64, 64,16,4,4,false><<<dim3(R/ 64,  128/ 64), 256, 0, stream>>>(a3, enc_w[3], enc_b[3], zb, R,  128,  512);

        // kuma + RQ + inverse + losses
        kuma_h_kernel<<<(R * 128) / 256, 256, 0, stream>>>(zb, kp, zpb, R * 128);
        rq_kernel<<<R / RQ_ROWS, 256, 0, stream>>>(zpb, cb, cbT, cnorm, xqb, idxc, sums);
        zq_nvq_kernel<<<(R * 128) / 256, 256, 0, stream>>>(xqb, zpb, zb, kp, xqb, sums, R * 128);

        // decoder (xqb now holds z_q)
        gemm_bias<128,128,16,8,8,true ><<<dim3(R/128,  512/128), 256, 0, stream>>>(xqb, dec_w[0], dec_b[0], a3, R,  512,  128);
        gemm_bias<128,128,16,8,8,true ><<<dim3(R/128, 1024/128), 256, 0, stream>>>(a3, dec_w[1], dec_b[1], a2, R, 1024,  512);
        gemm_bias<128,128,16,8,8,true ><<<dim3(R/128, 2048/128), 256, 0, stream>>>(a2, dec_w[2], dec_b[2], a1, R, 2048, 1024);
        gemm_bias<128,128,16,8,8,false><<<dim3(R/128,  768/128), 256, 0, stream>>>(a1, dec_w[3], dec_b[3], outc, R,  768, 2048);
    }

    finalize_kernel<<<1, 64, 0, stream>>>(sums, out_loss);
}

// Round 4
// 2988.242 us; speedup vs baseline: 1.3648x; 1.3648x over previous
//
#include <hip/hip_runtime.h>
#include <math.h>

#define EPS_F 1e-6f
#define ONE_M_EPS (1.0f - 1e-6f)

typedef __attribute__((ext_vector_type(8))) short s16x8;
typedef __attribute__((ext_vector_type(4))) float f32x4;

__device__ __forceinline__ ushort f2bf(float f) {
    union { float f; unsigned u; } v; v.f = f;
    unsigned u = v.u;
    return (ushort)((u + 0x7FFFu + ((u >> 16) & 1u)) >> 16);
}

// ---------------------------------------------------------------------------
// Tiled fp32 GEMM (encoder):  C[M,N] = act(A[M,K] @ W[K,N] + bias[N])
// ---------------------------------------------------------------------------
template<int BM, int BN, int BK, int TM, int TN, bool RELU>
__global__ __launch_bounds__(256) void gemm_bias(
    const float* __restrict__ A, const float* __restrict__ W,
    const float* __restrict__ bias, float* __restrict__ C,
    int M, int N, int K)
{
    constexpr int APAD = (BM == 128) ? 132 : 68;
    __shared__ float As[BK][APAD];
    __shared__ float Bs[BK][BN];

    const int tid = threadIdx.x;
    const int tx = tid & 15;
    const int ty = tid >> 4;
    const int bm = blockIdx.x * BM;
    const int bn = blockIdx.y * BN;

    constexpr int NG = TN / 4;
    constexpr int GSTRIDE = BN / NG;

    float acc[TM][TN];
#pragma unroll
    for (int i = 0; i < TM; i++)
#pragma unroll
        for (int j = 0; j < TN; j++) acc[i][j] = 0.f;

    constexpr int A_F4 = BM * BK / 4 / 256;
    constexpr int B_F4 = BK * BN / 4 / 256;

    for (int k0 = 0; k0 < K; k0 += BK) {
#pragma unroll
        for (int p = 0; p < A_F4; p++) {
            int fi = tid + p * 256;
            int row = fi / (BK / 4);
            int kc = (fi % (BK / 4)) * 4;
            float4 v = *reinterpret_cast<const float4*>(
                &A[(size_t)(bm + row) * K + k0 + kc]);
            As[kc + 0][row] = v.x;
            As[kc + 1][row] = v.y;
            As[kc + 2][row] = v.z;
            As[kc + 3][row] = v.w;
        }
#pragma unroll
        for (int p = 0; p < B_F4; p++) {
            int fi = tid + p * 256;
            int row = fi / (BN / 4);
            int c = (fi % (BN / 4)) * 4;
            float4 v = *reinterpret_cast<const float4*>(
                &W[(size_t)(k0 + row) * N + bn + c]);
            *reinterpret_cast<float4*>(&Bs[row][c]) = v;
        }
        __syncthreads();

#pragma unroll
        for (int kk = 0; kk < BK; kk++) {
            float a[TM];
#pragma unroll
            for (int i = 0; i < TM; i += 4) {
                float4 v = *reinterpret_cast<const float4*>(&As[kk][ty * TM + i]);
                a[i] = v.x; a[i + 1] = v.y; a[i + 2] = v.z; a[i + 3] = v.w;
            }
            float b[TN];
#pragma unroll
            for (int g = 0; g < NG; g++) {
                float4 v = *reinterpret_cast<const float4*>(&Bs[kk][g * GSTRIDE + tx * 4]);
                b[g * 4] = v.x; b[g * 4 + 1] = v.y; b[g * 4 + 2] = v.z; b[g * 4 + 3] = v.w;
            }
#pragma unroll
            for (int i = 0; i < TM; i++)
#pragma unroll
                for (int j = 0; j < TN; j++)
                    acc[i][j] += a[i] * b[j];
        }
        __syncthreads();
    }

#pragma unroll
    for (int g = 0; g < NG; g++) {
        int cn = bn + g * GSTRIDE + tx * 4;
        float4 bv = *reinterpret_cast<const float4*>(&bias[cn]);
#pragma unroll
        for (int i = 0; i < TM; i++) {
            int rm = bm + ty * TM + i;
            float4 o;
            o.x = acc[i][g * 4 + 0] + bv.x;
            o.y = acc[i][g * 4 + 1] + bv.y;
            o.z = acc[i][g * 4 + 2] + bv.z;
            o.w = acc[i][g * 4 + 3] + bv.w;
            if (RELU) {
                o.x = fmaxf(o.x, 0.f); o.y = fmaxf(o.y, 0.f);
                o.z = fmaxf(o.z, 0.f); o.w = fmaxf(o.w, 0.f);
            }
            *reinterpret_cast<float4*>(&C[(size_t)rm * N + cn]) = o;
        }
    }
}

// ---------------------------------------------------------------------------
// MFMA bf16 GEMM (decoder): C[M,N] = act(A[M,K] @ WT[N,K]^T + bias[N])
// A, WT bf16 (K-major). 128x128 tile, BK=32, 4 waves, global_load_lds(16B).
// m97 structure: stage -> barrier -> ds_read frags -> 16 MFMA -> barrier.
// ---------------------------------------------------------------------------
#define GLL16(srcp, dstp)                                                     \
    __builtin_amdgcn_global_load_lds(                                         \
        (const __attribute__((address_space(1))) void*)(srcp),                \
        (__attribute__((address_space(3))) void*)(dstp), 16, 0, 0)

template<bool RELU, bool OUT_BF16>
__global__ __launch_bounds__(256) void gemm_mfma_bt(
    const ushort* __restrict__ A, const ushort* __restrict__ WT,
    const float* __restrict__ bias, void* __restrict__ Cv,
    int M, int N, int K)
{
    __shared__ __align__(16) ushort As[128 * 32];
    __shared__ __align__(16) ushort Bs[128 * 32];

    const int tid  = threadIdx.x;
    const int lane = tid & 63;
    const int w    = tid >> 6;          // wave 0..3
    const int wm   = (w >> 1) * 64;     // wave row offset in tile
    const int wn   = (w & 1) * 64;      // wave col offset in tile
    const int bm   = blockIdx.x * 128;
    const int bn   = blockIdx.y * 128;

    f32x4 acc[4][4];
#pragma unroll
    for (int i = 0; i < 4; i++)
#pragma unroll
        for (int j = 0; j < 4; j++) acc[i][j] = f32x4{0.f, 0.f, 0.f, 0.f};

    // staging: tile = 512 chunks of 16B; chunk c -> row c>>2, kelem (c&3)*8.
    // wave w issues 2 instructions per operand, covering chunks [seg*64, seg*64+64)
    const int c0 = (w * 2) * 64 + lane;
    const int c1 = (w * 2 + 1) * 64 + lane;
    const int r0 = c0 >> 2, k0e = (c0 & 3) * 8;
    const int r1 = c1 >> 2, k1e = (c1 & 3) * 8;

    const ushort* a_src0 = A  + (size_t)(bm + r0) * K + k0e;
    const ushort* a_src1 = A  + (size_t)(bm + r1) * K + k1e;
    const ushort* b_src0 = WT + (size_t)(bn + r0) * K + k0e;
    const ushort* b_src1 = WT + (size_t)(bn + r1) * K + k1e;
    ushort* a_dst0 = &As[(w * 2) * 512];
    ushort* a_dst1 = &As[(w * 2 + 1) * 512];
    ushort* b_dst0 = &Bs[(w * 2) * 512];
    ushort* b_dst1 = &Bs[(w * 2 + 1) * 512];

    const int fm = lane & 15;           // frag row/col within 16
    const int fk = (lane >> 4) * 8;     // frag k offset

    for (int k0 = 0; k0 < K; k0 += 32) {
        GLL16(a_src0 + k0, a_dst0);
        GLL16(a_src1 + k0, a_dst1);
        GLL16(b_src0 + k0, b_dst0);
        GLL16(b_src1 + k0, b_dst1);
        __syncthreads();   // drains vmcnt -> tiles ready

        s16x8 af[4], bfr[4];
#pragma unroll
        for (int i = 0; i < 4; i++)
            af[i] = *reinterpret_cast<const s16x8*>(&As[(wm + i * 16 + fm) * 32 + fk]);
#pragma unroll
        for (int j = 0; j < 4; j++)
            bfr[j] = *reinterpret_cast<const s16x8*>(&Bs[(wn + j * 16 + fm) * 32 + fk]);
#pragma unroll
        for (int i = 0; i < 4; i++)
#pragma unroll
            for (int j = 0; j < 4; j++)
                acc[i][j] = __builtin_amdgcn_mfma_f32_16x16x32_bf16(
                    af[i], bfr[j], acc[i][j], 0, 0, 0);
        __syncthreads();   // all reads done before next stage overwrites
    }

    // epilogue: D row = (lane>>4)*4 + r, col = lane&15 within each 16x16 frag
#pragma unroll
    for (int j = 0; j < 4; j++) {
        const int coln = bn + wn + j * 16 + fm;
        const float bv = bias[coln];
#pragma unroll
        for (int i = 0; i < 4; i++) {
            const int row0 = bm + wm + i * 16 + (lane >> 4) * 4;
#pragma unroll
            for (int r = 0; r < 4; r++) {
                float o = acc[i][j][r] + bv;
                if (RELU) o = fmaxf(o, 0.f);
                if (OUT_BF16)
                    ((ushort*)Cv)[(size_t)(row0 + r) * N + coln] = f2bf(o);
                else
                    ((float*)Cv)[(size_t)(row0 + r) * N + coln] = o;
            }
        }
    }
}

// ---------------------------------------------------------------------------
// Weight prep: W[K][N] fp32 -> WT[N][K] bf16 (RTN). grid (K/32, N/32), 256 thr.
// ---------------------------------------------------------------------------
__global__ __launch_bounds__(256) void transpose_to_bf16(
    const float* __restrict__ W, ushort* __restrict__ WT, int K, int N)
{
    __shared__ float t[32][33];
    const int kb = blockIdx.x * 32, nb = blockIdx.y * 32;
    const int tx = threadIdx.x & 31, ty = threadIdx.x >> 5;  // ty 0..7
#pragma unroll
    for (int i = ty; i < 32; i += 8)
        t[i][tx] = W[(size_t)(kb + i) * N + nb + tx];
    __syncthreads();
#pragma unroll
    for (int i = ty; i < 32; i += 8)
        WT[(size_t)(nb + i) * K + kb + tx] = f2bf(t[tx][i]);
}

// ---------------------------------------------------------------------------
// Codebook prep
// ---------------------------------------------------------------------------
__global__ __launch_bounds__(128) void prep_cb_kernel(
    const float* __restrict__ cb, float* __restrict__ cbT, float* __restrict__ cnorm)
{
    int b = blockIdx.x;
    int d = threadIdx.x;
    float v = cb[(size_t)b * 128 + d];
    int l = b >> 8, c = b & 255;
    cbT[((size_t)l * 128 + d) * 256 + c] = v;
    float s = v * v;
#pragma unroll
    for (int off = 32; off > 0; off >>= 1) s += __shfl_down(s, off);
    __shared__ float ps[2];
    if ((d & 63) == 0) ps[d >> 6] = s;
    __syncthreads();
    if (d == 0) cnorm[b] = ps[0] + ps[1];
}

__device__ __forceinline__ float softplusf(float x) {
    return (x > 20.f) ? x : log1pf(expf(x));
}

__global__ void kuma_ab_init(const float* __restrict__ a_raw, const float* __restrict__ b_raw,
                             float* __restrict__ kp, float* __restrict__ sums)
{
    int t = threadIdx.x;
    if (t < 128) {
        float a = softplusf(a_raw[t]) + EPS_F;
        float b = softplusf(b_raw[t]) + EPS_F;
        kp[t] = a;
        kp[128 + t] = b;
        kp[256 + t] = 1.f / a;
        kp[384 + t] = 1.f / b;
    }
    if (t < 8) sums[t] = 0.f;
}

__global__ __launch_bounds__(256) void kuma_h_kernel(
    const float* __restrict__ z, const float* __restrict__ kp,
    float* __restrict__ zp, int n)
{
    int i = blockIdx.x * 256 + threadIdx.x;
    if (i >= n) return;
    int col = i & 127;
    float a = kp[col], b = kp[128 + col];
    float zv = z[i];
    float x = 1.f / (1.f + expf(-zv));
    x = fminf(fmaxf(x, EPS_F), ONE_M_EPS);
    float inner = 1.f - powf(x, a);
    inner = fminf(fmaxf(inner, EPS_F), 1.f);
    float y = 1.f - powf(inner, b);
    y = fminf(fmaxf(y, EPS_F), ONE_M_EPS);
    zp[i] = y;
}

// ---------------------------------------------------------------------------
// Fused residual quantizer (unchanged, index-exact fp32)
// ---------------------------------------------------------------------------
#define RQ_ROWS 8
__global__ __launch_bounds__(256) void rq_kernel(
    const float* __restrict__ zp, const float* __restrict__ cb,
    const float* __restrict__ cbT, const float* __restrict__ cnorm,
    float* __restrict__ xq, float* __restrict__ idx_out, float* __restrict__ sums)
{
    __shared__ float res[RQ_ROWS][128];
    __shared__ float rd[4][RQ_ROWS];
    __shared__ int   ri[4][RQ_ROWS];
    __shared__ int   bidx[RQ_ROWS];

    const int t = threadIdx.x;
    const int lane = t & 63;
    const int wv = t >> 6;
    const int row0 = blockIdx.x * RQ_ROWS;

#pragma unroll
    for (int j = 0; j < RQ_ROWS * 128 / 256; j++) {
        int e = t + j * 256;
        res[e >> 7][e & 127] = zp[(size_t)row0 * 128 + e];
    }
    __syncthreads();

    float lsum[4] = {0.f, 0.f, 0.f, 0.f};

#pragma unroll 1
    for (int l = 0; l < 4; l++) {
        const float* cT = cbT + (size_t)l * 128 * 256;
        float acc[RQ_ROWS];
#pragma unroll
        for (int r = 0; r < RQ_ROWS; r++) acc[r] = 0.f;

        for (int d = 0; d < 128; d += 4) {
            float c0 = cT[(d + 0) * 256 + t];
            float c1 = cT[(d + 1) * 256 + t];
            float c2 = cT[(d + 2) * 256 + t];
            float c3 = cT[(d + 3) * 256 + t];
#pragma unroll
            for (int r = 0; r < RQ_ROWS; r++) {
                float4 rv = *reinterpret_cast<const float4*>(&res[r][d]);
                acc[r] += rv.x * c0 + rv.y * c1 + rv.z * c2 + rv.w * c3;
            }
        }
        float cn = cnorm[l * 256 + t];

#pragma unroll
        for (int r = 0; r < RQ_ROWS; r++) {
            float dmin = cn - 2.f * acc[r];
            int imin = t;
#pragma unroll
            for (int off = 32; off > 0; off >>= 1) {
                float d2 = __shfl_down(dmin, off);
                int i2 = __shfl_down(imin, off);
                if (d2 < dmin || (d2 == dmin && i2 < imin)) { dmin = d2; imin = i2; }
            }
            if (lane == 0) { rd[wv][r] = dmin; ri[wv][r] = imin; }
        }
        __syncthreads();
        if (t < RQ_ROWS) {
            float dm = rd[0][t]; int im = ri[0][t];
#pragma unroll
            for (int w = 1; w < 4; w++) {
                float d2 = rd[w][t]; int i2 = ri[w][t];
                if (d2 < dm || (d2 == dm && i2 < im)) { dm = d2; im = i2; }
            }
            bidx[t] = im;
            idx_out[(size_t)(row0 + t) * 4 + l] = (float)im;
        }
        __syncthreads();

        float s = 0.f;
#pragma unroll
        for (int j = 0; j < RQ_ROWS * 128 / 256; j++) {
            int e = t + j * 256; int r = e >> 7; int d = e & 127;
            float q = cb[((size_t)l * 256 + bidx[r]) * 128 + d];
            float nr = res[r][d] - q;
            res[r][d] = nr;
            s += nr * nr;
        }
        lsum[l] = s;
        __syncthreads();
    }

#pragma unroll
    for (int j = 0; j < RQ_ROWS * 128 / 256; j++) {
        int e = t + j * 256;
        xq[(size_t)row0 * 128 + e] = zp[(size_t)row0 * 128 + e] - res[e >> 7][e & 127];
    }

#pragma unroll
    for (int l = 0; l < 4; l++) {
        float s = lsum[l];
#pragma unroll
        for (int off = 32; off > 0; off >>= 1) s += __shfl_down(s, off);
        if (lane == 0) atomicAdd(&sums[l], s);
    }
}

// ---------------------------------------------------------------------------
// z_q = h_inv(x_q) (in-place ok) + bf16 copy;  z_recon = h_inv(z');  nvq sum
// ---------------------------------------------------------------------------
__device__ __forceinline__ float kuma_h_inv_f(float y, float ia, float ib) {
    y = fminf(fmaxf(y, EPS_F), ONE_M_EPS);
    float omy = fminf(fmaxf(1.f - y, EPS_F), 1.f);
    float inner = fminf(fmaxf(1.f - powf(omy, ib), EPS_F), ONE_M_EPS);
    float x = fminf(fmaxf(powf(inner, ia), EPS_F), ONE_M_EPS);
    return logf(x / (1.f - x));
}

__global__ __launch_bounds__(256) void zq_nvq_kernel(
    const float* __restrict__ xq, const float* __restrict__ zp,
    const float* __restrict__ z, const float* __restrict__ kp,
    float* __restrict__ zq, ushort* __restrict__ zq16,
    float* __restrict__ sums, int n)
{
    int i = blockIdx.x * 256 + threadIdx.x;
    float ds = 0.f;
    if (i < n) {
        int col = i & 127;
        float ia = kp[256 + col], ib = kp[384 + col];
        float xv = xq[i];
        float zpv = zp[i];
        float zv = z[i];
        float zr = kuma_h_inv_f(zpv, ia, ib);
        float d = zr - zv;
        ds = d * d;
        float zqv = kuma_h_inv_f(xv, ia, ib);
        zq[i] = zqv;
        zq16[i] = f2bf(zqv);
    }
#pragma unroll
    for (int off = 32; off > 0; off >>= 1) ds += __shfl_down(ds, off);
    if ((threadIdx.x & 63) == 0) atomicAdd(&sums[4], ds);
}

__global__ void finalize_kernel(const float* __restrict__ sums, float* __restrict__ out_loss)
{
    if (threadIdx.x == 0) {
        const float inv = 1.f / (16384.f * 128.f);
        float rq = 0.f;
        for (int l = 0; l < 4; l++) rq += 1.25f * sums[l] * inv;
        rq *= 0.25f;
        out_loss[0] = rq + sums[4] * inv;
    }
}

// ---------------------------------------------------------------------------
// Launcher — encoder fp32, decoder bf16-MFMA, row-chunked to ws_size.
// Per-R floats: a1 R*2048 + a2 R*1024 + a3 R*512 + 3*R*128 + zq16 R*64 = R*4032
// Fixed floats: WT (4.26M ushort = 2.13M fl) + cbT 131072 + 1024 + 512 + 8
// R=16384 -> 273.3 MB, 8192 -> 140.6 MB, 4096 -> 74.3 MB ...
// ---------------------------------------------------------------------------
extern "C" void kernel_launch(void* const* d_in, const int* in_sizes, int n_in,
                              void* d_out, int out_size, void* d_ws, size_t ws_size,
                              hipStream_t stream)
{
    constexpr int B = 16384;

    const float* x = (const float*)d_in[0];
    const float* enc_w[4]; const float* enc_b[4];
    const float* dec_w[4]; const float* dec_b[4];
    for (int i = 0; i < 4; i++) {
        enc_w[i] = (const float*)d_in[1 + 4 * i];
        enc_b[i] = (const float*)d_in[2 + 4 * i];
        dec_w[i] = (const float*)d_in[3 + 4 * i];
        dec_b[i] = (const float*)d_in[4 + 4 * i];
    }
    const float* cb    = (const float*)d_in[17];
    const float* a_raw = (const float*)d_in[18];
    const float* b_raw = (const float*)d_in[19];

    // chunk size
    size_t avail = ws_size / 4;
    const size_t fixed_f = (size_t)(512*128 + 1024*512 + 2048*1024 + 768*2048) / 2
                         + 131072 + 1024 + 512 + 8;
    int R = 16384;
    while (R > 256 && (size_t)R * 4032 + fixed_f > avail) R >>= 1;

    // carve (floats)
    float* ws   = (float*)d_ws;
    float* a1   = ws;                        // R x 2048 fp32 (enc) / R x 2048 bf16 (dec h16c)
    float* a2   = a1 + (size_t)R * 2048;     // R x 1024 fp32 / bf16 h16b
    float* a3   = a2 + (size_t)R * 1024;     // R x 512 fp32 / bf16 h16a
    float* zb   = a3 + (size_t)R * 512;
    float* zpb  = zb + (size_t)R * 128;
    float* xqb  = zpb + (size_t)R * 128;
    float* zq16f= xqb + (size_t)R * 128;     // R*128 ushort
    float* wt0f = zq16f + (size_t)R * 64;    // 512*128 ushort
    float* wt1f = wt0f + (512 * 128) / 2;    // 1024*512 ushort
    float* wt2f = wt1f + (1024 * 512) / 2;   // 2048*1024 ushort
    float* wt3f = wt2f + (2048 * 1024) / 2;  // 768*2048 ushort
    float* cbT  = wt3f + (768 * 2048) / 2;
    float* cnorm= cbT + 4 * 128 * 256;
    float* kp   = cnorm + 4 * 256;
    float* sums = kp + 512;

    ushort* zq16 = (ushort*)zq16f;
    ushort* wt0 = (ushort*)wt0f;
    ushort* wt1 = (ushort*)wt1f;
    ushort* wt2 = (ushort*)wt2f;
    ushort* wt3 = (ushort*)wt3f;
    ushort* h16a = (ushort*)a3;   // R x 512  bf16
    ushort* h16b = (ushort*)a2;   // R x 1024 bf16
    ushort* h16c = (ushort*)a1;   // R x 2048 bf16

    float* out      = (float*)d_out;
    float* out_loss = out + (size_t)B * 768;
    float* out_idx  = out_loss + 1;

    // prep (once per launch)
    prep_cb_kernel<<<1024, 128, 0, stream>>>(cb, cbT, cnorm);
    kuma_ab_init<<<1, 128, 0, stream>>>(a_raw, b_raw, kp, sums);
    transpose_to_bf16<<<dim3(128/32,  512/32), 256, 0, stream>>>(dec_w[0], wt0,  128,  512);
    transpose_to_bf16<<<dim3(512/32, 1024/32), 256, 0, stream>>>(dec_w[1], wt1,  512, 1024);
    transpose_to_bf16<<<dim3(1024/32,2048/32), 256, 0, stream>>>(dec_w[2], wt2, 1024, 2048);
    transpose_to_bf16<<<dim3(2048/32, 768/32), 256, 0, stream>>>(dec_w[3], wt3, 2048,  768);

    const int nc = B / R;
    for (int c = 0; c < nc; c++) {
        const size_t base = (size_t)c * R;
        const float* xc = x + base * 768;
        float* outc = out + base * 768;
        float* idxc = out_idx + base * 4;

        // encoder (fp32, index-exact)
        gemm_bias<128,128,16,8,8,true ><<<dim3(R/128, 2048/128), 256, 0, stream>>>(xc, enc_w[0], enc_b[0], a1, R, 2048, 768);
        gemm_bias<128,128,16,8,8,true ><<<dim3(R/128, 1024/128), 256, 0, stream>>>(a1, enc_w[1], enc_b[1], a2, R, 1024, 2048);
        gemm_bias<128,128,16,8,8,true ><<<dim3(R/128,  512/128), 256, 0, stream>>>(a2, enc_w[2], enc_b[2], a3, R,  512, 1024);
        gemm_bias< 64, 64,16,4,4,false><<<dim3(R/ 64,  128/ 64), 256, 0, stream>>>(a3, enc_w[3], enc_b[3], zb, R,  128,  512);

        // kuma + RQ + inverse + losses (fp32)
        kuma_h_kernel<<<(R * 128) / 256, 256, 0, stream>>>(zb, kp, zpb, R * 128);
        rq_kernel<<<R / RQ_ROWS, 256, 0, stream>>>(zpb, cb, cbT, cnorm, xqb, idxc, sums);
        zq_nvq_kernel<<<(R * 128) / 256, 256, 0, stream>>>(xqb, zpb, zb, kp, xqb, zq16, sums, R * 128);

        // decoder (bf16 MFMA; activations chained in bf16, aliased into arenas)
        gemm_mfma_bt<true , true ><<<dim3(R/128,  512/128), 256, 0, stream>>>(zq16, wt0, dec_b[0], h16a, R,  512,  128);
        gemm_mfma_bt<true , true ><<<dim3(R/128, 1024/128), 256, 0, stream>>>(h16a, wt1, dec_b[1], h16b, R, 1024,  512);
        gemm_mfma_bt<true , true ><<<dim3(R/128, 2048/128), 256, 0, stream>>>(h16b, wt2, dec_b[2], h16c, R, 2048, 1024);
        gemm_mfma_bt<false, false><<<dim3(R/128,  768/128), 256, 0, stream>>>(h16c, wt3, dec_b[3], outc, R,  768, 2048);
    }

    finalize_kernel<<<1, 64, 0, stream>>>(sums, out_loss);
}

// Round 5
// 2176.048 us; speedup vs baseline: 1.8742x; 1.3732x over previous
//
#include <hip/hip_runtime.h>
#include <math.h>

#define EPS_F 1e-6f
#define ONE_M_EPS (1.0f - 1e-6f)

typedef __attribute__((ext_vector_type(8))) short s16x8;
typedef __attribute__((ext_vector_type(4))) float f32x4;

__device__ __forceinline__ ushort f2bf(float f) {
    union { float f; unsigned u; } v; v.f = f;
    unsigned u = v.u;
    return (ushort)((u + 0x7FFFu + ((u >> 16) & 1u)) >> 16);
}
__device__ __forceinline__ float bf2f(ushort h) {
    union { unsigned u; float f; } v; v.u = ((unsigned)h) << 16;
    return v.f;
}
__device__ __forceinline__ void split3(float x, ushort& h, ushort& m, ushort& l) {
    h = f2bf(x); float r1 = x - bf2f(h);
    m = f2bf(r1); float r2 = r1 - bf2f(m);
    l = f2bf(r2);
}

#define GLL16(srcp, dstp)                                                     \
    __builtin_amdgcn_global_load_lds(                                         \
        (const __attribute__((address_space(1))) void*)(srcp),                \
        (__attribute__((address_space(3))) void*)(dstp), 16, 0, 0)

// ---------------------------------------------------------------------------
// Split-bf16 MFMA GEMM (encoder, fp32-grade):
// C = act(A @ WT^T + bias), A ~ Ah+Am+Al, W ~ Wh+Wm+Wl (bf16 planes, K-major).
// 6 products (p+q<=2) accumulated in fp32: error ~2^-24 — index-safe.
// OUT3=1: emit 3 bf16 planes (next layer input); OUT3=0: emit fp32.
// ---------------------------------------------------------------------------
template<bool RELU, int OUT3>
__global__ __launch_bounds__(256) void gemm_mfma_split(
    const ushort* __restrict__ Ah, const ushort* __restrict__ Am, const ushort* __restrict__ Al,
    const ushort* __restrict__ Wh, const ushort* __restrict__ Wm, const ushort* __restrict__ Wl,
    const float* __restrict__ bias,
    void* __restrict__ C0, void* __restrict__ C1, void* __restrict__ C2,
    int M, int N, int K)
{
    __shared__ __align__(16) ushort As[3][128 * 32];
    __shared__ __align__(16) ushort Bs[3][128 * 32];

    const int tid  = threadIdx.x;
    const int lane = tid & 63;
    const int w    = tid >> 6;
    const int wm   = (w >> 1) * 64;
    const int wn   = (w & 1) * 64;
    const int bm   = blockIdx.x * 128;
    const int bn   = blockIdx.y * 128;

    f32x4 acc[4][4];
#pragma unroll
    for (int i = 0; i < 4; i++)
#pragma unroll
        for (int j = 0; j < 4; j++) acc[i][j] = f32x4{0.f, 0.f, 0.f, 0.f};

    const int c0 = (w * 2) * 64 + lane;
    const int c1 = (w * 2 + 1) * 64 + lane;
    const int r0 = c0 >> 2, k0e = (c0 & 3) * 8;
    const int r1 = c1 >> 2, k1e = (c1 & 3) * 8;

    const size_t a_off0 = (size_t)(bm + r0) * K + k0e;
    const size_t a_off1 = (size_t)(bm + r1) * K + k1e;
    const size_t b_off0 = (size_t)(bn + r0) * K + k0e;
    const size_t b_off1 = (size_t)(bn + r1) * K + k1e;
    const int d0 = (w * 2) * 512;
    const int d1 = (w * 2 + 1) * 512;

    const ushort* Ap[3] = {Ah, Am, Al};
    const ushort* Wp[3] = {Wh, Wm, Wl};

    const int fm = lane & 15;
    const int fk = (lane >> 4) * 8;

    for (int k0 = 0; k0 < K; k0 += 32) {
#pragma unroll
        for (int p = 0; p < 3; p++) {
            GLL16(Ap[p] + a_off0 + k0, &As[p][d0]);
            GLL16(Ap[p] + a_off1 + k0, &As[p][d1]);
            GLL16(Wp[p] + b_off0 + k0, &Bs[p][d0]);
            GLL16(Wp[p] + b_off1 + k0, &Bs[p][d1]);
        }
        __syncthreads();

        s16x8 af[3][4];
#pragma unroll
        for (int p = 0; p < 3; p++)
#pragma unroll
            for (int i = 0; i < 4; i++)
                af[p][i] = *reinterpret_cast<const s16x8*>(&As[p][(wm + i * 16 + fm) * 32 + fk]);

#pragma unroll
        for (int q = 0; q < 3; q++) {
            s16x8 bq[4];
#pragma unroll
            for (int j = 0; j < 4; j++)
                bq[j] = *reinterpret_cast<const s16x8*>(&Bs[q][(wn + j * 16 + fm) * 32 + fk]);
#pragma unroll
            for (int p = 0; p < 3; p++) {
                if (p + q <= 2) {
#pragma unroll
                    for (int i = 0; i < 4; i++)
#pragma unroll
                        for (int j = 0; j < 4; j++)
                            acc[i][j] = __builtin_amdgcn_mfma_f32_16x16x32_bf16(
                                af[p][i], bq[j], acc[i][j], 0, 0, 0);
                }
            }
        }
        __syncthreads();
    }

#pragma unroll
    for (int j = 0; j < 4; j++) {
        const int coln = bn + wn + j * 16 + fm;
        const float bv = bias[coln];
#pragma unroll
        for (int i = 0; i < 4; i++) {
            const int row0 = bm + wm + i * 16 + (lane >> 4) * 4;
#pragma unroll
            for (int r = 0; r < 4; r++) {
                float o = acc[i][j][r] + bv;
                if (RELU) o = fmaxf(o, 0.f);
                const size_t idx = (size_t)(row0 + r) * N + coln;
                if (OUT3) {
                    ushort h, m, l;
                    split3(o, h, m, l);
                    ((ushort*)C0)[idx] = h;
                    ((ushort*)C1)[idx] = m;
                    ((ushort*)C2)[idx] = l;
                } else {
                    ((float*)C0)[idx] = o;
                }
            }
        }
    }
}

// ---------------------------------------------------------------------------
// MFMA bf16 GEMM (decoder, single product) — unchanged from round 4.
// ---------------------------------------------------------------------------
template<bool RELU, bool OUT_BF16>
__global__ __launch_bounds__(256) void gemm_mfma_bt(
    const ushort* __restrict__ A, const ushort* __restrict__ WT,
    const float* __restrict__ bias, void* __restrict__ Cv,
    int M, int N, int K)
{
    __shared__ __align__(16) ushort As[128 * 32];
    __shared__ __align__(16) ushort Bs[128 * 32];

    const int tid  = threadIdx.x;
    const int lane = tid & 63;
    const int w    = tid >> 6;
    const int wm   = (w >> 1) * 64;
    const int wn   = (w & 1) * 64;
    const int bm   = blockIdx.x * 128;
    const int bn   = blockIdx.y * 128;

    f32x4 acc[4][4];
#pragma unroll
    for (int i = 0; i < 4; i++)
#pragma unroll
        for (int j = 0; j < 4; j++) acc[i][j] = f32x4{0.f, 0.f, 0.f, 0.f};

    const int c0 = (w * 2) * 64 + lane;
    const int c1 = (w * 2 + 1) * 64 + lane;
    const int r0 = c0 >> 2, k0e = (c0 & 3) * 8;
    const int r1 = c1 >> 2, k1e = (c1 & 3) * 8;

    const ushort* a_src0 = A  + (size_t)(bm + r0) * K + k0e;
    const ushort* a_src1 = A  + (size_t)(bm + r1) * K + k1e;
    const ushort* b_src0 = WT + (size_t)(bn + r0) * K + k0e;
    const ushort* b_src1 = WT + (size_t)(bn + r1) * K + k1e;
    ushort* a_dst0 = &As[(w * 2) * 512];
    ushort* a_dst1 = &As[(w * 2 + 1) * 512];
    ushort* b_dst0 = &Bs[(w * 2) * 512];
    ushort* b_dst1 = &Bs[(w * 2 + 1) * 512];

    const int fm = lane & 15;
    const int fk = (lane >> 4) * 8;

    for (int k0 = 0; k0 < K; k0 += 32) {
        GLL16(a_src0 + k0, a_dst0);
        GLL16(a_src1 + k0, a_dst1);
        GLL16(b_src0 + k0, b_dst0);
        GLL16(b_src1 + k0, b_dst1);
        __syncthreads();

        s16x8 af[4], bfr[4];
#pragma unroll
        for (int i = 0; i < 4; i++)
            af[i] = *reinterpret_cast<const s16x8*>(&As[(wm + i * 16 + fm) * 32 + fk]);
#pragma unroll
        for (int j = 0; j < 4; j++)
            bfr[j] = *reinterpret_cast<const s16x8*>(&Bs[(wn + j * 16 + fm) * 32 + fk]);
#pragma unroll
        for (int i = 0; i < 4; i++)
#pragma unroll
            for (int j = 0; j < 4; j++)
                acc[i][j] = __builtin_amdgcn_mfma_f32_16x16x32_bf16(
                    af[i], bfr[j], acc[i][j], 0, 0, 0);
        __syncthreads();
    }

#pragma unroll
    for (int j = 0; j < 4; j++) {
        const int coln = bn + wn + j * 16 + fm;
        const float bv = bias[coln];
#pragma unroll
        for (int i = 0; i < 4; i++) {
            const int row0 = bm + wm + i * 16 + (lane >> 4) * 4;
#pragma unroll
            for (int r = 0; r < 4; r++) {
                float o = acc[i][j][r] + bv;
                if (RELU) o = fmaxf(o, 0.f);
                if (OUT_BF16)
                    ((ushort*)Cv)[(size_t)(row0 + r) * N + coln] = f2bf(o);
                else
                    ((float*)Cv)[(size_t)(row0 + r) * N + coln] = o;
            }
        }
    }
}

// ---------------------------------------------------------------------------
// Weight prep: W[K][N] fp32 -> WT[N][K], single bf16 plane (decoder)
// ---------------------------------------------------------------------------
__global__ __launch_bounds__(256) void transpose_to_bf16(
    const float* __restrict__ W, ushort* __restrict__ WT, int K, int N)
{
    __shared__ float t[32][33];
    const int kb = blockIdx.x * 32, nb = blockIdx.y * 32;
    const int tx = threadIdx.x & 31, ty = threadIdx.x >> 5;
#pragma unroll
    for (int i = ty; i < 32; i += 8)
        t[i][tx] = W[(size_t)(kb + i) * N + nb + tx];
    __syncthreads();
#pragma unroll
    for (int i = ty; i < 32; i += 8)
        WT[(size_t)(nb + i) * K + kb + tx] = f2bf(t[tx][i]);
}

// Weight prep: W[K][N] fp32 -> 3 bf16 planes [N][K] (encoder split)
__global__ __launch_bounds__(256) void transpose_split_bf16(
    const float* __restrict__ W, ushort* __restrict__ TH,
    ushort* __restrict__ TM, ushort* __restrict__ TL, int K, int N)
{
    __shared__ float t[32][33];
    const int kb = blockIdx.x * 32, nb = blockIdx.y * 32;
    const int tx = threadIdx.x & 31, ty = threadIdx.x >> 5;
#pragma unroll
    for (int i = ty; i < 32; i += 8)
        t[i][tx] = W[(size_t)(kb + i) * N + nb + tx];
    __syncthreads();
#pragma unroll
    for (int i = ty; i < 32; i += 8) {
        ushort h, m, l;
        split3(t[tx][i], h, m, l);
        const size_t idx = (size_t)(nb + i) * K + kb + tx;
        TH[idx] = h; TM[idx] = m; TL[idx] = l;
    }
}

// Split fp32 activations -> 3 bf16 planes (same layout)
__global__ __launch_bounds__(256) void split_plane_kernel(
    const float* __restrict__ X, ushort* __restrict__ H,
    ushort* __restrict__ M, ushort* __restrict__ L, size_t n)
{
    size_t i = (size_t)blockIdx.x * 256 + threadIdx.x;
    if (i >= n) return;
    ushort h, m, l;
    split3(X[i], h, m, l);
    H[i] = h; M[i] = m; L[i] = l;
}

// ---------------------------------------------------------------------------
// Codebook prep
// ---------------------------------------------------------------------------
__global__ __launch_bounds__(128) void prep_cb_kernel(
    const float* __restrict__ cb, float* __restrict__ cbT, float* __restrict__ cnorm)
{
    int b = blockIdx.x;
    int d = threadIdx.x;
    float v = cb[(size_t)b * 128 + d];
    int l = b >> 8, c = b & 255;
    cbT[((size_t)l * 128 + d) * 256 + c] = v;
    float s = v * v;
#pragma unroll
    for (int off = 32; off > 0; off >>= 1) s += __shfl_down(s, off);
    __shared__ float ps[2];
    if ((d & 63) == 0) ps[d >> 6] = s;
    __syncthreads();
    if (d == 0) cnorm[b] = ps[0] + ps[1];
}

__device__ __forceinline__ float softplusf(float x) {
    return (x > 20.f) ? x : log1pf(expf(x));
}

__global__ void kuma_ab_init(const float* __restrict__ a_raw, const float* __restrict__ b_raw,
                             float* __restrict__ kp, float* __restrict__ sums)
{
    int t = threadIdx.x;
    if (t < 128) {
        float a = softplusf(a_raw[t]) + EPS_F;
        float b = softplusf(b_raw[t]) + EPS_F;
        kp[t] = a;
        kp[128 + t] = b;
        kp[256 + t] = 1.f / a;
        kp[384 + t] = 1.f / b;
    }
    if (t < 8) sums[t] = 0.f;
}

__global__ __launch_bounds__(256) void kuma_h_kernel(
    const float* __restrict__ z, const float* __restrict__ kp,
    float* __restrict__ zp, int n)
{
    int i = blockIdx.x * 256 + threadIdx.x;
    if (i >= n) return;
    int col = i & 127;
    float a = kp[col], b = kp[128 + col];
    float zv = z[i];
    float x = 1.f / (1.f + expf(-zv));
    x = fminf(fmaxf(x, EPS_F), ONE_M_EPS);
    float inner = 1.f - powf(x, a);
    inner = fminf(fmaxf(inner, EPS_F), 1.f);
    float y = 1.f - powf(inner, b);
    y = fminf(fmaxf(y, EPS_F), ONE_M_EPS);
    zp[i] = y;
}

// ---------------------------------------------------------------------------
// Fused residual quantizer (index-exact fp32)
// ---------------------------------------------------------------------------
#define RQ_ROWS 8
__global__ __launch_bounds__(256) void rq_kernel(
    const float* __restrict__ zp, const float* __restrict__ cb,
    const float* __restrict__ cbT, const float* __restrict__ cnorm,
    float* __restrict__ xq, float* __restrict__ idx_out, float* __restrict__ sums)
{
    __shared__ float res[RQ_ROWS][128];
    __shared__ float rd[4][RQ_ROWS];
    __shared__ int   ri[4][RQ_ROWS];
    __shared__ int   bidx[RQ_ROWS];

    const int t = threadIdx.x;
    const int lane = t & 63;
    const int wv = t >> 6;
    const int row0 = blockIdx.x * RQ_ROWS;

#pragma unroll
    for (int j = 0; j < RQ_ROWS * 128 / 256; j++) {
        int e = t + j * 256;
        res[e >> 7][e & 127] = zp[(size_t)row0 * 128 + e];
    }
    __syncthreads();

    float lsum[4] = {0.f, 0.f, 0.f, 0.f};

#pragma unroll 1
    for (int l = 0; l < 4; l++) {
        const float* cT = cbT + (size_t)l * 128 * 256;
        float acc[RQ_ROWS];
#pragma unroll
        for (int r = 0; r < RQ_ROWS; r++) acc[r] = 0.f;

        for (int d = 0; d < 128; d += 4) {
            float c0 = cT[(d + 0) * 256 + t];
            float c1 = cT[(d + 1) * 256 + t];
            float c2 = cT[(d + 2) * 256 + t];
            float c3 = cT[(d + 3) * 256 + t];
#pragma unroll
            for (int r = 0; r < RQ_ROWS; r++) {
                float4 rv = *reinterpret_cast<const float4*>(&res[r][d]);
                acc[r] += rv.x * c0 + rv.y * c1 + rv.z * c2 + rv.w * c3;
            }
        }
        float cn = cnorm[l * 256 + t];

#pragma unroll
        for (int r = 0; r < RQ_ROWS; r++) {
            float dmin = cn - 2.f * acc[r];
            int imin = t;
#pragma unroll
            for (int off = 32; off > 0; off >>= 1) {
                float d2 = __shfl_down(dmin, off);
                int i2 = __shfl_down(imin, off);
                if (d2 < dmin || (d2 == dmin && i2 < imin)) { dmin = d2; imin = i2; }
            }
            if (lane == 0) { rd[wv][r] = dmin; ri[wv][r] = imin; }
        }
        __syncthreads();
        if (t < RQ_ROWS) {
            float dm = rd[0][t]; int im = ri[0][t];
#pragma unroll
            for (int w = 1; w < 4; w++) {
                float d2 = rd[w][t]; int i2 = ri[w][t];
                if (d2 < dm || (d2 == dm && i2 < im)) { dm = d2; im = i2; }
            }
            bidx[t] = im;
            idx_out[(size_t)(row0 + t) * 4 + l] = (float)im;
        }
        __syncthreads();

        float s = 0.f;
#pragma unroll
        for (int j = 0; j < RQ_ROWS * 128 / 256; j++) {
            int e = t + j * 256; int r = e >> 7; int d = e & 127;
            float q = cb[((size_t)l * 256 + bidx[r]) * 128 + d];
            float nr = res[r][d] - q;
            res[r][d] = nr;
            s += nr * nr;
        }
        lsum[l] = s;
        __syncthreads();
    }

#pragma unroll
    for (int j = 0; j < RQ_ROWS * 128 / 256; j++) {
        int e = t + j * 256;
        xq[(size_t)row0 * 128 + e] = zp[(size_t)row0 * 128 + e] - res[e >> 7][e & 127];
    }

#pragma unroll
    for (int l = 0; l < 4; l++) {
        float s = lsum[l];
#pragma unroll
        for (int off = 32; off > 0; off >>= 1) s += __shfl_down(s, off);
        if (lane == 0) atomicAdd(&sums[l], s);
    }
}

// ---------------------------------------------------------------------------
// z_q = h_inv(x_q) (+ bf16 copy);  z_recon = h_inv(z');  nvq sum
// ---------------------------------------------------------------------------
__device__ __forceinline__ float kuma_h_inv_f(float y, float ia, float ib) {
    y = fminf(fmaxf(y, EPS_F), ONE_M_EPS);
    float omy = fminf(fmaxf(1.f - y, EPS_F), 1.f);
    float inner = fminf(fmaxf(1.f - powf(omy, ib), EPS_F), ONE_M_EPS);
    float x = fminf(fmaxf(powf(inner, ia), EPS_F), ONE_M_EPS);
    return logf(x / (1.f - x));
}

__global__ __launch_bounds__(256) void zq_nvq_kernel(
    const float* __restrict__ xq, const float* __restrict__ zp,
    const float* __restrict__ z, const float* __restrict__ kp,
    float* __restrict__ zq, ushort* __restrict__ zq16,
    float* __restrict__ sums, int n)
{
    int i = blockIdx.x * 256 + threadIdx.x;
    float ds = 0.f;
    if (i < n) {
        int col = i & 127;
        float ia = kp[256 + col], ib = kp[384 + col];
        float xv = xq[i];
        float zpv = zp[i];
        float zv = z[i];
        float zr = kuma_h_inv_f(zpv, ia, ib);
        float d = zr - zv;
        ds = d * d;
        float zqv = kuma_h_inv_f(xv, ia, ib);
        zq[i] = zqv;
        zq16[i] = f2bf(zqv);
    }
#pragma unroll
    for (int off = 32; off > 0; off >>= 1) ds += __shfl_down(ds, off);
    if ((threadIdx.x & 63) == 0) atomicAdd(&sums[4], ds);
}

__global__ void finalize_kernel(const float* __restrict__ sums, float* __restrict__ out_loss)
{
    if (threadIdx.x == 0) {
        const float inv = 1.f / (16384.f * 128.f);
        float rq = 0.f;
        for (int l = 0; l < 4; l++) rq += 1.25f * sums[l] * inv;
        rq *= 0.25f;
        out_loss[0] = rq + sums[4] * inv;
    }
}

// ---------------------------------------------------------------------------
// Launcher — split-bf16 MFMA encoder (fp32-grade) + bf16 MFMA decoder.
// Per-R floats: slotA R*1536 + slotB R*3072 + z/zp/xq/zq16 R*448 = R*5056
// Fixed floats: enc planes 6,389,760 + dec WT 2,129,920 + cb 132,616
//             = 8,652,296 (~34.6 MB).  R=8192 -> ~200 MB total.
// ---------------------------------------------------------------------------
extern "C" void kernel_launch(void* const* d_in, const int* in_sizes, int n_in,
                              void* d_out, int out_size, void* d_ws, size_t ws_size,
                              hipStream_t stream)
{
    constexpr int B = 16384;

    const float* x = (const float*)d_in[0];
    const float* enc_w[4]; const float* enc_b[4];
    const float* dec_w[4]; const float* dec_b[4];
    for (int i = 0; i < 4; i++) {
        enc_w[i] = (const float*)d_in[1 + 4 * i];
        enc_b[i] = (const float*)d_in[2 + 4 * i];
        dec_w[i] = (const float*)d_in[3 + 4 * i];
        dec_b[i] = (const float*)d_in[4 + 4 * i];
    }
    const float* cb    = (const float*)d_in[17];
    const float* a_raw = (const float*)d_in[18];
    const float* b_raw = (const float*)d_in[19];

    // chunk size
    size_t avail = ws_size / 4;
    const size_t fixed_f = 8652296;
    int R = 16384;
    while (R > 256 && (size_t)R * 5056 + fixed_f > avail) R >>= 1;

    // carve (floats)
    float* ws    = (float*)d_ws;
    float* slotA = ws;                         // R*1536: xP | h1P | dec dC
    float* slotB = slotA + (size_t)R * 1536;   // R*3072: h0P | h2P | dec dA,dB
    float* zb    = slotB + (size_t)R * 3072;   // R*128
    float* zpb   = zb  + (size_t)R * 128;      // R*128
    float* xqb   = zpb + (size_t)R * 128;      // R*128
    float* zq16f = xqb + (size_t)R * 128;      // R*64 (ushort R*128)
    float* fixp  = zq16f + (size_t)R * 64;

    // fixed: encoder weight planes (3 each), decoder WT, cb scratch
    ushort* ew = (ushort*)fixp;
    ushort* e0h = ew;                ushort* e0m = e0h + 1572864; ushort* e0l = e0m + 1572864;
    ushort* e1h = e0l + 1572864;     ushort* e1m = e1h + 2097152; ushort* e1l = e1m + 2097152;
    ushort* e2h = e1l + 2097152;     ushort* e2m = e2h + 524288;  ushort* e2l = e2m + 524288;
    ushort* e3h = e2l + 524288;      ushort* e3m = e3h + 65536;   ushort* e3l = e3m + 65536;
    ushort* wt0 = e3l + 65536;       // dec planes (single)
    ushort* wt1 = wt0 + 65536;
    ushort* wt2 = wt1 + 524288;
    ushort* wt3 = wt2 + 2097152;
    float* cbT   = (float*)(wt3 + 1572864);
    float* cnorm = cbT + 4 * 128 * 256;
    float* kp    = cnorm + 4 * 256;
    float* sums  = kp + 512;

    ushort* zq16 = (ushort*)zq16f;

    // encoder activation plane aliases
    ushort* xH  = (ushort*)slotA;  ushort* xM  = xH  + (size_t)R * 768;  ushort* xL  = xM  + (size_t)R * 768;
    ushort* h0H = (ushort*)slotB;  ushort* h0M = h0H + (size_t)R * 2048; ushort* h0L = h0M + (size_t)R * 2048;
    ushort* h1H = (ushort*)slotA;  ushort* h1M = h1H + (size_t)R * 1024; ushort* h1L = h1M + (size_t)R * 1024;
    ushort* h2H = (ushort*)slotB;  ushort* h2M = h2H + (size_t)R * 512;  ushort* h2L = h2M + (size_t)R * 512;

    // decoder activation aliases
    ushort* dA = (ushort*)slotB;                       // R x 512 bf16
    ushort* dB = (ushort*)(slotB + (size_t)R * 256);   // R x 1024 bf16
    ushort* dC = (ushort*)slotA;                       // R x 2048 bf16

    float* out      = (float*)d_out;
    float* out_loss = out + (size_t)B * 768;
    float* out_idx  = out_loss + 1;

    // prep (once per launch)
    prep_cb_kernel<<<1024, 128, 0, stream>>>(cb, cbT, cnorm);
    kuma_ab_init<<<1, 128, 0, stream>>>(a_raw, b_raw, kp, sums);
    transpose_split_bf16<<<dim3( 768/32, 2048/32), 256, 0, stream>>>(enc_w[0], e0h, e0m, e0l,  768, 2048);
    transpose_split_bf16<<<dim3(2048/32, 1024/32), 256, 0, stream>>>(enc_w[1], e1h, e1m, e1l, 2048, 1024);
    transpose_split_bf16<<<dim3(1024/32,  512/32), 256, 0, stream>>>(enc_w[2], e2h, e2m, e2l, 1024,  512);
    transpose_split_bf16<<<dim3( 512/32,  128/32), 256, 0, stream>>>(enc_w[3], e3h, e3m, e3l,  512,  128);
    transpose_to_bf16<<<dim3(128/32,  512/32), 256, 0, stream>>>(dec_w[0], wt0,  128,  512);
    transpose_to_bf16<<<dim3(512/32, 1024/32), 256, 0, stream>>>(dec_w[1], wt1,  512, 1024);
    transpose_to_bf16<<<dim3(1024/32,2048/32), 256, 0, stream>>>(dec_w[2], wt2, 1024, 2048);
    transpose_to_bf16<<<dim3(2048/32, 768/32), 256, 0, stream>>>(dec_w[3], wt3, 2048,  768);

    const int nc = B / R;
    for (int c = 0; c < nc; c++) {
        const size_t base = (size_t)c * R;
        const float* xc = x + base * 768;
        float* outc = out + base * 768;
        float* idxc = out_idx + base * 4;

        // split x into 3 bf16 planes
        {
            size_t n = (size_t)R * 768;
            split_plane_kernel<<<(unsigned)((n + 255) / 256), 256, 0, stream>>>(xc, xH, xM, xL, n);
        }

        // encoder (split-bf16 MFMA, fp32-grade)
        gemm_mfma_split<true , 1><<<dim3(R/128, 16), 256, 0, stream>>>(
            xH, xM, xL, e0h, e0m, e0l, enc_b[0], h0H, h0M, h0L, R, 2048, 768);
        gemm_mfma_split<true , 1><<<dim3(R/128,  8), 256, 0, stream>>>(
            h0H, h0M, h0L, e1h, e1m, e1l, enc_b[1], h1H, h1M, h1L, R, 1024, 2048);
        gemm_mfma_split<true , 1><<<dim3(R/128,  4), 256, 0, stream>>>(
            h1H, h1M, h1L, e2h, e2m, e2l, enc_b[2], h2H, h2M, h2L, R,  512, 1024);
        gemm_mfma_split<false, 0><<<dim3(R/128,  1), 256, 0, stream>>>(
            h2H, h2M, h2L, e3h, e3m, e3l, enc_b[3], zb, nullptr, nullptr, R, 128, 512);

        // kuma + RQ + inverse + losses (fp32)
        kuma_h_kernel<<<(R * 128) / 256, 256, 0, stream>>>(zb, kp, zpb, R * 128);
        rq_kernel<<<R / RQ_ROWS, 256, 0, stream>>>(zpb, cb, cbT, cnorm, xqb, idxc, sums);
        zq_nvq_kernel<<<(R * 128) / 256, 256, 0, stream>>>(xqb, zpb, zb, kp, xqb, zq16, sums, R * 128);

        // decoder (bf16 MFMA)
        gemm_mfma_bt<true , true ><<<dim3(R/128,  512/128), 256, 0, stream>>>(zq16, wt0, dec_b[0], dA, R,  512,  128);
        gemm_mfma_bt<true , true ><<<dim3(R/128, 1024/128), 256, 0, stream>>>(dA,   wt1, dec_b[1], dB, R, 1024,  512);
        gemm_mfma_bt<true , true ><<<dim3(R/128, 2048/128), 256, 0, stream>>>(dB,   wt2, dec_b[2], dC, R, 2048, 1024);
        gemm_mfma_bt<false, false><<<dim3(R/128,  768/128), 256, 0, stream>>>(dC,   wt3, dec_b[3], outc, R,  768, 2048);
    }

    finalize_kernel<<<1, 64, 0, stream>>>(sums, out_loss);
}

// Round 6
// 1980.378 us; speedup vs baseline: 2.0594x; 1.0988x over previous
//
#include <hip/hip_runtime.h>
#include <math.h>

#define EPS_F 1e-6f
#define ONE_M_EPS (1.0f - 1e-6f)

typedef __attribute__((ext_vector_type(8))) short s16x8;
typedef __attribute__((ext_vector_type(4))) float f32x4;

__device__ __forceinline__ ushort f2bf(float f) {
    union { float f; unsigned u; } v; v.f = f;
    unsigned u = v.u;
    return (ushort)((u + 0x7FFFu + ((u >> 16) & 1u)) >> 16);
}
__device__ __forceinline__ float bf2f(ushort h) {
    union { unsigned u; float f; } v; v.u = ((unsigned)h) << 16;
    return v.f;
}
__device__ __forceinline__ void split3(float x, ushort& h, ushort& m, ushort& l) {
    h = f2bf(x); float r1 = x - bf2f(h);
    m = f2bf(r1); float r2 = r1 - bf2f(m);
    l = f2bf(r2);
}

#define GLL16(srcp, dstp)                                                     \
    __builtin_amdgcn_global_load_lds(                                         \
        (const __attribute__((address_space(1))) void*)(srcp),                \
        (__attribute__((address_space(3))) void*)(dstp), 16, 0, 0)

// ---------------------------------------------------------------------------
// Split-bf16 MFMA GEMM (encoder, fp32-grade): 6 products (p+q<=2), fp32 acc.
// ---------------------------------------------------------------------------
template<bool RELU, int OUT3>
__global__ __launch_bounds__(256) void gemm_mfma_split(
    const ushort* __restrict__ Ah, const ushort* __restrict__ Am, const ushort* __restrict__ Al,
    const ushort* __restrict__ Wh, const ushort* __restrict__ Wm, const ushort* __restrict__ Wl,
    const float* __restrict__ bias,
    void* __restrict__ C0, void* __restrict__ C1, void* __restrict__ C2,
    int M, int N, int K)
{
    __shared__ __align__(16) ushort As[3][128 * 32];
    __shared__ __align__(16) ushort Bs[3][128 * 32];

    const int tid  = threadIdx.x;
    const int lane = tid & 63;
    const int w    = tid >> 6;
    const int wm   = (w >> 1) * 64;
    const int wn   = (w & 1) * 64;
    const int bm   = blockIdx.x * 128;
    const int bn   = blockIdx.y * 128;

    f32x4 acc[4][4];
#pragma unroll
    for (int i = 0; i < 4; i++)
#pragma unroll
        for (int j = 0; j < 4; j++) acc[i][j] = f32x4{0.f, 0.f, 0.f, 0.f};

    const int c0 = (w * 2) * 64 + lane;
    const int c1 = (w * 2 + 1) * 64 + lane;
    const int r0 = c0 >> 2, k0e = (c0 & 3) * 8;
    const int r1 = c1 >> 2, k1e = (c1 & 3) * 8;

    const size_t a_off0 = (size_t)(bm + r0) * K + k0e;
    const size_t a_off1 = (size_t)(bm + r1) * K + k1e;
    const size_t b_off0 = (size_t)(bn + r0) * K + k0e;
    const size_t b_off1 = (size_t)(bn + r1) * K + k1e;
    const int d0 = (w * 2) * 512;
    const int d1 = (w * 2 + 1) * 512;

    const ushort* Ap[3] = {Ah, Am, Al};
    const ushort* Wp[3] = {Wh, Wm, Wl};

    const int fm = lane & 15;
    const int fk = (lane >> 4) * 8;

    for (int k0 = 0; k0 < K; k0 += 32) {
#pragma unroll
        for (int p = 0; p < 3; p++) {
            GLL16(Ap[p] + a_off0 + k0, &As[p][d0]);
            GLL16(Ap[p] + a_off1 + k0, &As[p][d1]);
            GLL16(Wp[p] + b_off0 + k0, &Bs[p][d0]);
            GLL16(Wp[p] + b_off1 + k0, &Bs[p][d1]);
        }
        __syncthreads();

        s16x8 af[3][4];
#pragma unroll
        for (int p = 0; p < 3; p++)
#pragma unroll
            for (int i = 0; i < 4; i++)
                af[p][i] = *reinterpret_cast<const s16x8*>(&As[p][(wm + i * 16 + fm) * 32 + fk]);

#pragma unroll
        for (int q = 0; q < 3; q++) {
            s16x8 bq[4];
#pragma unroll
            for (int j = 0; j < 4; j++)
                bq[j] = *reinterpret_cast<const s16x8*>(&Bs[q][(wn + j * 16 + fm) * 32 + fk]);
#pragma unroll
            for (int p = 0; p < 3; p++) {
                if (p + q <= 2) {
#pragma unroll
                    for (int i = 0; i < 4; i++)
#pragma unroll
                        for (int j = 0; j < 4; j++)
                            acc[i][j] = __builtin_amdgcn_mfma_f32_16x16x32_bf16(
                                af[p][i], bq[j], acc[i][j], 0, 0, 0);
                }
            }
        }
        __syncthreads();
    }

#pragma unroll
    for (int j = 0; j < 4; j++) {
        const int coln = bn + wn + j * 16 + fm;
        const float bv = bias[coln];
#pragma unroll
        for (int i = 0; i < 4; i++) {
            const int row0 = bm + wm + i * 16 + (lane >> 4) * 4;
#pragma unroll
            for (int r = 0; r < 4; r++) {
                float o = acc[i][j][r] + bv;
                if (RELU) o = fmaxf(o, 0.f);
                const size_t idx = (size_t)(row0 + r) * N + coln;
                if (OUT3) {
                    ushort h, m, l;
                    split3(o, h, m, l);
                    ((ushort*)C0)[idx] = h;
                    ((ushort*)C1)[idx] = m;
                    ((ushort*)C2)[idx] = l;
                } else {
                    ((float*)C0)[idx] = o;
                }
            }
        }
    }
}

// ---------------------------------------------------------------------------
// MFMA bf16 GEMM (decoder, single product)
// ---------------------------------------------------------------------------
template<bool RELU, bool OUT_BF16>
__global__ __launch_bounds__(256) void gemm_mfma_bt(
    const ushort* __restrict__ A, const ushort* __restrict__ WT,
    const float* __restrict__ bias, void* __restrict__ Cv,
    int M, int N, int K)
{
    __shared__ __align__(16) ushort As[128 * 32];
    __shared__ __align__(16) ushort Bs[128 * 32];

    const int tid  = threadIdx.x;
    const int lane = tid & 63;
    const int w    = tid >> 6;
    const int wm   = (w >> 1) * 64;
    const int wn   = (w & 1) * 64;
    const int bm   = blockIdx.x * 128;
    const int bn   = blockIdx.y * 128;

    f32x4 acc[4][4];
#pragma unroll
    for (int i = 0; i < 4; i++)
#pragma unroll
        for (int j = 0; j < 4; j++) acc[i][j] = f32x4{0.f, 0.f, 0.f, 0.f};

    const int c0 = (w * 2) * 64 + lane;
    const int c1 = (w * 2 + 1) * 64 + lane;
    const int r0 = c0 >> 2, k0e = (c0 & 3) * 8;
    const int r1 = c1 >> 2, k1e = (c1 & 3) * 8;

    const ushort* a_src0 = A  + (size_t)(bm + r0) * K + k0e;
    const ushort* a_src1 = A  + (size_t)(bm + r1) * K + k1e;
    const ushort* b_src0 = WT + (size_t)(bn + r0) * K + k0e;
    const ushort* b_src1 = WT + (size_t)(bn + r1) * K + k1e;
    ushort* a_dst0 = &As[(w * 2) * 512];
    ushort* a_dst1 = &As[(w * 2 + 1) * 512];
    ushort* b_dst0 = &Bs[(w * 2) * 512];
    ushort* b_dst1 = &Bs[(w * 2 + 1) * 512];

    const int fm = lane & 15;
    const int fk = (lane >> 4) * 8;

    for (int k0 = 0; k0 < K; k0 += 32) {
        GLL16(a_src0 + k0, a_dst0);
        GLL16(a_src1 + k0, a_dst1);
        GLL16(b_src0 + k0, b_dst0);
        GLL16(b_src1 + k0, b_dst1);
        __syncthreads();

        s16x8 af[4], bfr[4];
#pragma unroll
        for (int i = 0; i < 4; i++)
            af[i] = *reinterpret_cast<const s16x8*>(&As[(wm + i * 16 + fm) * 32 + fk]);
#pragma unroll
        for (int j = 0; j < 4; j++)
            bfr[j] = *reinterpret_cast<const s16x8*>(&Bs[(wn + j * 16 + fm) * 32 + fk]);
#pragma unroll
        for (int i = 0; i < 4; i++)
#pragma unroll
            for (int j = 0; j < 4; j++)
                acc[i][j] = __builtin_amdgcn_mfma_f32_16x16x32_bf16(
                    af[i], bfr[j], acc[i][j], 0, 0, 0);
        __syncthreads();
    }

#pragma unroll
    for (int j = 0; j < 4; j++) {
        const int coln = bn + wn + j * 16 + fm;
        const float bv = bias[coln];
#pragma unroll
        for (int i = 0; i < 4; i++) {
            const int row0 = bm + wm + i * 16 + (lane >> 4) * 4;
#pragma unroll
            for (int r = 0; r < 4; r++) {
                float o = acc[i][j][r] + bv;
                if (RELU) o = fmaxf(o, 0.f);
                if (OUT_BF16)
                    ((ushort*)Cv)[(size_t)(row0 + r) * N + coln] = f2bf(o);
                else
                    ((float*)Cv)[(size_t)(row0 + r) * N + coln] = o;
            }
        }
    }
}

// ---------------------------------------------------------------------------
// Weight prep kernels
// ---------------------------------------------------------------------------
__global__ __launch_bounds__(256) void transpose_to_bf16(
    const float* __restrict__ W, ushort* __restrict__ WT, int K, int N)
{
    __shared__ float t[32][33];
    const int kb = blockIdx.x * 32, nb = blockIdx.y * 32;
    const int tx = threadIdx.x & 31, ty = threadIdx.x >> 5;
#pragma unroll
    for (int i = ty; i < 32; i += 8)
        t[i][tx] = W[(size_t)(kb + i) * N + nb + tx];
    __syncthreads();
#pragma unroll
    for (int i = ty; i < 32; i += 8)
        WT[(size_t)(nb + i) * K + kb + tx] = f2bf(t[tx][i]);
}

__global__ __launch_bounds__(256) void transpose_split_bf16(
    const float* __restrict__ W, ushort* __restrict__ TH,
    ushort* __restrict__ TM, ushort* __restrict__ TL, int K, int N)
{
    __shared__ float t[32][33];
    const int kb = blockIdx.x * 32, nb = blockIdx.y * 32;
    const int tx = threadIdx.x & 31, ty = threadIdx.x >> 5;
#pragma unroll
    for (int i = ty; i < 32; i += 8)
        t[i][tx] = W[(size_t)(kb + i) * N + nb + tx];
    __syncthreads();
#pragma unroll
    for (int i = ty; i < 32; i += 8) {
        ushort h, m, l;
        split3(t[tx][i], h, m, l);
        const size_t idx = (size_t)(nb + i) * K + kb + tx;
        TH[idx] = h; TM[idx] = m; TL[idx] = l;
    }
}

__global__ __launch_bounds__(256) void split_plane_kernel(
    const float* __restrict__ X, ushort* __restrict__ H,
    ushort* __restrict__ M, ushort* __restrict__ L, size_t n)
{
    size_t i = (size_t)blockIdx.x * 256 + threadIdx.x;
    if (i >= n) return;
    ushort h, m, l;
    split3(X[i], h, m, l);
    H[i] = h; M[i] = m; L[i] = l;
}

// ---------------------------------------------------------------------------
// Codebook prep
// ---------------------------------------------------------------------------
__global__ __launch_bounds__(128) void prep_cb_kernel(
    const float* __restrict__ cb, float* __restrict__ cbT, float* __restrict__ cnorm)
{
    int b = blockIdx.x;
    int d = threadIdx.x;
    float v = cb[(size_t)b * 128 + d];
    int l = b >> 8, c = b & 255;
    cbT[((size_t)l * 128 + d) * 256 + c] = v;
    float s = v * v;
#pragma unroll
    for (int off = 32; off > 0; off >>= 1) s += __shfl_down(s, off);
    __shared__ float ps[2];
    if ((d & 63) == 0) ps[d >> 6] = s;
    __syncthreads();
    if (d == 0) cnorm[b] = ps[0] + ps[1];
}

__device__ __forceinline__ float softplusf(float x) {
    return (x > 20.f) ? x : log1pf(expf(x));
}

__global__ void kuma_ab_init(const float* __restrict__ a_raw, const float* __restrict__ b_raw,
                             float* __restrict__ kp, float* __restrict__ sums)
{
    int t = threadIdx.x;
    if (t < 128) {
        float a = softplusf(a_raw[t]) + EPS_F;
        float b = softplusf(b_raw[t]) + EPS_F;
        kp[t] = a;
        kp[128 + t] = b;
        kp[256 + t] = 1.f / a;
        kp[384 + t] = 1.f / b;
    }
    if (t < 8) sums[t] = 0.f;
}

__global__ __launch_bounds__(256) void kuma_h_kernel(
    const float* __restrict__ z, const float* __restrict__ kp,
    float* __restrict__ zp, int n)
{
    int i = blockIdx.x * 256 + threadIdx.x;
    if (i >= n) return;
    int col = i & 127;
    float a = kp[col], b = kp[128 + col];
    float zv = z[i];
    float x = 1.f / (1.f + expf(-zv));
    x = fminf(fmaxf(x, EPS_F), ONE_M_EPS);
    float inner = 1.f - powf(x, a);
    inner = fminf(fmaxf(inner, EPS_F), 1.f);
    float y = 1.f - powf(inner, b);
    y = fminf(fmaxf(y, EPS_F), ONE_M_EPS);
    zp[i] = y;
}

// ---------------------------------------------------------------------------
// Residual quantizer v2 — 1 wave/block, 4 rows, 4 codes/thread,
// register-prefetched codebook stream, barrier-free, butterfly argmin.
// ---------------------------------------------------------------------------
__global__ __launch_bounds__(64) void rq_kernel2(
    const float* __restrict__ zp, const float* __restrict__ cb,
    const float* __restrict__ cbT, const float* __restrict__ cnorm,
    float* __restrict__ xq, float* __restrict__ idx_out, float* __restrict__ sums)
{
    __shared__ float res[4][128];

    const int t = threadIdx.x;          // 0..63
    const int row0 = blockIdx.x * 4;

    // load z' (512 elems, 8/thread)
#pragma unroll
    for (int j = 0; j < 8; j++) {
        int e = t + j * 64;
        res[e >> 7][e & 127] = zp[(size_t)row0 * 128 + e];
    }
    // single wave: LDS write->read ordering handled by lgkmcnt (no barrier)

    float lsum[4];
    float totq[4];   // unused slot padding

#pragma unroll 1
    for (int l = 0; l < 4; l++) {
        const float* cT = cbT + (size_t)l * 32768;

        float acc[4][4];
#pragma unroll
        for (int r = 0; r < 4; r++)
#pragma unroll
            for (int cc = 0; cc < 4; cc++) acc[r][cc] = 0.f;

        // prefetch codes {t, t+64, t+128, t+192} for d=0..3
        float pc[16];
#pragma unroll
        for (int dd = 0; dd < 4; dd++)
#pragma unroll
            for (int cc = 0; cc < 4; cc++)
                pc[dd * 4 + cc] = cT[dd * 256 + cc * 64 + t];

#pragma unroll 2
        for (int d = 0; d < 128; d += 4) {
            float nc[16];
            if (d < 124) {
#pragma unroll
                for (int dd = 0; dd < 4; dd++)
#pragma unroll
                    for (int cc = 0; cc < 4; cc++)
                        nc[dd * 4 + cc] = cT[(d + 4 + dd) * 256 + cc * 64 + t];
            }
#pragma unroll
            for (int r = 0; r < 4; r++) {
                float4 rv = *reinterpret_cast<const float4*>(&res[r][d]);
#pragma unroll
                for (int cc = 0; cc < 4; cc++) {
                    acc[r][cc] += rv.x * pc[cc] + rv.y * pc[4 + cc]
                                + rv.z * pc[8 + cc] + rv.w * pc[12 + cc];
                }
            }
#pragma unroll
            for (int k = 0; k < 16; k++) pc[k] = nc[k];
        }

        float cn[4];
#pragma unroll
        for (int cc = 0; cc < 4; cc++) cn[cc] = cnorm[l * 256 + cc * 64 + t];

        int bidx0, bidx1, bidx2, bidx3;
#pragma unroll
        for (int r = 0; r < 4; r++) {
            float dmin = cn[0] - 2.f * acc[r][0];
            int imin = t;
#pragma unroll
            for (int cc = 1; cc < 4; cc++) {
                float dv = cn[cc] - 2.f * acc[r][cc];
                if (dv < dmin) { dmin = dv; imin = cc * 64 + t; }  // strict < keeps lowest idx
            }
            // butterfly: every lane ends with the global argmin
#pragma unroll
            for (int off = 1; off < 64; off <<= 1) {
                float d2 = __shfl_xor(dmin, off);
                int i2 = __shfl_xor(imin, off);
                if (d2 < dmin || (d2 == dmin && i2 < imin)) { dmin = d2; imin = i2; }
            }
            if (r == 0) bidx0 = imin;
            else if (r == 1) bidx1 = imin;
            else if (r == 2) bidx2 = imin;
            else bidx3 = imin;
            if (t == 0) idx_out[(size_t)(row0 + r) * 4 + l] = (float)imin;
        }

        // residual update + loss (rows j>>1, d = (j&1)*64 + t)
        float s = 0.f;
#pragma unroll
        for (int j = 0; j < 8; j++) {
            const int r = j >> 1;
            const int d = (j & 1) * 64 + t;
            const int bi = (r == 0) ? bidx0 : (r == 1) ? bidx1 : (r == 2) ? bidx2 : bidx3;
            float q = cb[((size_t)(l * 256) + bi) * 128 + d];
            float nr = res[r][d] - q;
            res[r][d] = nr;
            s += nr * nr;
        }
        lsum[l] = s;
        (void)totq;
    }

    // x_q = z' - final residual
#pragma unroll
    for (int j = 0; j < 8; j++) {
        int e = t + j * 64;
        xq[(size_t)row0 * 128 + e] = zp[(size_t)row0 * 128 + e] - res[e >> 7][e & 127];
    }

    // loss reduce + atomics
#pragma unroll
    for (int l = 0; l < 4; l++) {
        float s = lsum[l];
#pragma unroll
        for (int off = 32; off > 0; off >>= 1) s += __shfl_down(s, off);
        if (t == 0) atomicAdd(&sums[l], s);
    }
}

// ---------------------------------------------------------------------------
// z_q = h_inv(x_q) (+ bf16 copy);  z_recon = h_inv(z');  nvq sum
// ---------------------------------------------------------------------------
__device__ __forceinline__ float kuma_h_inv_f(float y, float ia, float ib) {
    y = fminf(fmaxf(y, EPS_F), ONE_M_EPS);
    float omy = fminf(fmaxf(1.f - y, EPS_F), 1.f);
    float inner = fminf(fmaxf(1.f - powf(omy, ib), EPS_F), ONE_M_EPS);
    float x = fminf(fmaxf(powf(inner, ia), EPS_F), ONE_M_EPS);
    return logf(x / (1.f - x));
}

__global__ __launch_bounds__(256) void zq_nvq_kernel(
    const float* __restrict__ xq, const float* __restrict__ zp,
    const float* __restrict__ z, const float* __restrict__ kp,
    float* __restrict__ zq, ushort* __restrict__ zq16,
    float* __restrict__ sums, int n)
{
    int i = blockIdx.x * 256 + threadIdx.x;
    float ds = 0.f;
    if (i < n) {
        int col = i & 127;
        float ia = kp[256 + col], ib = kp[384 + col];
        float xv = xq[i];
        float zpv = zp[i];
        float zv = z[i];
        float zr = kuma_h_inv_f(zpv, ia, ib);
        float d = zr - zv;
        ds = d * d;
        float zqv = kuma_h_inv_f(xv, ia, ib);
        zq[i] = zqv;
        zq16[i] = f2bf(zqv);
    }
#pragma unroll
    for (int off = 32; off > 0; off >>= 1) ds += __shfl_down(ds, off);
    if ((threadIdx.x & 63) == 0) atomicAdd(&sums[4], ds);
}

__global__ void finalize_kernel(const float* __restrict__ sums, float* __restrict__ out_loss)
{
    if (threadIdx.x == 0) {
        const float inv = 1.f / (16384.f * 128.f);
        float rq = 0.f;
        for (int l = 0; l < 4; l++) rq += 1.25f * sums[l] * inv;
        rq *= 0.25f;
        out_loss[0] = rq + sums[4] * inv;
    }
}

// ---------------------------------------------------------------------------
// Launcher
// ---------------------------------------------------------------------------
extern "C" void kernel_launch(void* const* d_in, const int* in_sizes, int n_in,
                              void* d_out, int out_size, void* d_ws, size_t ws_size,
                              hipStream_t stream)
{
    constexpr int B = 16384;

    const float* x = (const float*)d_in[0];
    const float* enc_w[4]; const float* enc_b[4];
    const float* dec_w[4]; const float* dec_b[4];
    for (int i = 0; i < 4; i++) {
        enc_w[i] = (const float*)d_in[1 + 4 * i];
        enc_b[i] = (const float*)d_in[2 + 4 * i];
        dec_w[i] = (const float*)d_in[3 + 4 * i];
        dec_b[i] = (const float*)d_in[4 + 4 * i];
    }
    const float* cb    = (const float*)d_in[17];
    const float* a_raw = (const float*)d_in[18];
    const float* b_raw = (const float*)d_in[19];

    // chunk size
    size_t avail = ws_size / 4;
    const size_t fixed_f = 8652296;
    int R = 16384;
    while (R > 256 && (size_t)R * 5056 + fixed_f > avail) R >>= 1;

    // carve (floats)
    float* ws    = (float*)d_ws;
    float* slotA = ws;                         // R*1536
    float* slotB = slotA + (size_t)R * 1536;   // R*3072
    float* zb    = slotB + (size_t)R * 3072;   // R*128
    float* zpb   = zb  + (size_t)R * 128;      // R*128
    float* xqb   = zpb + (size_t)R * 128;      // R*128
    float* zq16f = xqb + (size_t)R * 128;      // R*64 (ushort R*128)
    float* fixp  = zq16f + (size_t)R * 64;

    ushort* ew = (ushort*)fixp;
    ushort* e0h = ew;                ushort* e0m = e0h + 1572864; ushort* e0l = e0m + 1572864;
    ushort* e1h = e0l + 1572864;     ushort* e1m = e1h + 2097152; ushort* e1l = e1m + 2097152;
    ushort* e2h = e1l + 2097152;     ushort* e2m = e2h + 524288;  ushort* e2l = e2m + 524288;
    ushort* e3h = e2l + 524288;      ushort* e3m = e3h + 65536;   ushort* e3l = e3m + 65536;
    ushort* wt0 = e3l + 65536;
    ushort* wt1 = wt0 + 65536;
    ushort* wt2 = wt1 + 524288;
    ushort* wt3 = wt2 + 2097152;
    float* cbT   = (float*)(wt3 + 1572864);
    float* cnorm = cbT + 4 * 128 * 256;
    float* kp    = cnorm + 4 * 256;
    float* sums  = kp + 512;

    ushort* zq16 = (ushort*)zq16f;

    ushort* xH  = (ushort*)slotA;  ushort* xM  = xH  + (size_t)R * 768;  ushort* xL  = xM  + (size_t)R * 768;
    ushort* h0H = (ushort*)slotB;  ushort* h0M = h0H + (size_t)R * 2048; ushort* h0L = h0M + (size_t)R * 2048;
    ushort* h1H = (ushort*)slotA;  ushort* h1M = h1H + (size_t)R * 1024; ushort* h1L = h1M + (size_t)R * 1024;
    ushort* h2H = (ushort*)slotB;  ushort* h2M = h2H + (size_t)R * 512;  ushort* h2L = h2M + (size_t)R * 512;

    ushort* dA = (ushort*)slotB;
    ushort* dB = (ushort*)(slotB + (size_t)R * 256);
    ushort* dC = (ushort*)slotA;

    float* out      = (float*)d_out;
    float* out_loss = out + (size_t)B * 768;
    float* out_idx  = out_loss + 1;

    // prep (once per launch)
    prep_cb_kernel<<<1024, 128, 0, stream>>>(cb, cbT, cnorm);
    kuma_ab_init<<<1, 128, 0, stream>>>(a_raw, b_raw, kp, sums);
    transpose_split_bf16<<<dim3( 768/32, 2048/32), 256, 0, stream>>>(enc_w[0], e0h, e0m, e0l,  768, 2048);
    transpose_split_bf16<<<dim3(2048/32, 1024/32), 256, 0, stream>>>(enc_w[1], e1h, e1m, e1l, 2048, 1024);
    transpose_split_bf16<<<dim3(1024/32,  512/32), 256, 0, stream>>>(enc_w[2], e2h, e2m, e2l, 1024,  512);
    transpose_split_bf16<<<dim3( 512/32,  128/32), 256, 0, stream>>>(enc_w[3], e3h, e3m, e3l,  512,  128);
    transpose_to_bf16<<<dim3(128/32,  512/32), 256, 0, stream>>>(dec_w[0], wt0,  128,  512);
    transpose_to_bf16<<<dim3(512/32, 1024/32), 256, 0, stream>>>(dec_w[1], wt1,  512, 1024);
    transpose_to_bf16<<<dim3(1024/32,2048/32), 256, 0, stream>>>(dec_w[2], wt2, 1024, 2048);
    transpose_to_bf16<<<dim3(2048/32, 768/32), 256, 0, stream>>>(dec_w[3], wt3, 2048,  768);

    const int nc = B / R;
    for (int c = 0; c < nc; c++) {
        const size_t base = (size_t)c * R;
        const float* xc = x + base * 768;
        float* outc = out + base * 768;
        float* idxc = out_idx + base * 4;

        {
            size_t n = (size_t)R * 768;
            split_plane_kernel<<<(unsigned)((n + 255) / 256), 256, 0, stream>>>(xc, xH, xM, xL, n);
        }

        // encoder (split-bf16 MFMA, fp32-grade)
        gemm_mfma_split<true , 1><<<dim3(R/128, 16), 256, 0, stream>>>(
            xH, xM, xL, e0h, e0m, e0l, enc_b[0], h0H, h0M, h0L, R, 2048, 768);
        gemm_mfma_split<true , 1><<<dim3(R/128,  8), 256, 0, stream>>>(
            h0H, h0M, h0L, e1h, e1m, e1l, enc_b[1], h1H, h1M, h1L, R, 1024, 2048);
        gemm_mfma_split<true , 1><<<dim3(R/128,  4), 256, 0, stream>>>(
            h1H, h1M, h1L, e2h, e2m, e2l, enc_b[2], h2H, h2M, h2L, R,  512, 1024);
        gemm_mfma_split<false, 0><<<dim3(R/128,  1), 256, 0, stream>>>(
            h2H, h2M, h2L, e3h, e3m, e3l, enc_b[3], zb, nullptr, nullptr, R, 128, 512);

        // kuma + RQ + inverse + losses (fp32)
        kuma_h_kernel<<<(R * 128) / 256, 256, 0, stream>>>(zb, kp, zpb, R * 128);
        rq_kernel2<<<R / 4, 64, 0, stream>>>(zpb, cb, cbT, cnorm, xqb, idxc, sums);
        zq_nvq_kernel<<<(R * 128) / 256, 256, 0, stream>>>(xqb, zpb, zb, kp, xqb, zq16, sums, R * 128);

        // decoder (bf16 MFMA)
        gemm_mfma_bt<true , true ><<<dim3(R/128,  512/128), 256, 0, stream>>>(zq16, wt0, dec_b[0], dA, R,  512,  128);
        gemm_mfma_bt<true , true ><<<dim3(R/128, 1024/128), 256, 0, stream>>>(dA,   wt1, dec_b[1], dB, R, 1024,  512);
        gemm_mfma_bt<true , true ><<<dim3(R/128, 2048/128), 256, 0, stream>>>(dB,   wt2, dec_b[2], dC, R, 2048, 1024);
        gemm_mfma_bt<false, false><<<dim3(R/128,  768/128), 256, 0, stream>>>(dC,   wt3, dec_b[3], outc, R,  768, 2048);
    }

    finalize_kernel<<<1, 64, 0, stream>>>(sums, out_loss);
}

// Round 7
// 1441.841 us; speedup vs baseline: 2.8285x; 1.3735x over previous
//
#include <hip/hip_runtime.h>
#include <math.h>

#define EPS_F 1e-6f
#define ONE_M_EPS (1.0f - 1e-6f)

typedef __attribute__((ext_vector_type(8))) short s16x8;
typedef __attribute__((ext_vector_type(4))) float f32x4;

__device__ __forceinline__ ushort f2bf(float f) {
    union { float f; unsigned u; } v; v.f = f;
    unsigned u = v.u;
    return (ushort)((u + 0x7FFFu + ((u >> 16) & 1u)) >> 16);
}
__device__ __forceinline__ float bf2f(ushort h) {
    union { unsigned u; float f; } v; v.u = ((unsigned)h) << 16;
    return v.f;
}
__device__ __forceinline__ void split3(float x, ushort& h, ushort& m, ushort& l) {
    h = f2bf(x); float r1 = x - bf2f(h);
    m = f2bf(r1); float r2 = r1 - bf2f(m);
    l = f2bf(r2);
}

#define GLL16(srcp, dstp)                                                     \
    __builtin_amdgcn_global_load_lds(                                         \
        (const __attribute__((address_space(1))) void*)(srcp),                \
        (__attribute__((address_space(3))) void*)(dstp), 16, 0, 0)

// ---------------------------------------------------------------------------
// Split-bf16 MFMA GEMM (encoder, fp32-grade): 6 products (p+q<=2), fp32 acc.
// ---------------------------------------------------------------------------
template<bool RELU, int OUT3>
__global__ __launch_bounds__(256) void gemm_mfma_split(
    const ushort* __restrict__ Ah, const ushort* __restrict__ Am, const ushort* __restrict__ Al,
    const ushort* __restrict__ Wh, const ushort* __restrict__ Wm, const ushort* __restrict__ Wl,
    const float* __restrict__ bias,
    void* __restrict__ C0, void* __restrict__ C1, void* __restrict__ C2,
    int M, int N, int K)
{
    __shared__ __align__(16) ushort As[3][128 * 32];
    __shared__ __align__(16) ushort Bs[3][128 * 32];

    const int tid  = threadIdx.x;
    const int lane = tid & 63;
    const int w    = tid >> 6;
    const int wm   = (w >> 1) * 64;
    const int wn   = (w & 1) * 64;
    const int bm   = blockIdx.x * 128;
    const int bn   = blockIdx.y * 128;

    f32x4 acc[4][4];
#pragma unroll
    for (int i = 0; i < 4; i++)
#pragma unroll
        for (int j = 0; j < 4; j++) acc[i][j] = f32x4{0.f, 0.f, 0.f, 0.f};

    const int c0 = (w * 2) * 64 + lane;
    const int c1 = (w * 2 + 1) * 64 + lane;
    const int r0 = c0 >> 2, k0e = (c0 & 3) * 8;
    const int r1 = c1 >> 2, k1e = (c1 & 3) * 8;

    const size_t a_off0 = (size_t)(bm + r0) * K + k0e;
    const size_t a_off1 = (size_t)(bm + r1) * K + k1e;
    const size_t b_off0 = (size_t)(bn + r0) * K + k0e;
    const size_t b_off1 = (size_t)(bn + r1) * K + k1e;
    const int d0 = (w * 2) * 512;
    const int d1 = (w * 2 + 1) * 512;

    const ushort* Ap[3] = {Ah, Am, Al};
    const ushort* Wp[3] = {Wh, Wm, Wl};

    const int fm = lane & 15;
    const int fk = (lane >> 4) * 8;

    for (int k0 = 0; k0 < K; k0 += 32) {
#pragma unroll
        for (int p = 0; p < 3; p++) {
            GLL16(Ap[p] + a_off0 + k0, &As[p][d0]);
            GLL16(Ap[p] + a_off1 + k0, &As[p][d1]);
            GLL16(Wp[p] + b_off0 + k0, &Bs[p][d0]);
            GLL16(Wp[p] + b_off1 + k0, &Bs[p][d1]);
        }
        __syncthreads();

        s16x8 af[3][4];
#pragma unroll
        for (int p = 0; p < 3; p++)
#pragma unroll
            for (int i = 0; i < 4; i++)
                af[p][i] = *reinterpret_cast<const s16x8*>(&As[p][(wm + i * 16 + fm) * 32 + fk]);

#pragma unroll
        for (int q = 0; q < 3; q++) {
            s16x8 bq[4];
#pragma unroll
            for (int j = 0; j < 4; j++)
                bq[j] = *reinterpret_cast<const s16x8*>(&Bs[q][(wn + j * 16 + fm) * 32 + fk]);
#pragma unroll
            for (int p = 0; p < 3; p++) {
                if (p + q <= 2) {
#pragma unroll
                    for (int i = 0; i < 4; i++)
#pragma unroll
                        for (int j = 0; j < 4; j++)
                            acc[i][j] = __builtin_amdgcn_mfma_f32_16x16x32_bf16(
                                af[p][i], bq[j], acc[i][j], 0, 0, 0);
                }
            }
        }
        __syncthreads();
    }

#pragma unroll
    for (int j = 0; j < 4; j++) {
        const int coln = bn + wn + j * 16 + fm;
        const float bv = bias[coln];
#pragma unroll
        for (int i = 0; i < 4; i++) {
            const int row0 = bm + wm + i * 16 + (lane >> 4) * 4;
#pragma unroll
            for (int r = 0; r < 4; r++) {
                float o = acc[i][j][r] + bv;
                if (RELU) o = fmaxf(o, 0.f);
                const size_t idx = (size_t)(row0 + r) * N + coln;
                if (OUT3) {
                    ushort h, m, l;
                    split3(o, h, m, l);
                    ((ushort*)C0)[idx] = h;
                    ((ushort*)C1)[idx] = m;
                    ((ushort*)C2)[idx] = l;
                } else {
                    ((float*)C0)[idx] = o;
                }
            }
        }
    }
}

// ---------------------------------------------------------------------------
// MFMA bf16 GEMM (decoder, single product)
// ---------------------------------------------------------------------------
template<bool RELU, bool OUT_BF16>
__global__ __launch_bounds__(256) void gemm_mfma_bt(
    const ushort* __restrict__ A, const ushort* __restrict__ WT,
    const float* __restrict__ bias, void* __restrict__ Cv,
    int M, int N, int K)
{
    __shared__ __align__(16) ushort As[128 * 32];
    __shared__ __align__(16) ushort Bs[128 * 32];

    const int tid  = threadIdx.x;
    const int lane = tid & 63;
    const int w    = tid >> 6;
    const int wm   = (w >> 1) * 64;
    const int wn   = (w & 1) * 64;
    const int bm   = blockIdx.x * 128;
    const int bn   = blockIdx.y * 128;

    f32x4 acc[4][4];
#pragma unroll
    for (int i = 0; i < 4; i++)
#pragma unroll
        for (int j = 0; j < 4; j++) acc[i][j] = f32x4{0.f, 0.f, 0.f, 0.f};

    const int c0 = (w * 2) * 64 + lane;
    const int c1 = (w * 2 + 1) * 64 + lane;
    const int r0 = c0 >> 2, k0e = (c0 & 3) * 8;
    const int r1 = c1 >> 2, k1e = (c1 & 3) * 8;

    const ushort* a_src0 = A  + (size_t)(bm + r0) * K + k0e;
    const ushort* a_src1 = A  + (size_t)(bm + r1) * K + k1e;
    const ushort* b_src0 = WT + (size_t)(bn + r0) * K + k0e;
    const ushort* b_src1 = WT + (size_t)(bn + r1) * K + k1e;
    ushort* a_dst0 = &As[(w * 2) * 512];
    ushort* a_dst1 = &As[(w * 2 + 1) * 512];
    ushort* b_dst0 = &Bs[(w * 2) * 512];
    ushort* b_dst1 = &Bs[(w * 2 + 1) * 512];

    const int fm = lane & 15;
    const int fk = (lane >> 4) * 8;

    for (int k0 = 0; k0 < K; k0 += 32) {
        GLL16(a_src0 + k0, a_dst0);
        GLL16(a_src1 + k0, a_dst1);
        GLL16(b_src0 + k0, b_dst0);
        GLL16(b_src1 + k0, b_dst1);
        __syncthreads();

        s16x8 af[4], bfr[4];
#pragma unroll
        for (int i = 0; i < 4; i++)
            af[i] = *reinterpret_cast<const s16x8*>(&As[(wm + i * 16 + fm) * 32 + fk]);
#pragma unroll
        for (int j = 0; j < 4; j++)
            bfr[j] = *reinterpret_cast<const s16x8*>(&Bs[(wn + j * 16 + fm) * 32 + fk]);
#pragma unroll
        for (int i = 0; i < 4; i++)
#pragma unroll
            for (int j = 0; j < 4; j++)
                acc[i][j] = __builtin_amdgcn_mfma_f32_16x16x32_bf16(
                    af[i], bfr[j], acc[i][j], 0, 0, 0);
        __syncthreads();
    }

#pragma unroll
    for (int j = 0; j < 4; j++) {
        const int coln = bn + wn + j * 16 + fm;
        const float bv = bias[coln];
#pragma unroll
        for (int i = 0; i < 4; i++) {
            const int row0 = bm + wm + i * 16 + (lane >> 4) * 4;
#pragma unroll
            for (int r = 0; r < 4; r++) {
                float o = acc[i][j][r] + bv;
                if (RELU) o = fmaxf(o, 0.f);
                if (OUT_BF16)
                    ((ushort*)Cv)[(size_t)(row0 + r) * N + coln] = f2bf(o);
                else
                    ((float*)Cv)[(size_t)(row0 + r) * N + coln] = o;
            }
        }
    }
}

// ---------------------------------------------------------------------------
// Weight prep kernels
// ---------------------------------------------------------------------------
__global__ __launch_bounds__(256) void transpose_to_bf16(
    const float* __restrict__ W, ushort* __restrict__ WT, int K, int N)
{
    __shared__ float t[32][33];
    const int kb = blockIdx.x * 32, nb = blockIdx.y * 32;
    const int tx = threadIdx.x & 31, ty = threadIdx.x >> 5;
#pragma unroll
    for (int i = ty; i < 32; i += 8)
        t[i][tx] = W[(size_t)(kb + i) * N + nb + tx];
    __syncthreads();
#pragma unroll
    for (int i = ty; i < 32; i += 8)
        WT[(size_t)(nb + i) * K + kb + tx] = f2bf(t[tx][i]);
}

__global__ __launch_bounds__(256) void transpose_split_bf16(
    const float* __restrict__ W, ushort* __restrict__ TH,
    ushort* __restrict__ TM, ushort* __restrict__ TL, int K, int N)
{
    __shared__ float t[32][33];
    const int kb = blockIdx.x * 32, nb = blockIdx.y * 32;
    const int tx = threadIdx.x & 31, ty = threadIdx.x >> 5;
#pragma unroll
    for (int i = ty; i < 32; i += 8)
        t[i][tx] = W[(size_t)(kb + i) * N + nb + tx];
    __syncthreads();
#pragma unroll
    for (int i = ty; i < 32; i += 8) {
        ushort h, m, l;
        split3(t[tx][i], h, m, l);
        const size_t idx = (size_t)(nb + i) * K + kb + tx;
        TH[idx] = h; TM[idx] = m; TL[idx] = l;
    }
}

__global__ __launch_bounds__(256) void split_plane_kernel(
    const float* __restrict__ X, ushort* __restrict__ H,
    ushort* __restrict__ M, ushort* __restrict__ L, size_t n)
{
    size_t i = (size_t)blockIdx.x * 256 + threadIdx.x;
    if (i >= n) return;
    ushort h, m, l;
    split3(X[i], h, m, l);
    H[i] = h; M[i] = m; L[i] = l;
}

// ---------------------------------------------------------------------------
// Codebook prep
// ---------------------------------------------------------------------------
__global__ __launch_bounds__(128) void prep_cb_kernel(
    const float* __restrict__ cb, float* __restrict__ cbT, float* __restrict__ cnorm)
{
    int b = blockIdx.x;
    int d = threadIdx.x;
    float v = cb[(size_t)b * 128 + d];
    int l = b >> 8, c = b & 255;
    cbT[((size_t)l * 128 + d) * 256 + c] = v;
    float s = v * v;
#pragma unroll
    for (int off = 32; off > 0; off >>= 1) s += __shfl_down(s, off);
    __shared__ float ps[2];
    if ((d & 63) == 0) ps[d >> 6] = s;
    __syncthreads();
    if (d == 0) cnorm[b] = ps[0] + ps[1];
}

__device__ __forceinline__ float softplusf(float x) {
    return (x > 20.f) ? x : log1pf(expf(x));
}

__global__ void kuma_ab_init(const float* __restrict__ a_raw, const float* __restrict__ b_raw,
                             float* __restrict__ kp)
{
    int t = threadIdx.x;
    if (t < 128) {
        float a = softplusf(a_raw[t]) + EPS_F;
        float b = softplusf(b_raw[t]) + EPS_F;
        kp[t] = a;
        kp[128 + t] = b;
        kp[256 + t] = 1.f / a;
        kp[384 + t] = 1.f / b;
    }
}

__global__ __launch_bounds__(256) void kuma_h_kernel(
    const float* __restrict__ z, const float* __restrict__ kp,
    float* __restrict__ zp, int n)
{
    int i = blockIdx.x * 256 + threadIdx.x;
    if (i >= n) return;
    int col = i & 127;
    float a = kp[col], b = kp[128 + col];
    float zv = z[i];
    float x = 1.f / (1.f + expf(-zv));
    x = fminf(fmaxf(x, EPS_F), ONE_M_EPS);
    float inner = 1.f - powf(x, a);
    inner = fminf(fmaxf(inner, EPS_F), 1.f);
    float y = 1.f - powf(inner, b);
    y = fminf(fmaxf(y, EPS_F), ONE_M_EPS);
    zp[i] = y;
}

// ---------------------------------------------------------------------------
// Residual quantizer v2 — 1 wave/block, 4 rows, 4 codes/thread,
// register-prefetched codebook stream, barrier-free, butterfly argmin.
// Per-level partial loss -> plain store (no contended atomics).
// ---------------------------------------------------------------------------
__global__ __launch_bounds__(64) void rq_kernel2(
    const float* __restrict__ zp, const float* __restrict__ cb,
    const float* __restrict__ cbT, const float* __restrict__ cnorm,
    float* __restrict__ xq, float* __restrict__ idx_out,
    float* __restrict__ prq, int bid0, int nRq)
{
    __shared__ float res[4][128];

    const int t = threadIdx.x;          // 0..63
    const int row0 = blockIdx.x * 4;

#pragma unroll
    for (int j = 0; j < 8; j++) {
        int e = t + j * 64;
        res[e >> 7][e & 127] = zp[(size_t)row0 * 128 + e];
    }
    // single wave: LDS write->read ordering handled by lgkmcnt (no barrier)

    float lsum[4];

#pragma unroll 1
    for (int l = 0; l < 4; l++) {
        const float* cT = cbT + (size_t)l * 32768;

        float acc[4][4];
#pragma unroll
        for (int r = 0; r < 4; r++)
#pragma unroll
            for (int cc = 0; cc < 4; cc++) acc[r][cc] = 0.f;

        float pc[16];
#pragma unroll
        for (int dd = 0; dd < 4; dd++)
#pragma unroll
            for (int cc = 0; cc < 4; cc++)
                pc[dd * 4 + cc] = cT[dd * 256 + cc * 64 + t];

#pragma unroll 2
        for (int d = 0; d < 128; d += 4) {
            float nc[16];
            if (d < 124) {
#pragma unroll
                for (int dd = 0; dd < 4; dd++)
#pragma unroll
                    for (int cc = 0; cc < 4; cc++)
                        nc[dd * 4 + cc] = cT[(d + 4 + dd) * 256 + cc * 64 + t];
            }
#pragma unroll
            for (int r = 0; r < 4; r++) {
                float4 rv = *reinterpret_cast<const float4*>(&res[r][d]);
#pragma unroll
                for (int cc = 0; cc < 4; cc++) {
                    acc[r][cc] += rv.x * pc[cc] + rv.y * pc[4 + cc]
                                + rv.z * pc[8 + cc] + rv.w * pc[12 + cc];
                }
            }
#pragma unroll
            for (int k = 0; k < 16; k++) pc[k] = nc[k];
        }

        float cn[4];
#pragma unroll
        for (int cc = 0; cc < 4; cc++) cn[cc] = cnorm[l * 256 + cc * 64 + t];

        int bidx0, bidx1, bidx2, bidx3;
#pragma unroll
        for (int r = 0; r < 4; r++) {
            float dmin = cn[0] - 2.f * acc[r][0];
            int imin = t;
#pragma unroll
            for (int cc = 1; cc < 4; cc++) {
                float dv = cn[cc] - 2.f * acc[r][cc];
                if (dv < dmin) { dmin = dv; imin = cc * 64 + t; }
            }
#pragma unroll
            for (int off = 1; off < 64; off <<= 1) {
                float d2 = __shfl_xor(dmin, off);
                int i2 = __shfl_xor(imin, off);
                if (d2 < dmin || (d2 == dmin && i2 < imin)) { dmin = d2; imin = i2; }
            }
            if (r == 0) bidx0 = imin;
            else if (r == 1) bidx1 = imin;
            else if (r == 2) bidx2 = imin;
            else bidx3 = imin;
            if (t == 0) idx_out[(size_t)(row0 + r) * 4 + l] = (float)imin;
        }

        float s = 0.f;
#pragma unroll
        for (int j = 0; j < 8; j++) {
            const int r = j >> 1;
            const int d = (j & 1) * 64 + t;
            const int bi = (r == 0) ? bidx0 : (r == 1) ? bidx1 : (r == 2) ? bidx2 : bidx3;
            float q = cb[((size_t)(l * 256) + bi) * 128 + d];
            float nr = res[r][d] - q;
            res[r][d] = nr;
            s += nr * nr;
        }
        lsum[l] = s;
    }

#pragma unroll
    for (int j = 0; j < 8; j++) {
        int e = t + j * 64;
        xq[(size_t)row0 * 128 + e] = zp[(size_t)row0 * 128 + e] - res[e >> 7][e & 127];
    }

    // per-level wave reduce -> plain store (no atomic)
#pragma unroll
    for (int l = 0; l < 4; l++) {
        float s = lsum[l];
#pragma unroll
        for (int off = 32; off > 0; off >>= 1) s += __shfl_down(s, off);
        if (t == 0) prq[(size_t)l * nRq + bid0 + blockIdx.x] = s;
    }
}

// ---------------------------------------------------------------------------
// z_q = h_inv(x_q) (+ bf16 copy);  z_recon = h_inv(z');  nvq partial store
// ---------------------------------------------------------------------------
__device__ __forceinline__ float kuma_h_inv_f(float y, float ia, float ib) {
    y = fminf(fmaxf(y, EPS_F), ONE_M_EPS);
    float omy = fminf(fmaxf(1.f - y, EPS_F), 1.f);
    float inner = fminf(fmaxf(1.f - powf(omy, ib), EPS_F), ONE_M_EPS);
    float x = fminf(fmaxf(powf(inner, ia), EPS_F), ONE_M_EPS);
    return logf(x / (1.f - x));
}

__global__ __launch_bounds__(256) void zq_nvq_kernel(
    const float* __restrict__ xq, const float* __restrict__ zp,
    const float* __restrict__ z, const float* __restrict__ kp,
    float* __restrict__ zq, ushort* __restrict__ zq16,
    float* __restrict__ pnvq, int bid0, int n)
{
    int i = blockIdx.x * 256 + threadIdx.x;
    float ds = 0.f;
    if (i < n) {
        int col = i & 127;
        float ia = kp[256 + col], ib = kp[384 + col];
        float xv = xq[i];
        float zpv = zp[i];
        float zv = z[i];
        float zr = kuma_h_inv_f(zpv, ia, ib);
        float d = zr - zv;
        ds = d * d;
        float zqv = kuma_h_inv_f(xv, ia, ib);
        zq[i] = zqv;
        zq16[i] = f2bf(zqv);
    }
#pragma unroll
    for (int off = 32; off > 0; off >>= 1) ds += __shfl_down(ds, off);
    __shared__ float ps[4];
    if ((threadIdx.x & 63) == 0) ps[threadIdx.x >> 6] = ds;
    __syncthreads();
    if (threadIdx.x == 0)
        pnvq[bid0 + blockIdx.x] = ps[0] + ps[1] + ps[2] + ps[3];
}

// ---------------------------------------------------------------------------
// Final loss: sum rq partials (nRq*4) and nvq partials (nNvq)
// ---------------------------------------------------------------------------
__global__ __launch_bounds__(256) void finalize_kernel(
    const float* __restrict__ prq, const float* __restrict__ pnvq,
    int nRqAll, int nNvq, float* __restrict__ out_loss)
{
    const int t = threadIdx.x;
    float srq = 0.f, snvq = 0.f;
    for (int i = t; i < nRqAll; i += 256) srq += prq[i];
    for (int i = t; i < nNvq; i += 256) snvq += pnvq[i];
#pragma unroll
    for (int off = 32; off > 0; off >>= 1) {
        srq += __shfl_down(srq, off);
        snvq += __shfl_down(snvq, off);
    }
    __shared__ float pr[4], pn[4];
    if ((t & 63) == 0) { pr[t >> 6] = srq; pn[t >> 6] = snvq; }
    __syncthreads();
    if (t == 0) {
        const float inv = 1.f / (16384.f * 128.f);
        float rq = (pr[0] + pr[1] + pr[2] + pr[3]);
        float nv = (pn[0] + pn[1] + pn[2] + pn[3]);
        out_loss[0] = 0.3125f * rq * inv + nv * inv;  // 0.25*1.25*S_rq + S_nvq
    }
}

// ---------------------------------------------------------------------------
// Launcher
// ---------------------------------------------------------------------------
extern "C" void kernel_launch(void* const* d_in, const int* in_sizes, int n_in,
                              void* d_out, int out_size, void* d_ws, size_t ws_size,
                              hipStream_t stream)
{
    constexpr int B = 16384;

    const float* x = (const float*)d_in[0];
    const float* enc_w[4]; const float* enc_b[4];
    const float* dec_w[4]; const float* dec_b[4];
    for (int i = 0; i < 4; i++) {
        enc_w[i] = (const float*)d_in[1 + 4 * i];
        enc_b[i] = (const float*)d_in[2 + 4 * i];
        dec_w[i] = (const float*)d_in[3 + 4 * i];
        dec_b[i] = (const float*)d_in[4 + 4 * i];
    }
    const float* cb    = (const float*)d_in[17];
    const float* a_raw = (const float*)d_in[18];
    const float* b_raw = (const float*)d_in[19];

    // chunk size
    size_t avail = ws_size / 4;
    const size_t fixed_f = 8652296 + 24576 + 64;
    int R = 16384;
    while (R > 256 && (size_t)R * 5056 + fixed_f > avail) R >>= 1;

    // carve (floats)
    float* ws    = (float*)d_ws;
    float* slotA = ws;                         // R*1536
    float* slotB = slotA + (size_t)R * 1536;   // R*3072
    float* zb    = slotB + (size_t)R * 3072;   // R*128
    float* zpb   = zb  + (size_t)R * 128;      // R*128
    float* xqb   = zpb + (size_t)R * 128;      // R*128
    float* zq16f = xqb + (size_t)R * 128;      // R*64 (ushort R*128)
    float* fixp  = zq16f + (size_t)R * 64;

    ushort* ew = (ushort*)fixp;
    ushort* e0h = ew;                ushort* e0m = e0h + 1572864; ushort* e0l = e0m + 1572864;
    ushort* e1h = e0l + 1572864;     ushort* e1m = e1h + 2097152; ushort* e1l = e1m + 2097152;
    ushort* e2h = e1l + 2097152;     ushort* e2m = e2h + 524288;  ushort* e2l = e2m + 524288;
    ushort* e3h = e2l + 524288;      ushort* e3m = e3h + 65536;   ushort* e3l = e3m + 65536;
    ushort* wt0 = e3l + 65536;
    ushort* wt1 = wt0 + 65536;
    ushort* wt2 = wt1 + 524288;
    ushort* wt3 = wt2 + 2097152;
    float* cbT   = (float*)(wt3 + 1572864);
    float* cnorm = cbT + 4 * 128 * 256;
    float* kp    = cnorm + 4 * 256;
    float* prq   = kp + 512;              // 4 * (B/4) = 16384
    float* pnvq  = prq + 16384;           // B*128/256 = 8192
    // total fixed ≈ 8652296 + 24576

    ushort* zq16 = (ushort*)zq16f;

    ushort* xH  = (ushort*)slotA;  ushort* xM  = xH  + (size_t)R * 768;  ushort* xL  = xM  + (size_t)R * 768;
    ushort* h0H = (ushort*)slotB;  ushort* h0M = h0H + (size_t)R * 2048; ushort* h0L = h0M + (size_t)R * 2048;
    ushort* h1H = (ushort*)slotA;  ushort* h1M = h1H + (size_t)R * 1024; ushort* h1L = h1M + (size_t)R * 1024;
    ushort* h2H = (ushort*)slotB;  ushort* h2M = h2H + (size_t)R * 512;  ushort* h2L = h2M + (size_t)R * 512;

    ushort* dA = (ushort*)slotB;
    ushort* dB = (ushort*)(slotB + (size_t)R * 256);
    ushort* dC = (ushort*)slotA;

    float* out      = (float*)d_out;
    float* out_loss = out + (size_t)B * 768;
    float* out_idx  = out_loss + 1;

    // prep (once per launch)
    prep_cb_kernel<<<1024, 128, 0, stream>>>(cb, cbT, cnorm);
    kuma_ab_init<<<1, 128, 0, stream>>>(a_raw, b_raw, kp);
    transpose_split_bf16<<<dim3( 768/32, 2048/32), 256, 0, stream>>>(enc_w[0], e0h, e0m, e0l,  768, 2048);
    transpose_split_bf16<<<dim3(2048/32, 1024/32), 256, 0, stream>>>(enc_w[1], e1h, e1m, e1l, 2048, 1024);
    transpose_split_bf16<<<dim3(1024/32,  512/32), 256, 0, stream>>>(enc_w[2], e2h, e2m, e2l, 1024,  512);
    transpose_split_bf16<<<dim3( 512/32,  128/32), 256, 0, stream>>>(enc_w[3], e3h, e3m, e3l,  512,  128);
    transpose_to_bf16<<<dim3(128/32,  512/32), 256, 0, stream>>>(dec_w[0], wt0,  128,  512);
    transpose_to_bf16<<<dim3(512/32, 1024/32), 256, 0, stream>>>(dec_w[1], wt1,  512, 1024);
    transpose_to_bf16<<<dim3(1024/32,2048/32), 256, 0, stream>>>(dec_w[2], wt2, 1024, 2048);
    transpose_to_bf16<<<dim3(2048/32, 768/32), 256, 0, stream>>>(dec_w[3], wt3, 2048,  768);

    const int nc = B / R;
    const int nRq = B / 4;                 // rq blocks total
    const int rqPerChunk = R / 4;
    const int nvqPerChunk = (R * 128) / 256;
    for (int c = 0; c < nc; c++) {
        const size_t base = (size_t)c * R;
        const float* xc = x + base * 768;
        float* outc = out + base * 768;
        float* idxc = out_idx + base * 4;

        {
            size_t n = (size_t)R * 768;
            split_plane_kernel<<<(unsigned)((n + 255) / 256), 256, 0, stream>>>(xc, xH, xM, xL, n);
        }

        // encoder (split-bf16 MFMA, fp32-grade)
        gemm_mfma_split<true , 1><<<dim3(R/128, 16), 256, 0, stream>>>(
            xH, xM, xL, e0h, e0m, e0l, enc_b[0], h0H, h0M, h0L, R, 2048, 768);
        gemm_mfma_split<true , 1><<<dim3(R/128,  8), 256, 0, stream>>>(
            h0H, h0M, h0L, e1h, e1m, e1l, enc_b[1], h1H, h1M, h1L, R, 1024, 2048);
        gemm_mfma_split<true , 1><<<dim3(R/128,  4), 256, 0, stream>>>(
            h1H, h1M, h1L, e2h, e2m, e2l, enc_b[2], h2H, h2M, h2L, R,  512, 1024);
        gemm_mfma_split<false, 0><<<dim3(R/128,  1), 256, 0, stream>>>(
            h2H, h2M, h2L, e3h, e3m, e3l, enc_b[3], zb, nullptr, nullptr, R, 128, 512);

        // kuma + RQ + inverse + losses (fp32)
        kuma_h_kernel<<<(R * 128) / 256, 256, 0, stream>>>(zb, kp, zpb, R * 128);
        rq_kernel2<<<rqPerChunk, 64, 0, stream>>>(zpb, cb, cbT, cnorm, xqb, idxc,
                                                  prq, c * rqPerChunk, nRq);
        zq_nvq_kernel<<<nvqPerChunk, 256, 0, stream>>>(xqb, zpb, zb, kp, xqb, zq16,
                                                       pnvq, c * nvqPerChunk, R * 128);

        // decoder (bf16 MFMA)
        gemm_mfma_bt<true , true ><<<dim3(R/128,  512/128), 256, 0, stream>>>(zq16, wt0, dec_b[0], dA, R,  512,  128);
        gemm_mfma_bt<true , true ><<<dim3(R/128, 1024/128), 256, 0, stream>>>(dA,   wt1, dec_b[1], dB, R, 1024,  512);
        gemm_mfma_bt<true , true ><<<dim3(R/128, 2048/128), 256, 0, stream>>>(dB,   wt2, dec_b[2], dC, R, 2048, 1024);
        gemm_mfma_bt<false, false><<<dim3(R/128,  768/128), 256, 0, stream>>>(dC,   wt3, dec_b[3], outc, R,  768, 2048);
    }

    finalize_kernel<<<1, 256, 0, stream>>>(prq, pnvq, 4 * nRq, B * 128 / 256, out_loss);
}

// Round 8
// 1422.333 us; speedup vs baseline: 2.8673x; 1.0137x over previous
//
#include <hip/hip_runtime.h>
#include <math.h>

#define EPS_F 1e-6f
#define ONE_M_EPS (1.0f - 1e-6f)

typedef __attribute__((ext_vector_type(8))) short s16x8;
typedef __attribute__((ext_vector_type(4))) float f32x4;

__device__ __forceinline__ ushort f2bf(float f) {
    union { float f; unsigned u; } v; v.f = f;
    unsigned u = v.u;
    return (ushort)((u + 0x7FFFu + ((u >> 16) & 1u)) >> 16);
}
__device__ __forceinline__ float bf2f(ushort h) {
    union { unsigned u; float f; } v; v.u = ((unsigned)h) << 16;
    return v.f;
}
__device__ __forceinline__ void split3(float x, ushort& h, ushort& m, ushort& l) {
    h = f2bf(x); float r1 = x - bf2f(h);
    m = f2bf(r1); float r2 = r1 - bf2f(m);
    l = f2bf(r2);
}

#define GLL16(srcp, dstp)                                                     \
    __builtin_amdgcn_global_load_lds(                                         \
        (const __attribute__((address_space(1))) void*)(srcp),                \
        (__attribute__((address_space(3))) void*)(dstp), 16, 0, 0)

// Bank-conflict swizzle (16B-chunk granularity, rule #21: swizzle source+read,
// LDS stays linear for global_load_lds):  k_phys = k_log ^ ((row>>1)&3)
__device__ __forceinline__ int swz_k(int row, int k) { return k ^ ((row >> 1) & 3); }

// ---------------------------------------------------------------------------
// Split-bf16 MFMA GEMM (encoder, fp32-grade): 6 products (p+q<=2), fp32 acc.
// ---------------------------------------------------------------------------
template<bool RELU, int OUT3>
__global__ __launch_bounds__(256) void gemm_mfma_split(
    const ushort* __restrict__ Ah, const ushort* __restrict__ Am, const ushort* __restrict__ Al,
    const ushort* __restrict__ Wh, const ushort* __restrict__ Wm, const ushort* __restrict__ Wl,
    const float* __restrict__ bias,
    void* __restrict__ C0, void* __restrict__ C1, void* __restrict__ C2,
    int M, int N, int K)
{
    __shared__ __align__(16) ushort As[3][128 * 32];
    __shared__ __align__(16) ushort Bs[3][128 * 32];

    const int tid  = threadIdx.x;
    const int lane = tid & 63;
    const int w    = tid >> 6;
    const int wm   = (w >> 1) * 64;
    const int wn   = (w & 1) * 64;
    const int bm   = blockIdx.x * 128;
    const int bn   = blockIdx.y * 128;

    f32x4 acc[4][4];
#pragma unroll
    for (int i = 0; i < 4; i++)
#pragma unroll
        for (int j = 0; j < 4; j++) acc[i][j] = f32x4{0.f, 0.f, 0.f, 0.f};

    // staging: physical chunk c -> row c>>2, k-block c&3; source k pre-swizzled
    const int c0 = (w * 2) * 64 + lane;
    const int c1 = (w * 2 + 1) * 64 + lane;
    const int r0 = c0 >> 2, k0e = swz_k(r0, c0 & 3) * 8;
    const int r1 = c1 >> 2, k1e = swz_k(r1, c1 & 3) * 8;

    const size_t a_off0 = (size_t)(bm + r0) * K + k0e;
    const size_t a_off1 = (size_t)(bm + r1) * K + k1e;
    const size_t b_off0 = (size_t)(bn + r0) * K + k0e;
    const size_t b_off1 = (size_t)(bn + r1) * K + k1e;
    const int d0 = (w * 2) * 512;
    const int d1 = (w * 2 + 1) * 512;

    const ushort* Ap[3] = {Ah, Am, Al};
    const ushort* Wp[3] = {Wh, Wm, Wl};

    const int fm  = lane & 15;
    const int fkb = lane >> 4;   // logical k-block 0..3

    for (int k0 = 0; k0 < K; k0 += 32) {
#pragma unroll
        for (int p = 0; p < 3; p++) {
            GLL16(Ap[p] + a_off0 + k0, &As[p][d0]);
            GLL16(Ap[p] + a_off1 + k0, &As[p][d1]);
            GLL16(Wp[p] + b_off0 + k0, &Bs[p][d0]);
            GLL16(Wp[p] + b_off1 + k0, &Bs[p][d1]);
        }
        __syncthreads();

        s16x8 af[3][4];
#pragma unroll
        for (int p = 0; p < 3; p++)
#pragma unroll
            for (int i = 0; i < 4; i++) {
                const int row = wm + i * 16 + fm;
                af[p][i] = *reinterpret_cast<const s16x8*>(
                    &As[p][row * 32 + swz_k(row, fkb) * 8]);
            }

#pragma unroll
        for (int q = 0; q < 3; q++) {
            s16x8 bq[4];
#pragma unroll
            for (int j = 0; j < 4; j++) {
                const int row = wn + j * 16 + fm;
                bq[j] = *reinterpret_cast<const s16x8*>(
                    &Bs[q][row * 32 + swz_k(row, fkb) * 8]);
            }
#pragma unroll
            for (int p = 0; p < 3; p++) {
                if (p + q <= 2) {
#pragma unroll
                    for (int i = 0; i < 4; i++)
#pragma unroll
                        for (int j = 0; j < 4; j++)
                            acc[i][j] = __builtin_amdgcn_mfma_f32_16x16x32_bf16(
                                af[p][i], bq[j], acc[i][j], 0, 0, 0);
                }
            }
        }
        __syncthreads();
    }

#pragma unroll
    for (int j = 0; j < 4; j++) {
        const int coln = bn + wn + j * 16 + fm;
        const float bv = bias[coln];
#pragma unroll
        for (int i = 0; i < 4; i++) {
            const int row0 = bm + wm + i * 16 + (lane >> 4) * 4;
#pragma unroll
            for (int r = 0; r < 4; r++) {
                float o = acc[i][j][r] + bv;
                if (RELU) o = fmaxf(o, 0.f);
                const size_t idx = (size_t)(row0 + r) * N + coln;
                if (OUT3) {
                    ushort h, m, l;
                    split3(o, h, m, l);
                    ((ushort*)C0)[idx] = h;
                    ((ushort*)C1)[idx] = m;
                    ((ushort*)C2)[idx] = l;
                } else {
                    ((float*)C0)[idx] = o;
                }
            }
        }
    }
}

// ---------------------------------------------------------------------------
// MFMA bf16 GEMM (decoder, single product), same swizzle
// ---------------------------------------------------------------------------
template<bool RELU, bool OUT_BF16>
__global__ __launch_bounds__(256) void gemm_mfma_bt(
    const ushort* __restrict__ A, const ushort* __restrict__ WT,
    const float* __restrict__ bias, void* __restrict__ Cv,
    int M, int N, int K)
{
    __shared__ __align__(16) ushort As[128 * 32];
    __shared__ __align__(16) ushort Bs[128 * 32];

    const int tid  = threadIdx.x;
    const int lane = tid & 63;
    const int w    = tid >> 6;
    const int wm   = (w >> 1) * 64;
    const int wn   = (w & 1) * 64;
    const int bm   = blockIdx.x * 128;
    const int bn   = blockIdx.y * 128;

    f32x4 acc[4][4];
#pragma unroll
    for (int i = 0; i < 4; i++)
#pragma unroll
        for (int j = 0; j < 4; j++) acc[i][j] = f32x4{0.f, 0.f, 0.f, 0.f};

    const int c0 = (w * 2) * 64 + lane;
    const int c1 = (w * 2 + 1) * 64 + lane;
    const int r0 = c0 >> 2, k0e = swz_k(r0, c0 & 3) * 8;
    const int r1 = c1 >> 2, k1e = swz_k(r1, c1 & 3) * 8;

    const ushort* a_src0 = A  + (size_t)(bm + r0) * K + k0e;
    const ushort* a_src1 = A  + (size_t)(bm + r1) * K + k1e;
    const ushort* b_src0 = WT + (size_t)(bn + r0) * K + k0e;
    const ushort* b_src1 = WT + (size_t)(bn + r1) * K + k1e;
    ushort* a_dst0 = &As[(w * 2) * 512];
    ushort* a_dst1 = &As[(w * 2 + 1) * 512];
    ushort* b_dst0 = &Bs[(w * 2) * 512];
    ushort* b_dst1 = &Bs[(w * 2 + 1) * 512];

    const int fm  = lane & 15;
    const int fkb = lane >> 4;

    for (int k0 = 0; k0 < K; k0 += 32) {
        GLL16(a_src0 + k0, a_dst0);
        GLL16(a_src1 + k0, a_dst1);
        GLL16(b_src0 + k0, b_dst0);
        GLL16(b_src1 + k0, b_dst1);
        __syncthreads();

        s16x8 af[4], bfr[4];
#pragma unroll
        for (int i = 0; i < 4; i++) {
            const int row = wm + i * 16 + fm;
            af[i] = *reinterpret_cast<const s16x8*>(&As[row * 32 + swz_k(row, fkb) * 8]);
        }
#pragma unroll
        for (int j = 0; j < 4; j++) {
            const int row = wn + j * 16 + fm;
            bfr[j] = *reinterpret_cast<const s16x8*>(&Bs[row * 32 + swz_k(row, fkb) * 8]);
        }
#pragma unroll
        for (int i = 0; i < 4; i++)
#pragma unroll
            for (int j = 0; j < 4; j++)
                acc[i][j] = __builtin_amdgcn_mfma_f32_16x16x32_bf16(
                    af[i], bfr[j], acc[i][j], 0, 0, 0);
        __syncthreads();
    }

#pragma unroll
    for (int j = 0; j < 4; j++) {
        const int coln = bn + wn + j * 16 + fm;
        const float bv = bias[coln];
#pragma unroll
        for (int i = 0; i < 4; i++) {
            const int row0 = bm + wm + i * 16 + (lane >> 4) * 4;
#pragma unroll
            for (int r = 0; r < 4; r++) {
                float o = acc[i][j][r] + bv;
                if (RELU) o = fmaxf(o, 0.f);
                if (OUT_BF16)
                    ((ushort*)Cv)[(size_t)(row0 + r) * N + coln] = f2bf(o);
                else
                    ((float*)Cv)[(size_t)(row0 + r) * N + coln] = o;
            }
        }
    }
}

// ---------------------------------------------------------------------------
// Weight prep kernels
// ---------------------------------------------------------------------------
__global__ __launch_bounds__(256) void transpose_to_bf16(
    const float* __restrict__ W, ushort* __restrict__ WT, int K, int N)
{
    __shared__ float t[32][33];
    const int kb = blockIdx.x * 32, nb = blockIdx.y * 32;
    const int tx = threadIdx.x & 31, ty = threadIdx.x >> 5;
#pragma unroll
    for (int i = ty; i < 32; i += 8)
        t[i][tx] = W[(size_t)(kb + i) * N + nb + tx];
    __syncthreads();
#pragma unroll
    for (int i = ty; i < 32; i += 8)
        WT[(size_t)(nb + i) * K + kb + tx] = f2bf(t[tx][i]);
}

__global__ __launch_bounds__(256) void transpose_split_bf16(
    const float* __restrict__ W, ushort* __restrict__ TH,
    ushort* __restrict__ TM, ushort* __restrict__ TL, int K, int N)
{
    __shared__ float t[32][33];
    const int kb = blockIdx.x * 32, nb = blockIdx.y * 32;
    const int tx = threadIdx.x & 31, ty = threadIdx.x >> 5;
#pragma unroll
    for (int i = ty; i < 32; i += 8)
        t[i][tx] = W[(size_t)(kb + i) * N + nb + tx];
    __syncthreads();
#pragma unroll
    for (int i = ty; i < 32; i += 8) {
        ushort h, m, l;
        split3(t[tx][i], h, m, l);
        const size_t idx = (size_t)(nb + i) * K + kb + tx;
        TH[idx] = h; TM[idx] = m; TL[idx] = l;
    }
}

__global__ __launch_bounds__(256) void split_plane_kernel(
    const float* __restrict__ X, ushort* __restrict__ H,
    ushort* __restrict__ M, ushort* __restrict__ L, size_t n)
{
    size_t i = (size_t)blockIdx.x * 256 + threadIdx.x;
    if (i >= n) return;
    ushort h, m, l;
    split3(X[i], h, m, l);
    H[i] = h; M[i] = m; L[i] = l;
}

// ---------------------------------------------------------------------------
// Codebook prep
// ---------------------------------------------------------------------------
__global__ __launch_bounds__(128) void prep_cb_kernel(
    const float* __restrict__ cb, float* __restrict__ cbT, float* __restrict__ cnorm)
{
    int b = blockIdx.x;
    int d = threadIdx.x;
    float v = cb[(size_t)b * 128 + d];
    int l = b >> 8, c = b & 255;
    cbT[((size_t)l * 128 + d) * 256 + c] = v;
    float s = v * v;
#pragma unroll
    for (int off = 32; off > 0; off >>= 1) s += __shfl_down(s, off);
    __shared__ float ps[2];
    if ((d & 63) == 0) ps[d >> 6] = s;
    __syncthreads();
    if (d == 0) cnorm[b] = ps[0] + ps[1];
}

__device__ __forceinline__ float softplusf(float x) {
    return (x > 20.f) ? x : log1pf(expf(x));
}

__global__ void kuma_ab_init(const float* __restrict__ a_raw, const float* __restrict__ b_raw,
                             float* __restrict__ kp)
{
    int t = threadIdx.x;
    if (t < 128) {
        float a = softplusf(a_raw[t]) + EPS_F;
        float b = softplusf(b_raw[t]) + EPS_F;
        kp[t] = a;
        kp[128 + t] = b;
        kp[256 + t] = 1.f / a;
        kp[384 + t] = 1.f / b;
    }
}

__global__ __launch_bounds__(256) void kuma_h_kernel(
    const float* __restrict__ z, const float* __restrict__ kp,
    float* __restrict__ zp, int n)
{
    int i = blockIdx.x * 256 + threadIdx.x;
    if (i >= n) return;
    int col = i & 127;
    float a = kp[col], b = kp[128 + col];
    float zv = z[i];
    float x = 1.f / (1.f + expf(-zv));
    x = fminf(fmaxf(x, EPS_F), ONE_M_EPS);
    float inner = 1.f - powf(x, a);
    inner = fminf(fmaxf(inner, EPS_F), 1.f);
    float y = 1.f - powf(inner, b);
    y = fminf(fmaxf(y, EPS_F), ONE_M_EPS);
    zp[i] = y;
}

// ---------------------------------------------------------------------------
// Residual quantizer v2 — 1 wave/block, 4 rows, 4 codes/thread,
// register-prefetched codebook stream, barrier-free, butterfly argmin.
// ---------------------------------------------------------------------------
__global__ __launch_bounds__(64) void rq_kernel2(
    const float* __restrict__ zp, const float* __restrict__ cb,
    const float* __restrict__ cbT, const float* __restrict__ cnorm,
    float* __restrict__ xq, float* __restrict__ idx_out,
    float* __restrict__ prq, int bid0, int nRq)
{
    __shared__ float res[4][128];

    const int t = threadIdx.x;          // 0..63
    const int row0 = blockIdx.x * 4;

#pragma unroll
    for (int j = 0; j < 8; j++) {
        int e = t + j * 64;
        res[e >> 7][e & 127] = zp[(size_t)row0 * 128 + e];
    }
    // single wave: LDS write->read ordering handled by lgkmcnt (no barrier)

    float lsum[4];

#pragma unroll 1
    for (int l = 0; l < 4; l++) {
        const float* cT = cbT + (size_t)l * 32768;

        float acc[4][4];
#pragma unroll
        for (int r = 0; r < 4; r++)
#pragma unroll
            for (int cc = 0; cc < 4; cc++) acc[r][cc] = 0.f;

        float pc[16];
#pragma unroll
        for (int dd = 0; dd < 4; dd++)
#pragma unroll
            for (int cc = 0; cc < 4; cc++)
                pc[dd * 4 + cc] = cT[dd * 256 + cc * 64 + t];

#pragma unroll 2
        for (int d = 0; d < 128; d += 4) {
            float nc[16];
            if (d < 124) {
#pragma unroll
                for (int dd = 0; dd < 4; dd++)
#pragma unroll
                    for (int cc = 0; cc < 4; cc++)
                        nc[dd * 4 + cc] = cT[(d + 4 + dd) * 256 + cc * 64 + t];
            }
#pragma unroll
            for (int r = 0; r < 4; r++) {
                float4 rv = *reinterpret_cast<const float4*>(&res[r][d]);
#pragma unroll
                for (int cc = 0; cc < 4; cc++) {
                    acc[r][cc] += rv.x * pc[cc] + rv.y * pc[4 + cc]
                                + rv.z * pc[8 + cc] + rv.w * pc[12 + cc];
                }
            }
#pragma unroll
            for (int k = 0; k < 16; k++) pc[k] = nc[k];
        }

        float cn[4];
#pragma unroll
        for (int cc = 0; cc < 4; cc++) cn[cc] = cnorm[l * 256 + cc * 64 + t];

        int bidx0, bidx1, bidx2, bidx3;
#pragma unroll
        for (int r = 0; r < 4; r++) {
            float dmin = cn[0] - 2.f * acc[r][0];
            int imin = t;
#pragma unroll
            for (int cc = 1; cc < 4; cc++) {
                float dv = cn[cc] - 2.f * acc[r][cc];
                if (dv < dmin) { dmin = dv; imin = cc * 64 + t; }
            }
#pragma unroll
            for (int off = 1; off < 64; off <<= 1) {
                float d2 = __shfl_xor(dmin, off);
                int i2 = __shfl_xor(imin, off);
                if (d2 < dmin || (d2 == dmin && i2 < imin)) { dmin = d2; imin = i2; }
            }
            if (r == 0) bidx0 = imin;
            else if (r == 1) bidx1 = imin;
            else if (r == 2) bidx2 = imin;
            else bidx3 = imin;
            if (t == 0) idx_out[(size_t)(row0 + r) * 4 + l] = (float)imin;
        }

        float s = 0.f;
#pragma unroll
        for (int j = 0; j < 8; j++) {
            const int r = j >> 1;
            const int d = (j & 1) * 64 + t;
            const int bi = (r == 0) ? bidx0 : (r == 1) ? bidx1 : (r == 2) ? bidx2 : bidx3;
            float q = cb[((size_t)(l * 256) + bi) * 128 + d];
            float nr = res[r][d] - q;
            res[r][d] = nr;
            s += nr * nr;
        }
        lsum[l] = s;
    }

#pragma unroll
    for (int j = 0; j < 8; j++) {
        int e = t + j * 64;
        xq[(size_t)row0 * 128 + e] = zp[(size_t)row0 * 128 + e] - res[e >> 7][e & 127];
    }

    // per-level wave reduce -> plain store (no atomic)
#pragma unroll
    for (int l = 0; l < 4; l++) {
        float s = lsum[l];
#pragma unroll
        for (int off = 32; off > 0; off >>= 1) s += __shfl_down(s, off);
        if (t == 0) prq[(size_t)l * nRq + bid0 + blockIdx.x] = s;
    }
}

// ---------------------------------------------------------------------------
// z_q = h_inv(x_q) (+ bf16 copy);  z_recon = h_inv(z');  nvq partial store
// ---------------------------------------------------------------------------
__device__ __forceinline__ float kuma_h_inv_f(float y, float ia, float ib) {
    y = fminf(fmaxf(y, EPS_F), ONE_M_EPS);
    float omy = fminf(fmaxf(1.f - y, EPS_F), 1.f);
    float inner = fminf(fmaxf(1.f - powf(omy, ib), EPS_F), ONE_M_EPS);
    float x = fminf(fmaxf(powf(inner, ia), EPS_F), ONE_M_EPS);
    return logf(x / (1.f - x));
}

__global__ __launch_bounds__(256) void zq_nvq_kernel(
    const float* __restrict__ xq, const float* __restrict__ zp,
    const float* __restrict__ z, const float* __restrict__ kp,
    float* __restrict__ zq, ushort* __restrict__ zq16,
    float* __restrict__ pnvq, int bid0, int n)
{
    int i = blockIdx.x * 256 + threadIdx.x;
    float ds = 0.f;
    if (i < n) {
        int col = i & 127;
        float ia = kp[256 + col], ib = kp[384 + col];
        float xv = xq[i];
        float zpv = zp[i];
        float zv = z[i];
        float zr = kuma_h_inv_f(zpv, ia, ib);
        float d = zr - zv;
        ds = d * d;
        float zqv = kuma_h_inv_f(xv, ia, ib);
        zq[i] = zqv;
        zq16[i] = f2bf(zqv);
    }
#pragma unroll
    for (int off = 32; off > 0; off >>= 1) ds += __shfl_down(ds, off);
    __shared__ float ps[4];
    if ((threadIdx.x & 63) == 0) ps[threadIdx.x >> 6] = ds;
    __syncthreads();
    if (threadIdx.x == 0)
        pnvq[bid0 + blockIdx.x] = ps[0] + ps[1] + ps[2] + ps[3];
}

// ---------------------------------------------------------------------------
// Final loss: sum rq partials (nRq*4) and nvq partials (nNvq)
// ---------------------------------------------------------------------------
__global__ __launch_bounds__(256) void finalize_kernel(
    const float* __restrict__ prq, const float* __restrict__ pnvq,
    int nRqAll, int nNvq, float* __restrict__ out_loss)
{
    const int t = threadIdx.x;
    float srq = 0.f, snvq = 0.f;
    for (int i = t; i < nRqAll; i += 256) srq += prq[i];
    for (int i = t; i < nNvq; i += 256) snvq += pnvq[i];
#pragma unroll
    for (int off = 32; off > 0; off >>= 1) {
        srq += __shfl_down(srq, off);
        snvq += __shfl_down(snvq, off);
    }
    __shared__ float pr[4], pn[4];
    if ((t & 63) == 0) { pr[t >> 6] = srq; pn[t >> 6] = snvq; }
    __syncthreads();
    if (t == 0) {
        const float inv = 1.f / (16384.f * 128.f);
        float rq = (pr[0] + pr[1] + pr[2] + pr[3]);
        float nv = (pn[0] + pn[1] + pn[2] + pn[3]);
        out_loss[0] = 0.3125f * rq * inv + nv * inv;  // 0.25*1.25*S_rq + S_nvq
    }
}

// ---------------------------------------------------------------------------
// Launcher
// ---------------------------------------------------------------------------
extern "C" void kernel_launch(void* const* d_in, const int* in_sizes, int n_in,
                              void* d_out, int out_size, void* d_ws, size_t ws_size,
                              hipStream_t stream)
{
    constexpr int B = 16384;

    const float* x = (const float*)d_in[0];
    const float* enc_w[4]; const float* enc_b[4];
    const float* dec_w[4]; const float* dec_b[4];
    for (int i = 0; i < 4; i++) {
        enc_w[i] = (const float*)d_in[1 + 4 * i];
        enc_b[i] = (const float*)d_in[2 + 4 * i];
        dec_w[i] = (const float*)d_in[3 + 4 * i];
        dec_b[i] = (const float*)d_in[4 + 4 * i];
    }
    const float* cb    = (const float*)d_in[17];
    const float* a_raw = (const float*)d_in[18];
    const float* b_raw = (const float*)d_in[19];

    // chunk size
    size_t avail = ws_size / 4;
    const size_t fixed_f = 8652296 + 24576 + 64;
    int R = 16384;
    while (R > 256 && (size_t)R * 5056 + fixed_f > avail) R >>= 1;

    // carve (floats)
    float* ws    = (float*)d_ws;
    float* slotA = ws;                         // R*1536
    float* slotB = slotA + (size_t)R * 1536;   // R*3072
    float* zb    = slotB + (size_t)R * 3072;   // R*128
    float* zpb   = zb  + (size_t)R * 128;      // R*128
    float* xqb   = zpb + (size_t)R * 128;      // R*128
    float* zq16f = xqb + (size_t)R * 128;      // R*64 (ushort R*128)
    float* fixp  = zq16f + (size_t)R * 64;

    ushort* ew = (ushort*)fixp;
    ushort* e0h = ew;                ushort* e0m = e0h + 1572864; ushort* e0l = e0m + 1572864;
    ushort* e1h = e0l + 1572864;     ushort* e1m = e1h + 2097152; ushort* e1l = e1m + 2097152;
    ushort* e2h = e1l + 2097152;     ushort* e2m = e2h + 524288;  ushort* e2l = e2m + 524288;
    ushort* e3h = e2l + 524288;      ushort* e3m = e3h + 65536;   ushort* e3l = e3m + 65536;
    ushort* wt0 = e3l + 65536;
    ushort* wt1 = wt0 + 65536;
    ushort* wt2 = wt1 + 524288;
    ushort* wt3 = wt2 + 2097152;
    float* cbT   = (float*)(wt3 + 1572864);
    float* cnorm = cbT + 4 * 128 * 256;
    float* kp    = cnorm + 4 * 256;
    float* prq   = kp + 512;              // 4 * (B/4) = 16384
    float* pnvq  = prq + 16384;           // B*128/256 = 8192

    ushort* zq16 = (ushort*)zq16f;

    ushort* xH  = (ushort*)slotA;  ushort* xM  = xH  + (size_t)R * 768;  ushort* xL  = xM  + (size_t)R * 768;
    ushort* h0H = (ushort*)slotB;  ushort* h0M = h0H + (size_t)R * 2048; ushort* h0L = h0M + (size_t)R * 2048;
    ushort* h1H = (ushort*)slotA;  ushort* h1M = h1H + (size_t)R * 1024; ushort* h1L = h1M + (size_t)R * 1024;
    ushort* h2H = (ushort*)slotB;  ushort* h2M = h2H + (size_t)R * 512;  ushort* h2L = h2M + (size_t)R * 512;

    ushort* dA = (ushort*)slotB;
    ushort* dB = (ushort*)(slotB + (size_t)R * 256);
    ushort* dC = (ushort*)slotA;

    float* out      = (float*)d_out;
    float* out_loss = out + (size_t)B * 768;
    float* out_idx  = out_loss + 1;

    // prep (once per launch)
    prep_cb_kernel<<<1024, 128, 0, stream>>>(cb, cbT, cnorm);
    kuma_ab_init<<<1, 128, 0, stream>>>(a_raw, b_raw, kp);
    transpose_split_bf16<<<dim3( 768/32, 2048/32), 256, 0, stream>>>(enc_w[0], e0h, e0m, e0l,  768, 2048);
    transpose_split_bf16<<<dim3(2048/32, 1024/32), 256, 0, stream>>>(enc_w[1], e1h, e1m, e1l, 2048, 1024);
    transpose_split_bf16<<<dim3(1024/32,  512/32), 256, 0, stream>>>(enc_w[2], e2h, e2m, e2l, 1024,  512);
    transpose_split_bf16<<<dim3( 512/32,  128/32), 256, 0, stream>>>(enc_w[3], e3h, e3m, e3l,  512,  128);
    transpose_to_bf16<<<dim3(128/32,  512/32), 256, 0, stream>>>(dec_w[0], wt0,  128,  512);
    transpose_to_bf16<<<dim3(512/32, 1024/32), 256, 0, stream>>>(dec_w[1], wt1,  512, 1024);
    transpose_to_bf16<<<dim3(1024/32,2048/32), 256, 0, stream>>>(dec_w[2], wt2, 1024, 2048);
    transpose_to_bf16<<<dim3(2048/32, 768/32), 256, 0, stream>>>(dec_w[3], wt3, 2048,  768);

    const int nc = B / R;
    const int nRq = B / 4;
    const int rqPerChunk = R / 4;
    const int nvqPerChunk = (R * 128) / 256;
    for (int c = 0; c < nc; c++) {
        const size_t base = (size_t)c * R;
        const float* xc = x + base * 768;
        float* outc = out + base * 768;
        float* idxc = out_idx + base * 4;

        {
            size_t n = (size_t)R * 768;
            split_plane_kernel<<<(unsigned)((n + 255) / 256), 256, 0, stream>>>(xc, xH, xM, xL, n);
        }

        // encoder (split-bf16 MFMA, fp32-grade)
        gemm_mfma_split<true , 1><<<dim3(R/128, 16), 256, 0, stream>>>(
            xH, xM, xL, e0h, e0m, e0l, enc_b[0], h0H, h0M, h0L, R, 2048, 768);
        gemm_mfma_split<true , 1><<<dim3(R/128,  8), 256, 0, stream>>>(
            h0H, h0M, h0L, e1h, e1m, e1l, enc_b[1], h1H, h1M, h1L, R, 1024, 2048);
        gemm_mfma_split<true , 1><<<dim3(R/128,  4), 256, 0, stream>>>(
            h1H, h1M, h1L, e2h, e2m, e2l, enc_b[2], h2H, h2M, h2L, R,  512, 1024);
        gemm_mfma_split<false, 0><<<dim3(R/128,  1), 256, 0, stream>>>(
            h2H, h2M, h2L, e3h, e3m, e3l, enc_b[3], zb, nullptr, nullptr, R, 128, 512);

        // kuma + RQ + inverse + losses (fp32)
        kuma_h_kernel<<<(R * 128) / 256, 256, 0, stream>>>(zb, kp, zpb, R * 128);
        rq_kernel2<<<rqPerChunk, 64, 0, stream>>>(zpb, cb, cbT, cnorm, xqb, idxc,
                                                  prq, c * rqPerChunk, nRq);
        zq_nvq_kernel<<<nvqPerChunk, 256, 0, stream>>>(xqb, zpb, zb, kp, xqb, zq16,
                                                       pnvq, c * nvqPerChunk, R * 128);

        // decoder (bf16 MFMA)
        gemm_mfma_bt<true , true ><<<dim3(R/128,  512/128), 256, 0, stream>>>(zq16, wt0, dec_b[0], dA, R,  512,  128);
        gemm_mfma_bt<true , true ><<<dim3(R/128, 1024/128), 256, 0, stream>>>(dA,   wt1, dec_b[1], dB, R, 1024,  512);
        gemm_mfma_bt<true , true ><<<dim3(R/128, 2048/128), 256, 0, stream>>>(dB,   wt2, dec_b[2], dC, R, 2048, 1024);
        gemm_mfma_bt<false, false><<<dim3(R/128,  768/128), 256, 0, stream>>>(dC,   wt3, dec_b[3], outc, R,  768, 2048);
    }

    finalize_kernel<<<1, 256, 0, stream>>>(prq, pnvq, 4 * nRq, B * 128 / 256, out_loss);
}

// Round 9
// 965.339 us; speedup vs baseline: 4.2247x; 1.4734x over previous
//
#include <hip/hip_runtime.h>
#include <math.h>

#define EPS_F 1e-6f
#define ONE_M_EPS (1.0f - 1e-6f)

typedef __attribute__((ext_vector_type(8))) short s16x8;
typedef __attribute__((ext_vector_type(8))) _Float16 f16x8;
typedef __attribute__((ext_vector_type(4))) float f32x4;

__device__ __forceinline__ ushort f2bf(float f) {
    union { float f; unsigned u; } v; v.f = f;
    unsigned u = v.u;
    return (ushort)((u + 0x7FFFu + ((u >> 16) & 1u)) >> 16);
}
__device__ __forceinline__ float bf2f(ushort h) {
    union { unsigned u; float f; } v; v.u = ((unsigned)h) << 16;
    return v.f;
}
// fp16 2-plane split: x = h + m, |x - h - m| <= 2^-22 |x|
__device__ __forceinline__ void split2h(float x, ushort& h, ushort& m) {
    union { _Float16 f; ushort u; } a, b;
    a.f = (_Float16)x;
    float r = x - (float)a.f;
    b.f = (_Float16)r;
    h = a.u; m = b.u;
}

#define GLL16(srcp, dstp)                                                     \
    __builtin_amdgcn_global_load_lds(                                         \
        (const __attribute__((address_space(1))) void*)(srcp),                \
        (__attribute__((address_space(3))) void*)(dstp), 16, 0, 0)

// Bank-conflict swizzle (16B-chunk granularity; source+read, LDS linear)
__device__ __forceinline__ int swz_k(int row, int k) { return k ^ ((row >> 1) & 3); }

// ---------------------------------------------------------------------------
// 2-plane fp16 MFMA GEMM (encoder, fp32-grade): 3 products (hh,hm,mh), fp32 acc.
// C = act(A @ WT^T + bias). OUT2=1: emit 2 fp16 planes; OUT2=0: fp32.
// ---------------------------------------------------------------------------
template<bool RELU, int OUT2>
__global__ __launch_bounds__(256) void gemm_mfma_split2(
    const ushort* __restrict__ Ah, const ushort* __restrict__ Am,
    const ushort* __restrict__ Wh, const ushort* __restrict__ Wm,
    const float* __restrict__ bias,
    void* __restrict__ C0, void* __restrict__ C1,
    int M, int N, int K)
{
    __shared__ __align__(16) ushort As[2][128 * 32];
    __shared__ __align__(16) ushort Bs[2][128 * 32];

    const int tid  = threadIdx.x;
    const int lane = tid & 63;
    const int w    = tid >> 6;
    const int wm   = (w >> 1) * 64;
    const int wn   = (w & 1) * 64;
    const int bm   = blockIdx.x * 128;
    const int bn   = blockIdx.y * 128;

    f32x4 acc[4][4];
#pragma unroll
    for (int i = 0; i < 4; i++)
#pragma unroll
        for (int j = 0; j < 4; j++) acc[i][j] = f32x4{0.f, 0.f, 0.f, 0.f};

    const int c0 = (w * 2) * 64 + lane;
    const int c1 = (w * 2 + 1) * 64 + lane;
    const int r0 = c0 >> 2, k0e = swz_k(r0, c0 & 3) * 8;
    const int r1 = c1 >> 2, k1e = swz_k(r1, c1 & 3) * 8;

    const size_t a_off0 = (size_t)(bm + r0) * K + k0e;
    const size_t a_off1 = (size_t)(bm + r1) * K + k1e;
    const size_t b_off0 = (size_t)(bn + r0) * K + k0e;
    const size_t b_off1 = (size_t)(bn + r1) * K + k1e;
    const int d0 = (w * 2) * 512;
    const int d1 = (w * 2 + 1) * 512;

    const ushort* Ap[2] = {Ah, Am};
    const ushort* Wp[2] = {Wh, Wm};

    const int fm  = lane & 15;
    const int fkb = lane >> 4;

    for (int k0 = 0; k0 < K; k0 += 32) {
#pragma unroll
        for (int p = 0; p < 2; p++) {
            GLL16(Ap[p] + a_off0 + k0, &As[p][d0]);
            GLL16(Ap[p] + a_off1 + k0, &As[p][d1]);
            GLL16(Wp[p] + b_off0 + k0, &Bs[p][d0]);
            GLL16(Wp[p] + b_off1 + k0, &Bs[p][d1]);
        }
        __syncthreads();

        f16x8 af[2][4];
#pragma unroll
        for (int p = 0; p < 2; p++)
#pragma unroll
            for (int i = 0; i < 4; i++) {
                const int row = wm + i * 16 + fm;
                af[p][i] = *reinterpret_cast<const f16x8*>(
                    &As[p][row * 32 + swz_k(row, fkb) * 8]);
            }

#pragma unroll
        for (int q = 0; q < 2; q++) {
            f16x8 bq[4];
#pragma unroll
            for (int j = 0; j < 4; j++) {
                const int row = wn + j * 16 + fm;
                bq[j] = *reinterpret_cast<const f16x8*>(
                    &Bs[q][row * 32 + swz_k(row, fkb) * 8]);
            }
#pragma unroll
            for (int p = 0; p < 2; p++) {
                if (p + q <= 1) {
#pragma unroll
                    for (int i = 0; i < 4; i++)
#pragma unroll
                        for (int j = 0; j < 4; j++)
                            acc[i][j] = __builtin_amdgcn_mfma_f32_16x16x32_f16(
                                af[p][i], bq[j], acc[i][j], 0, 0, 0);
                }
            }
        }
        __syncthreads();
    }

#pragma unroll
    for (int j = 0; j < 4; j++) {
        const int coln = bn + wn + j * 16 + fm;
        const float bv = bias[coln];
#pragma unroll
        for (int i = 0; i < 4; i++) {
            const int row0 = bm + wm + i * 16 + (lane >> 4) * 4;
#pragma unroll
            for (int r = 0; r < 4; r++) {
                float o = acc[i][j][r] + bv;
                if (RELU) o = fmaxf(o, 0.f);
                const size_t idx = (size_t)(row0 + r) * N + coln;
                if (OUT2) {
                    ushort h, m;
                    split2h(o, h, m);
                    ((ushort*)C0)[idx] = h;
                    ((ushort*)C1)[idx] = m;
                } else {
                    ((float*)C0)[idx] = o;
                }
            }
        }
    }
}

// ---------------------------------------------------------------------------
// MFMA bf16 GEMM (decoder, single product), swizzled
// ---------------------------------------------------------------------------
template<bool RELU, bool OUT_BF16>
__global__ __launch_bounds__(256) void gemm_mfma_bt(
    const ushort* __restrict__ A, const ushort* __restrict__ WT,
    const float* __restrict__ bias, void* __restrict__ Cv,
    int M, int N, int K)
{
    __shared__ __align__(16) ushort As[128 * 32];
    __shared__ __align__(16) ushort Bs[128 * 32];

    const int tid  = threadIdx.x;
    const int lane = tid & 63;
    const int w    = tid >> 6;
    const int wm   = (w >> 1) * 64;
    const int wn   = (w & 1) * 64;
    const int bm   = blockIdx.x * 128;
    const int bn   = blockIdx.y * 128;

    f32x4 acc[4][4];
#pragma unroll
    for (int i = 0; i < 4; i++)
#pragma unroll
        for (int j = 0; j < 4; j++) acc[i][j] = f32x4{0.f, 0.f, 0.f, 0.f};

    const int c0 = (w * 2) * 64 + lane;
    const int c1 = (w * 2 + 1) * 64 + lane;
    const int r0 = c0 >> 2, k0e = swz_k(r0, c0 & 3) * 8;
    const int r1 = c1 >> 2, k1e = swz_k(r1, c1 & 3) * 8;

    const ushort* a_src0 = A  + (size_t)(bm + r0) * K + k0e;
    const ushort* a_src1 = A  + (size_t)(bm + r1) * K + k1e;
    const ushort* b_src0 = WT + (size_t)(bn + r0) * K + k0e;
    const ushort* b_src1 = WT + (size_t)(bn + r1) * K + k1e;
    ushort* a_dst0 = &As[(w * 2) * 512];
    ushort* a_dst1 = &As[(w * 2 + 1) * 512];
    ushort* b_dst0 = &Bs[(w * 2) * 512];
    ushort* b_dst1 = &Bs[(w * 2 + 1) * 512];

    const int fm  = lane & 15;
    const int fkb = lane >> 4;

    for (int k0 = 0; k0 < K; k0 += 32) {
        GLL16(a_src0 + k0, a_dst0);
        GLL16(a_src1 + k0, a_dst1);
        GLL16(b_src0 + k0, b_dst0);
        GLL16(b_src1 + k0, b_dst1);
        __syncthreads();

        s16x8 af[4], bfr[4];
#pragma unroll
        for (int i = 0; i < 4; i++) {
            const int row = wm + i * 16 + fm;
            af[i] = *reinterpret_cast<const s16x8*>(&As[row * 32 + swz_k(row, fkb) * 8]);
        }
#pragma unroll
        for (int j = 0; j < 4; j++) {
            const int row = wn + j * 16 + fm;
            bfr[j] = *reinterpret_cast<const s16x8*>(&Bs[row * 32 + swz_k(row, fkb) * 8]);
        }
#pragma unroll
        for (int i = 0; i < 4; i++)
#pragma unroll
            for (int j = 0; j < 4; j++)
                acc[i][j] = __builtin_amdgcn_mfma_f32_16x16x32_bf16(
                    af[i], bfr[j], acc[i][j], 0, 0, 0);
        __syncthreads();
    }

#pragma unroll
    for (int j = 0; j < 4; j++) {
        const int coln = bn + wn + j * 16 + fm;
        const float bv = bias[coln];
#pragma unroll
        for (int i = 0; i < 4; i++) {
            const int row0 = bm + wm + i * 16 + (lane >> 4) * 4;
#pragma unroll
            for (int r = 0; r < 4; r++) {
                float o = acc[i][j][r] + bv;
                if (RELU) o = fmaxf(o, 0.f);
                if (OUT_BF16)
                    ((ushort*)Cv)[(size_t)(row0 + r) * N + coln] = f2bf(o);
                else
                    ((float*)Cv)[(size_t)(row0 + r) * N + coln] = o;
            }
        }
    }
}

// ---------------------------------------------------------------------------
// Weight prep kernels
// ---------------------------------------------------------------------------
__global__ __launch_bounds__(256) void transpose_to_bf16(
    const float* __restrict__ W, ushort* __restrict__ WT, int K, int N)
{
    __shared__ float t[32][33];
    const int kb = blockIdx.x * 32, nb = blockIdx.y * 32;
    const int tx = threadIdx.x & 31, ty = threadIdx.x >> 5;
#pragma unroll
    for (int i = ty; i < 32; i += 8)
        t[i][tx] = W[(size_t)(kb + i) * N + nb + tx];
    __syncthreads();
#pragma unroll
    for (int i = ty; i < 32; i += 8)
        WT[(size_t)(nb + i) * K + kb + tx] = f2bf(t[tx][i]);
}

__global__ __launch_bounds__(256) void transpose_split_f16(
    const float* __restrict__ W, ushort* __restrict__ TH,
    ushort* __restrict__ TM, int K, int N)
{
    __shared__ float t[32][33];
    const int kb = blockIdx.x * 32, nb = blockIdx.y * 32;
    const int tx = threadIdx.x & 31, ty = threadIdx.x >> 5;
#pragma unroll
    for (int i = ty; i < 32; i += 8)
        t[i][tx] = W[(size_t)(kb + i) * N + nb + tx];
    __syncthreads();
#pragma unroll
    for (int i = ty; i < 32; i += 8) {
        ushort h, m;
        split2h(t[tx][i], h, m);
        const size_t idx = (size_t)(nb + i) * K + kb + tx;
        TH[idx] = h; TM[idx] = m;
    }
}

__global__ __launch_bounds__(256) void split_plane2_kernel(
    const float* __restrict__ X, ushort* __restrict__ H,
    ushort* __restrict__ M, size_t n)
{
    size_t i = (size_t)blockIdx.x * 256 + threadIdx.x;
    if (i >= n) return;
    ushort h, m;
    split2h(X[i], h, m);
    H[i] = h; M[i] = m;
}

// ---------------------------------------------------------------------------
// Codebook prep
// ---------------------------------------------------------------------------
__global__ __launch_bounds__(128) void prep_cb_kernel(
    const float* __restrict__ cb, float* __restrict__ cbT, float* __restrict__ cnorm)
{
    int b = blockIdx.x;
    int d = threadIdx.x;
    float v = cb[(size_t)b * 128 + d];
    int l = b >> 8, c = b & 255;
    cbT[((size_t)l * 128 + d) * 256 + c] = v;
    float s = v * v;
#pragma unroll
    for (int off = 32; off > 0; off >>= 1) s += __shfl_down(s, off);
    __shared__ float ps[2];
    if ((d & 63) == 0) ps[d >> 6] = s;
    __syncthreads();
    if (d == 0) cnorm[b] = ps[0] + ps[1];
}

__device__ __forceinline__ float softplusf(float x) {
    return (x > 20.f) ? x : log1pf(expf(x));
}

__global__ void kuma_ab_init(const float* __restrict__ a_raw, const float* __restrict__ b_raw,
                             float* __restrict__ kp)
{
    int t = threadIdx.x;
    if (t < 128) {
        float a = softplusf(a_raw[t]) + EPS_F;
        float b = softplusf(b_raw[t]) + EPS_F;
        kp[t] = a;
        kp[128 + t] = b;
        kp[256 + t] = 1.f / a;
        kp[384 + t] = 1.f / b;
    }
}

__global__ __launch_bounds__(256) void kuma_h_kernel(
    const float* __restrict__ z, const float* __restrict__ kp,
    float* __restrict__ zp, int n)
{
    int i = blockIdx.x * 256 + threadIdx.x;
    if (i >= n) return;
    int col = i & 127;
    float a = kp[col], b = kp[128 + col];
    float zv = z[i];
    float x = 1.f / (1.f + expf(-zv));
    x = fminf(fmaxf(x, EPS_F), ONE_M_EPS);
    float inner = 1.f - powf(x, a);
    inner = fminf(fmaxf(inner, EPS_F), 1.f);
    float y = 1.f - powf(inner, b);
    y = fminf(fmaxf(y, EPS_F), ONE_M_EPS);
    zp[i] = y;
}

// ---------------------------------------------------------------------------
// Residual quantizer v2 — 1 wave/block, 4 rows, 4 codes/thread.
// ---------------------------------------------------------------------------
__global__ __launch_bounds__(64) void rq_kernel2(
    const float* __restrict__ zp, const float* __restrict__ cb,
    const float* __restrict__ cbT, const float* __restrict__ cnorm,
    float* __restrict__ xq, float* __restrict__ idx_out,
    float* __restrict__ prq, int bid0, int nRq)
{
    __shared__ float res[4][128];

    const int t = threadIdx.x;
    const int row0 = blockIdx.x * 4;

#pragma unroll
    for (int j = 0; j < 8; j++) {
        int e = t + j * 64;
        res[e >> 7][e & 127] = zp[(size_t)row0 * 128 + e];
    }

    float lsum[4];

#pragma unroll 1
    for (int l = 0; l < 4; l++) {
        const float* cT = cbT + (size_t)l * 32768;

        float acc[4][4];
#pragma unroll
        for (int r = 0; r < 4; r++)
#pragma unroll
            for (int cc = 0; cc < 4; cc++) acc[r][cc] = 0.f;

        float pc[16];
#pragma unroll
        for (int dd = 0; dd < 4; dd++)
#pragma unroll
            for (int cc = 0; cc < 4; cc++)
                pc[dd * 4 + cc] = cT[dd * 256 + cc * 64 + t];

#pragma unroll 2
        for (int d = 0; d < 128; d += 4) {
            float nc[16];
            if (d < 124) {
#pragma unroll
                for (int dd = 0; dd < 4; dd++)
#pragma unroll
                    for (int cc = 0; cc < 4; cc++)
                        nc[dd * 4 + cc] = cT[(d + 4 + dd) * 256 + cc * 64 + t];
            }
#pragma unroll
            for (int r = 0; r < 4; r++) {
                float4 rv = *reinterpret_cast<const float4*>(&res[r][d]);
#pragma unroll
                for (int cc = 0; cc < 4; cc++) {
                    acc[r][cc] += rv.x * pc[cc] + rv.y * pc[4 + cc]
                                + rv.z * pc[8 + cc] + rv.w * pc[12 + cc];
                }
            }
#pragma unroll
            for (int k = 0; k < 16; k++) pc[k] = nc[k];
        }

        float cn[4];
#pragma unroll
        for (int cc = 0; cc < 4; cc++) cn[cc] = cnorm[l * 256 + cc * 64 + t];

        int bidx0, bidx1, bidx2, bidx3;
#pragma unroll
        for (int r = 0; r < 4; r++) {
            float dmin = cn[0] - 2.f * acc[r][0];
            int imin = t;
#pragma unroll
            for (int cc = 1; cc < 4; cc++) {
                float dv = cn[cc] - 2.f * acc[r][cc];
                if (dv < dmin) { dmin = dv; imin = cc * 64 + t; }
            }
#pragma unroll
            for (int off = 1; off < 64; off <<= 1) {
                float d2 = __shfl_xor(dmin, off);
                int i2 = __shfl_xor(imin, off);
                if (d2 < dmin || (d2 == dmin && i2 < imin)) { dmin = d2; imin = i2; }
            }
            if (r == 0) bidx0 = imin;
            else if (r == 1) bidx1 = imin;
            else if (r == 2) bidx2 = imin;
            else bidx3 = imin;
            if (t == 0) idx_out[(size_t)(row0 + r) * 4 + l] = (float)imin;
        }

        float s = 0.f;
#pragma unroll
        for (int j = 0; j < 8; j++) {
            const int r = j >> 1;
            const int d = (j & 1) * 64 + t;
            const int bi = (r == 0) ? bidx0 : (r == 1) ? bidx1 : (r == 2) ? bidx2 : bidx3;
            float q = cb[((size_t)(l * 256) + bi) * 128 + d];
            float nr = res[r][d] - q;
            res[r][d] = nr;
            s += nr * nr;
        }
        lsum[l] = s;
    }

#pragma unroll
    for (int j = 0; j < 8; j++) {
        int e = t + j * 64;
        xq[(size_t)row0 * 128 + e] = zp[(size_t)row0 * 128 + e] - res[e >> 7][e & 127];
    }

#pragma unroll
    for (int l = 0; l < 4; l++) {
        float s = lsum[l];
#pragma unroll
        for (int off = 32; off > 0; off >>= 1) s += __shfl_down(s, off);
        if (t == 0) prq[(size_t)l * nRq + bid0 + blockIdx.x] = s;
    }
}

// ---------------------------------------------------------------------------
// z_q = h_inv(x_q) (+ bf16 copy);  z_recon = h_inv(z');  nvq partial store
// ---------------------------------------------------------------------------
__device__ __forceinline__ float kuma_h_inv_f(float y, float ia, float ib) {
    y = fminf(fmaxf(y, EPS_F), ONE_M_EPS);
    float omy = fminf(fmaxf(1.f - y, EPS_F), 1.f);
    float inner = fminf(fmaxf(1.f - powf(omy, ib), EPS_F), ONE_M_EPS);
    float x = fminf(fmaxf(powf(inner, ia), EPS_F), ONE_M_EPS);
    return logf(x / (1.f - x));
}

__global__ __launch_bounds__(256) void zq_nvq_kernel(
    const float* __restrict__ xq, const float* __restrict__ zp,
    const float* __restrict__ z, const float* __restrict__ kp,
    float* __restrict__ zq, ushort* __restrict__ zq16,
    float* __restrict__ pnvq, int bid0, int n)
{
    int i = blockIdx.x * 256 + threadIdx.x;
    float ds = 0.f;
    if (i < n) {
        int col = i & 127;
        float ia = kp[256 + col], ib = kp[384 + col];
        float xv = xq[i];
        float zpv = zp[i];
        float zv = z[i];
        float zr = kuma_h_inv_f(zpv, ia, ib);
        float d = zr - zv;
        ds = d * d;
        float zqv = kuma_h_inv_f(xv, ia, ib);
        zq[i] = zqv;
        zq16[i] = f2bf(zqv);
    }
#pragma unroll
    for (int off = 32; off > 0; off >>= 1) ds += __shfl_down(ds, off);
    __shared__ float ps[4];
    if ((threadIdx.x & 63) == 0) ps[threadIdx.x >> 6] = ds;
    __syncthreads();
    if (threadIdx.x == 0)
        pnvq[bid0 + blockIdx.x] = ps[0] + ps[1] + ps[2] + ps[3];
}

// ---------------------------------------------------------------------------
// Final loss
// ---------------------------------------------------------------------------
__global__ __launch_bounds__(256) void finalize_kernel(
    const float* __restrict__ prq, const float* __restrict__ pnvq,
    int nRqAll, int nNvq, float* __restrict__ out_loss)
{
    const int t = threadIdx.x;
    float srq = 0.f, snvq = 0.f;
    for (int i = t; i < nRqAll; i += 256) srq += prq[i];
    for (int i = t; i < nNvq; i += 256) snvq += pnvq[i];
#pragma unroll
    for (int off = 32; off > 0; off >>= 1) {
        srq += __shfl_down(srq, off);
        snvq += __shfl_down(snvq, off);
    }
    __shared__ float pr[4], pn[4];
    if ((t & 63) == 0) { pr[t >> 6] = srq; pn[t >> 6] = snvq; }
    __syncthreads();
    if (t == 0) {
        const float inv = 1.f / (16384.f * 128.f);
        float rq = (pr[0] + pr[1] + pr[2] + pr[3]);
        float nv = (pn[0] + pn[1] + pn[2] + pn[3]);
        out_loss[0] = 0.3125f * rq * inv + nv * inv;
    }
}

// ---------------------------------------------------------------------------
// Launcher — fp16 2-plane MFMA encoder + bf16 MFMA decoder.
// Per-R floats: slotA R*1024 + slotB R*2048 + 3*R*128 + R*64 = R*3520
// Fixed floats: enc planes 4,259,840 + dec 2,129,920 + cbT 131,072 + 1024
//             + 512 + prq 16384 + pnvq 8192 + 64 = 6,547,008
// R=16384 -> 64.2M floats (fits 256 MiB ws) -> SINGLE CHUNK.
// ---------------------------------------------------------------------------
extern "C" void kernel_launch(void* const* d_in, const int* in_sizes, int n_in,
                              void* d_out, int out_size, void* d_ws, size_t ws_size,
                              hipStream_t stream)
{
    constexpr int B = 16384;

    const float* x = (const float*)d_in[0];
    const float* enc_w[4]; const float* enc_b[4];
    const float* dec_w[4]; const float* dec_b[4];
    for (int i = 0; i < 4; i++) {
        enc_w[i] = (const float*)d_in[1 + 4 * i];
        enc_b[i] = (const float*)d_in[2 + 4 * i];
        dec_w[i] = (const float*)d_in[3 + 4 * i];
        dec_b[i] = (const float*)d_in[4 + 4 * i];
    }
    const float* cb    = (const float*)d_in[17];
    const float* a_raw = (const float*)d_in[18];
    const float* b_raw = (const float*)d_in[19];

    // chunk size
    size_t avail = ws_size / 4;
    const size_t fixed_f = 6547008;
    int R = 16384;
    while (R > 256 && (size_t)R * 3520 + fixed_f > avail) R >>= 1;

    // carve (floats)
    float* ws    = (float*)d_ws;
    float* slotA = ws;                         // R*1024 fl
    float* slotB = slotA + (size_t)R * 1024;   // R*2048 fl
    float* zb    = slotB + (size_t)R * 2048;   // R*128
    float* zpb   = zb  + (size_t)R * 128;      // R*128
    float* xqb   = zpb + (size_t)R * 128;      // R*128
    float* zq16f = xqb + (size_t)R * 128;      // R*64 (ushort R*128)
    float* fixp  = zq16f + (size_t)R * 64;

    // fixed: encoder fp16 weight planes (2 each), decoder bf16 WT, cb scratch
    ushort* ew = (ushort*)fixp;
    ushort* e0h = ew;            ushort* e0m = e0h + 1572864;
    ushort* e1h = e0m + 1572864; ushort* e1m = e1h + 2097152;
    ushort* e2h = e1m + 2097152; ushort* e2m = e2h + 524288;
    ushort* e3h = e2m + 524288;  ushort* e3m = e3h + 65536;
    ushort* wt0 = e3m + 65536;
    ushort* wt1 = wt0 + 65536;
    ushort* wt2 = wt1 + 524288;
    ushort* wt3 = wt2 + 2097152;
    float* cbT   = (float*)(wt3 + 1572864);
    float* cnorm = cbT + 4 * 128 * 256;
    float* kp    = cnorm + 4 * 256;
    float* prq   = kp + 512;              // 16384
    float* pnvq  = prq + 16384;           // 8192

    ushort* zq16 = (ushort*)zq16f;

    // encoder activation plane aliases (2 fp16 planes each)
    ushort* xH  = (ushort*)slotA;  ushort* xM  = xH  + (size_t)R * 768;
    ushort* h0H = (ushort*)slotB;  ushort* h0M = h0H + (size_t)R * 2048;
    ushort* h1H = (ushort*)slotA;  ushort* h1M = h1H + (size_t)R * 1024;
    ushort* h2H = (ushort*)slotB;  ushort* h2M = h2H + (size_t)R * 512;

    // decoder activation aliases (bf16)
    ushort* dA = (ushort*)slotB;                       // R x 512
    ushort* dB = (ushort*)(slotB + (size_t)R * 256);   // R x 1024
    ushort* dC = (ushort*)slotA;                       // R x 2048

    float* out      = (float*)d_out;
    float* out_loss = out + (size_t)B * 768;
    float* out_idx  = out_loss + 1;

    // prep (once per launch)
    prep_cb_kernel<<<1024, 128, 0, stream>>>(cb, cbT, cnorm);
    kuma_ab_init<<<1, 128, 0, stream>>>(a_raw, b_raw, kp);
    transpose_split_f16<<<dim3( 768/32, 2048/32), 256, 0, stream>>>(enc_w[0], e0h, e0m,  768, 2048);
    transpose_split_f16<<<dim3(2048/32, 1024/32), 256, 0, stream>>>(enc_w[1], e1h, e1m, 2048, 1024);
    transpose_split_f16<<<dim3(1024/32,  512/32), 256, 0, stream>>>(enc_w[2], e2h, e2m, 1024,  512);
    transpose_split_f16<<<dim3( 512/32,  128/32), 256, 0, stream>>>(enc_w[3], e3h, e3m,  512,  128);
    transpose_to_bf16<<<dim3(128/32,  512/32), 256, 0, stream>>>(dec_w[0], wt0,  128,  512);
    transpose_to_bf16<<<dim3(512/32, 1024/32), 256, 0, stream>>>(dec_w[1], wt1,  512, 1024);
    transpose_to_bf16<<<dim3(1024/32,2048/32), 256, 0, stream>>>(dec_w[2], wt2, 1024, 2048);
    transpose_to_bf16<<<dim3(2048/32, 768/32), 256, 0, stream>>>(dec_w[3], wt3, 2048,  768);

    const int nc = B / R;
    const int nRq = B / 4;
    const int rqPerChunk = R / 4;
    const int nvqPerChunk = (R * 128) / 256;
    for (int c = 0; c < nc; c++) {
        const size_t base = (size_t)c * R;
        const float* xc = x + base * 768;
        float* outc = out + base * 768;
        float* idxc = out_idx + base * 4;

        {
            size_t n = (size_t)R * 768;
            split_plane2_kernel<<<(unsigned)((n + 255) / 256), 256, 0, stream>>>(xc, xH, xM, n);
        }

        // encoder (2-plane fp16 MFMA, fp32-grade)
        gemm_mfma_split2<true , 1><<<dim3(R/128, 16), 256, 0, stream>>>(
            xH, xM, e0h, e0m, enc_b[0], h0H, h0M, R, 2048, 768);
        gemm_mfma_split2<true , 1><<<dim3(R/128,  8), 256, 0, stream>>>(
            h0H, h0M, e1h, e1m, enc_b[1], h1H, h1M, R, 1024, 2048);
        gemm_mfma_split2<true , 1><<<dim3(R/128,  4), 256, 0, stream>>>(
            h1H, h1M, e2h, e2m, enc_b[2], h2H, h2M, R,  512, 1024);
        gemm_mfma_split2<false, 0><<<dim3(R/128,  1), 256, 0, stream>>>(
            h2H, h2M, e3h, e3m, enc_b[3], zb, nullptr, R, 128, 512);

        // kuma + RQ + inverse + losses (fp32)
        kuma_h_kernel<<<(R * 128) / 256, 256, 0, stream>>>(zb, kp, zpb, R * 128);
        rq_kernel2<<<rqPerChunk, 64, 0, stream>>>(zpb, cb, cbT, cnorm, xqb, idxc,
                                                  prq, c * rqPerChunk, nRq);
        zq_nvq_kernel<<<nvqPerChunk, 256, 0, stream>>>(xqb, zpb, zb, kp, xqb, zq16,
                                                       pnvq, c * nvqPerChunk, R * 128);

        // decoder (bf16 MFMA)
        gemm_mfma_bt<true , true ><<<dim3(R/128,  512/128), 256, 0, stream>>>(zq16, wt0, dec_b[0], dA, R,  512,  128);
        gemm_mfma_bt<true , true ><<<dim3(R/128, 1024/128), 256, 0, stream>>>(dA,   wt1, dec_b[1], dB, R, 1024,  512);
        gemm_mfma_bt<true , true ><<<dim3(R/128, 2048/128), 256, 0, stream>>>(dB,   wt2, dec_b[2], dC, R, 2048, 1024);
        gemm_mfma_bt<false, false><<<dim3(R/128,  768/128), 256, 0, stream>>>(dC,   wt3, dec_b[3], outc, R,  768, 2048);
    }

    finalize_kernel<<<1, 256, 0, stream>>>(prq, pnvq, 4 * nRq, B * 128 / 256, out_loss);
}

// Round 10
// 954.049 us; speedup vs baseline: 4.2747x; 1.0118x over previous
//
#include <hip/hip_runtime.h>
#include <math.h>

#define EPS_F 1e-6f
#define ONE_M_EPS (1.0f - 1e-6f)

typedef __attribute__((ext_vector_type(8))) short s16x8;
typedef __attribute__((ext_vector_type(8))) _Float16 f16x8;
typedef __attribute__((ext_vector_type(4))) float f32x4;

__device__ __forceinline__ ushort f2bf(float f) {
    union { float f; unsigned u; } v; v.f = f;
    unsigned u = v.u;
    return (ushort)((u + 0x7FFFu + ((u >> 16) & 1u)) >> 16);
}
__device__ __forceinline__ float bf2f(ushort h) {
    union { unsigned u; float f; } v; v.u = ((unsigned)h) << 16;
    return v.f;
}
// fp16 2-plane split: x = h + m, |x - h - m| <= 2^-22 |x|
__device__ __forceinline__ void split2h(float x, ushort& h, ushort& m) {
    union { _Float16 f; ushort u; } a, b;
    a.f = (_Float16)x;
    float r = x - (float)a.f;
    b.f = (_Float16)r;
    h = a.u; m = b.u;
}

#define GLL16(srcp, dstp)                                                     \
    __builtin_amdgcn_global_load_lds(                                         \
        (const __attribute__((address_space(1))) void*)(srcp),                \
        (__attribute__((address_space(3))) void*)(dstp), 16, 0, 0)

// Bank-conflict swizzle (16B-chunk granularity; source+read, LDS linear)
__device__ __forceinline__ int swz_k(int row, int k) { return k ^ ((row >> 1) & 3); }

// ---------------------------------------------------------------------------
// 2-plane fp16 MFMA GEMM (encoder, fp32-grade): 3 products (hh,hm,mh), fp32 acc.
// Grid: (N/128, M/128) — bn fastest => consecutive blocks share the A row-panel
// (L2-resident); B cycles via L3. Cuts A re-fetch ~8-16x.
// ---------------------------------------------------------------------------
template<bool RELU, int OUT2>
__global__ __launch_bounds__(256) void gemm_mfma_split2(
    const ushort* __restrict__ Ah, const ushort* __restrict__ Am,
    const ushort* __restrict__ Wh, const ushort* __restrict__ Wm,
    const float* __restrict__ bias,
    void* __restrict__ C0, void* __restrict__ C1,
    int M, int N, int K)
{
    __shared__ __align__(16) ushort As[2][128 * 32];
    __shared__ __align__(16) ushort Bs[2][128 * 32];

    const int tid  = threadIdx.x;
    const int lane = tid & 63;
    const int w    = tid >> 6;
    const int wm   = (w >> 1) * 64;
    const int wn   = (w & 1) * 64;
    const int bm   = blockIdx.y * 128;   // M from slow dim
    const int bn   = blockIdx.x * 128;   // N from fast dim (L2 reuse of A-panel)

    f32x4 acc[4][4];
#pragma unroll
    for (int i = 0; i < 4; i++)
#pragma unroll
        for (int j = 0; j < 4; j++) acc[i][j] = f32x4{0.f, 0.f, 0.f, 0.f};

    const int c0 = (w * 2) * 64 + lane;
    const int c1 = (w * 2 + 1) * 64 + lane;
    const int r0 = c0 >> 2, k0e = swz_k(r0, c0 & 3) * 8;
    const int r1 = c1 >> 2, k1e = swz_k(r1, c1 & 3) * 8;

    const size_t a_off0 = (size_t)(bm + r0) * K + k0e;
    const size_t a_off1 = (size_t)(bm + r1) * K + k1e;
    const size_t b_off0 = (size_t)(bn + r0) * K + k0e;
    const size_t b_off1 = (size_t)(bn + r1) * K + k1e;
    const int d0 = (w * 2) * 512;
    const int d1 = (w * 2 + 1) * 512;

    const ushort* Ap[2] = {Ah, Am};
    const ushort* Wp[2] = {Wh, Wm};

    const int fm  = lane & 15;
    const int fkb = lane >> 4;

    for (int k0 = 0; k0 < K; k0 += 32) {
#pragma unroll
        for (int p = 0; p < 2; p++) {
            GLL16(Ap[p] + a_off0 + k0, &As[p][d0]);
            GLL16(Ap[p] + a_off1 + k0, &As[p][d1]);
            GLL16(Wp[p] + b_off0 + k0, &Bs[p][d0]);
            GLL16(Wp[p] + b_off1 + k0, &Bs[p][d1]);
        }
        __syncthreads();

        f16x8 af[2][4];
#pragma unroll
        for (int p = 0; p < 2; p++)
#pragma unroll
            for (int i = 0; i < 4; i++) {
                const int row = wm + i * 16 + fm;
                af[p][i] = *reinterpret_cast<const f16x8*>(
                    &As[p][row * 32 + swz_k(row, fkb) * 8]);
            }

#pragma unroll
        for (int q = 0; q < 2; q++) {
            f16x8 bq[4];
#pragma unroll
            for (int j = 0; j < 4; j++) {
                const int row = wn + j * 16 + fm;
                bq[j] = *reinterpret_cast<const f16x8*>(
                    &Bs[q][row * 32 + swz_k(row, fkb) * 8]);
            }
#pragma unroll
            for (int p = 0; p < 2; p++) {
                if (p + q <= 1) {
#pragma unroll
                    for (int i = 0; i < 4; i++)
#pragma unroll
                        for (int j = 0; j < 4; j++)
                            acc[i][j] = __builtin_amdgcn_mfma_f32_16x16x32_f16(
                                af[p][i], bq[j], acc[i][j], 0, 0, 0);
                }
            }
        }
        __syncthreads();
    }

#pragma unroll
    for (int j = 0; j < 4; j++) {
        const int coln = bn + wn + j * 16 + fm;
        const float bv = bias[coln];
#pragma unroll
        for (int i = 0; i < 4; i++) {
            const int row0 = bm + wm + i * 16 + (lane >> 4) * 4;
#pragma unroll
            for (int r = 0; r < 4; r++) {
                float o = acc[i][j][r] + bv;
                if (RELU) o = fmaxf(o, 0.f);
                const size_t idx = (size_t)(row0 + r) * N + coln;
                if (OUT2) {
                    ushort h, m;
                    split2h(o, h, m);
                    ((ushort*)C0)[idx] = h;
                    ((ushort*)C1)[idx] = m;
                } else {
                    ((float*)C0)[idx] = o;
                }
            }
        }
    }
}

// ---------------------------------------------------------------------------
// MFMA bf16 GEMM (decoder, single product), swizzled, bn-fastest grid
// ---------------------------------------------------------------------------
template<bool RELU, bool OUT_BF16>
__global__ __launch_bounds__(256) void gemm_mfma_bt(
    const ushort* __restrict__ A, const ushort* __restrict__ WT,
    const float* __restrict__ bias, void* __restrict__ Cv,
    int M, int N, int K)
{
    __shared__ __align__(16) ushort As[128 * 32];
    __shared__ __align__(16) ushort Bs[128 * 32];

    const int tid  = threadIdx.x;
    const int lane = tid & 63;
    const int w    = tid >> 6;
    const int wm   = (w >> 1) * 64;
    const int wn   = (w & 1) * 64;
    const int bm   = blockIdx.y * 128;
    const int bn   = blockIdx.x * 128;

    f32x4 acc[4][4];
#pragma unroll
    for (int i = 0; i < 4; i++)
#pragma unroll
        for (int j = 0; j < 4; j++) acc[i][j] = f32x4{0.f, 0.f, 0.f, 0.f};

    const int c0 = (w * 2) * 64 + lane;
    const int c1 = (w * 2 + 1) * 64 + lane;
    const int r0 = c0 >> 2, k0e = swz_k(r0, c0 & 3) * 8;
    const int r1 = c1 >> 2, k1e = swz_k(r1, c1 & 3) * 8;

    const ushort* a_src0 = A  + (size_t)(bm + r0) * K + k0e;
    const ushort* a_src1 = A  + (size_t)(bm + r1) * K + k1e;
    const ushort* b_src0 = WT + (size_t)(bn + r0) * K + k0e;
    const ushort* b_src1 = WT + (size_t)(bn + r1) * K + k1e;
    ushort* a_dst0 = &As[(w * 2) * 512];
    ushort* a_dst1 = &As[(w * 2 + 1) * 512];
    ushort* b_dst0 = &Bs[(w * 2) * 512];
    ushort* b_dst1 = &Bs[(w * 2 + 1) * 512];

    const int fm  = lane & 15;
    const int fkb = lane >> 4;

    for (int k0 = 0; k0 < K; k0 += 32) {
        GLL16(a_src0 + k0, a_dst0);
        GLL16(a_src1 + k0, a_dst1);
        GLL16(b_src0 + k0, b_dst0);
        GLL16(b_src1 + k0, b_dst1);
        __syncthreads();

        s16x8 af[4], bfr[4];
#pragma unroll
        for (int i = 0; i < 4; i++) {
            const int row = wm + i * 16 + fm;
            af[i] = *reinterpret_cast<const s16x8*>(&As[row * 32 + swz_k(row, fkb) * 8]);
        }
#pragma unroll
        for (int j = 0; j < 4; j++) {
            const int row = wn + j * 16 + fm;
            bfr[j] = *reinterpret_cast<const s16x8*>(&Bs[row * 32 + swz_k(row, fkb) * 8]);
        }
#pragma unroll
        for (int i = 0; i < 4; i++)
#pragma unroll
            for (int j = 0; j < 4; j++)
                acc[i][j] = __builtin_amdgcn_mfma_f32_16x16x32_bf16(
                    af[i], bfr[j], acc[i][j], 0, 0, 0);
        __syncthreads();
    }

#pragma unroll
    for (int j = 0; j < 4; j++) {
        const int coln = bn + wn + j * 16 + fm;
        const float bv = bias[coln];
#pragma unroll
        for (int i = 0; i < 4; i++) {
            const int row0 = bm + wm + i * 16 + (lane >> 4) * 4;
#pragma unroll
            for (int r = 0; r < 4; r++) {
                float o = acc[i][j][r] + bv;
                if (RELU) o = fmaxf(o, 0.f);
                if (OUT_BF16)
                    ((ushort*)Cv)[(size_t)(row0 + r) * N + coln] = f2bf(o);
                else
                    ((float*)Cv)[(size_t)(row0 + r) * N + coln] = o;
            }
        }
    }
}

// ---------------------------------------------------------------------------
// Weight prep kernels
// ---------------------------------------------------------------------------
__global__ __launch_bounds__(256) void transpose_to_bf16(
    const float* __restrict__ W, ushort* __restrict__ WT, int K, int N)
{
    __shared__ float t[32][33];
    const int kb = blockIdx.x * 32, nb = blockIdx.y * 32;
    const int tx = threadIdx.x & 31, ty = threadIdx.x >> 5;
#pragma unroll
    for (int i = ty; i < 32; i += 8)
        t[i][tx] = W[(size_t)(kb + i) * N + nb + tx];
    __syncthreads();
#pragma unroll
    for (int i = ty; i < 32; i += 8)
        WT[(size_t)(nb + i) * K + kb + tx] = f2bf(t[tx][i]);
}

__global__ __launch_bounds__(256) void transpose_split_f16(
    const float* __restrict__ W, ushort* __restrict__ TH,
    ushort* __restrict__ TM, int K, int N)
{
    __shared__ float t[32][33];
    const int kb = blockIdx.x * 32, nb = blockIdx.y * 32;
    const int tx = threadIdx.x & 31, ty = threadIdx.x >> 5;
#pragma unroll
    for (int i = ty; i < 32; i += 8)
        t[i][tx] = W[(size_t)(kb + i) * N + nb + tx];
    __syncthreads();
#pragma unroll
    for (int i = ty; i < 32; i += 8) {
        ushort h, m;
        split2h(t[tx][i], h, m);
        const size_t idx = (size_t)(nb + i) * K + kb + tx;
        TH[idx] = h; TM[idx] = m;
    }
}

__global__ __launch_bounds__(256) void split_plane2_kernel(
    const float* __restrict__ X, ushort* __restrict__ H,
    ushort* __restrict__ M, size_t n)
{
    size_t i = (size_t)blockIdx.x * 256 + threadIdx.x;
    if (i >= n) return;
    ushort h, m;
    split2h(X[i], h, m);
    H[i] = h; M[i] = m;
}

// ---------------------------------------------------------------------------
// Codebook prep
// ---------------------------------------------------------------------------
__global__ __launch_bounds__(128) void prep_cb_kernel(
    const float* __restrict__ cb, float* __restrict__ cbT, float* __restrict__ cnorm)
{
    int b = blockIdx.x;
    int d = threadIdx.x;
    float v = cb[(size_t)b * 128 + d];
    int l = b >> 8, c = b & 255;
    cbT[((size_t)l * 128 + d) * 256 + c] = v;
    float s = v * v;
#pragma unroll
    for (int off = 32; off > 0; off >>= 1) s += __shfl_down(s, off);
    __shared__ float ps[2];
    if ((d & 63) == 0) ps[d >> 6] = s;
    __syncthreads();
    if (d == 0) cnorm[b] = ps[0] + ps[1];
}

__device__ __forceinline__ float softplusf(float x) {
    return (x > 20.f) ? x : log1pf(expf(x));
}

__global__ void kuma_ab_init(const float* __restrict__ a_raw, const float* __restrict__ b_raw,
                             float* __restrict__ kp)
{
    int t = threadIdx.x;
    if (t < 128) {
        float a = softplusf(a_raw[t]) + EPS_F;
        float b = softplusf(b_raw[t]) + EPS_F;
        kp[t] = a;
        kp[128 + t] = b;
        kp[256 + t] = 1.f / a;
        kp[384 + t] = 1.f / b;
    }
}

__global__ __launch_bounds__(256) void kuma_h_kernel(
    const float* __restrict__ z, const float* __restrict__ kp,
    float* __restrict__ zp, int n)
{
    int i = blockIdx.x * 256 + threadIdx.x;
    if (i >= n) return;
    int col = i & 127;
    float a = kp[col], b = kp[128 + col];
    float zv = z[i];
    float x = 1.f / (1.f + expf(-zv));
    x = fminf(fmaxf(x, EPS_F), ONE_M_EPS);
    float inner = 1.f - powf(x, a);
    inner = fminf(fmaxf(inner, EPS_F), 1.f);
    float y = 1.f - powf(inner, b);
    y = fminf(fmaxf(y, EPS_F), ONE_M_EPS);
    zp[i] = y;
}

// ---------------------------------------------------------------------------
// Residual quantizer v2 — 1 wave/block, 4 rows, 4 codes/thread.
// ---------------------------------------------------------------------------
__global__ __launch_bounds__(64) void rq_kernel2(
    const float* __restrict__ zp, const float* __restrict__ cb,
    const float* __restrict__ cbT, const float* __restrict__ cnorm,
    float* __restrict__ xq, float* __restrict__ idx_out,
    float* __restrict__ prq, int bid0, int nRq)
{
    __shared__ float res[4][128];

    const int t = threadIdx.x;
    const int row0 = blockIdx.x * 4;

#pragma unroll
    for (int j = 0; j < 8; j++) {
        int e = t + j * 64;
        res[e >> 7][e & 127] = zp[(size_t)row0 * 128 + e];
    }

    float lsum[4];

#pragma unroll 1
    for (int l = 0; l < 4; l++) {
        const float* cT = cbT + (size_t)l * 32768;

        float acc[4][4];
#pragma unroll
        for (int r = 0; r < 4; r++)
#pragma unroll
            for (int cc = 0; cc < 4; cc++) acc[r][cc] = 0.f;

        float pc[16];
#pragma unroll
        for (int dd = 0; dd < 4; dd++)
#pragma unroll
            for (int cc = 0; cc < 4; cc++)
                pc[dd * 4 + cc] = cT[dd * 256 + cc * 64 + t];

#pragma unroll 2
        for (int d = 0; d < 128; d += 4) {
            float nc[16];
            if (d < 124) {
#pragma unroll
                for (int dd = 0; dd < 4; dd++)
#pragma unroll
                    for (int cc = 0; cc < 4; cc++)
                        nc[dd * 4 + cc] = cT[(d + 4 + dd) * 256 + cc * 64 + t];
            }
#pragma unroll
            for (int r = 0; r < 4; r++) {
                float4 rv = *reinterpret_cast<const float4*>(&res[r][d]);
#pragma unroll
                for (int cc = 0; cc < 4; cc++) {
                    acc[r][cc] += rv.x * pc[cc] + rv.y * pc[4 + cc]
                                + rv.z * pc[8 + cc] + rv.w * pc[12 + cc];
                }
            }
#pragma unroll
            for (int k = 0; k < 16; k++) pc[k] = nc[k];
        }

        float cn[4];
#pragma unroll
        for (int cc = 0; cc < 4; cc++) cn[cc] = cnorm[l * 256 + cc * 64 + t];

        int bidx0, bidx1, bidx2, bidx3;
#pragma unroll
        for (int r = 0; r < 4; r++) {
            float dmin = cn[0] - 2.f * acc[r][0];
            int imin = t;
#pragma unroll
            for (int cc = 1; cc < 4; cc++) {
                float dv = cn[cc] - 2.f * acc[r][cc];
                if (dv < dmin) { dmin = dv; imin = cc * 64 + t; }
            }
#pragma unroll
            for (int off = 1; off < 64; off <<= 1) {
                float d2 = __shfl_xor(dmin, off);
                int i2 = __shfl_xor(imin, off);
                if (d2 < dmin || (d2 == dmin && i2 < imin)) { dmin = d2; imin = i2; }
            }
            if (r == 0) bidx0 = imin;
            else if (r == 1) bidx1 = imin;
            else if (r == 2) bidx2 = imin;
            else bidx3 = imin;
            if (t == 0) idx_out[(size_t)(row0 + r) * 4 + l] = (float)imin;
        }

        float s = 0.f;
#pragma unroll
        for (int j = 0; j < 8; j++) {
            const int r = j >> 1;
            const int d = (j & 1) * 64 + t;
            const int bi = (r == 0) ? bidx0 : (r == 1) ? bidx1 : (r == 2) ? bidx2 : bidx3;
            float q = cb[((size_t)(l * 256) + bi) * 128 + d];
            float nr = res[r][d] - q;
            res[r][d] = nr;
            s += nr * nr;
        }
        lsum[l] = s;
    }

#pragma unroll
    for (int j = 0; j < 8; j++) {
        int e = t + j * 64;
        xq[(size_t)row0 * 128 + e] = zp[(size_t)row0 * 128 + e] - res[e >> 7][e & 127];
    }

#pragma unroll
    for (int l = 0; l < 4; l++) {
        float s = lsum[l];
#pragma unroll
        for (int off = 32; off > 0; off >>= 1) s += __shfl_down(s, off);
        if (t == 0) prq[(size_t)l * nRq + bid0 + blockIdx.x] = s;
    }
}

// ---------------------------------------------------------------------------
// z_q = h_inv(x_q) (+ bf16 copy);  z_recon = h_inv(z');  nvq partial store
// ---------------------------------------------------------------------------
__device__ __forceinline__ float kuma_h_inv_f(float y, float ia, float ib) {
    y = fminf(fmaxf(y, EPS_F), ONE_M_EPS);
    float omy = fminf(fmaxf(1.f - y, EPS_F), 1.f);
    float inner = fminf(fmaxf(1.f - powf(omy, ib), EPS_F), ONE_M_EPS);
    float x = fminf(fmaxf(powf(inner, ia), EPS_F), ONE_M_EPS);
    return logf(x / (1.f - x));
}

__global__ __launch_bounds__(256) void zq_nvq_kernel(
    const float* __restrict__ xq, const float* __restrict__ zp,
    const float* __restrict__ z, const float* __restrict__ kp,
    float* __restrict__ zq, ushort* __restrict__ zq16,
    float* __restrict__ pnvq, int bid0, int n)
{
    int i = blockIdx.x * 256 + threadIdx.x;
    float ds = 0.f;
    if (i < n) {
        int col = i & 127;
        float ia = kp[256 + col], ib = kp[384 + col];
        float xv = xq[i];
        float zpv = zp[i];
        float zv = z[i];
        float zr = kuma_h_inv_f(zpv, ia, ib);
        float d = zr - zv;
        ds = d * d;
        float zqv = kuma_h_inv_f(xv, ia, ib);
        zq[i] = zqv;
        zq16[i] = f2bf(zqv);
    }
#pragma unroll
    for (int off = 32; off > 0; off >>= 1) ds += __shfl_down(ds, off);
    __shared__ float ps[4];
    if ((threadIdx.x & 63) == 0) ps[threadIdx.x >> 6] = ds;
    __syncthreads();
    if (threadIdx.x == 0)
        pnvq[bid0 + blockIdx.x] = ps[0] + ps[1] + ps[2] + ps[3];
}

// ---------------------------------------------------------------------------
// Final loss
// ---------------------------------------------------------------------------
__global__ __launch_bounds__(256) void finalize_kernel(
    const float* __restrict__ prq, const float* __restrict__ pnvq,
    int nRqAll, int nNvq, float* __restrict__ out_loss)
{
    const int t = threadIdx.x;
    float srq = 0.f, snvq = 0.f;
    for (int i = t; i < nRqAll; i += 256) srq += prq[i];
    for (int i = t; i < nNvq; i += 256) snvq += pnvq[i];
#pragma unroll
    for (int off = 32; off > 0; off >>= 1) {
        srq += __shfl_down(srq, off);
        snvq += __shfl_down(snvq, off);
    }
    __shared__ float pr[4], pn[4];
    if ((t & 63) == 0) { pr[t >> 6] = srq; pn[t >> 6] = snvq; }
    __syncthreads();
    if (t == 0) {
        const float inv = 1.f / (16384.f * 128.f);
        float rq = (pr[0] + pr[1] + pr[2] + pr[3]);
        float nv = (pn[0] + pn[1] + pn[2] + pn[3]);
        out_loss[0] = 0.3125f * rq * inv + nv * inv;
    }
}

// ---------------------------------------------------------------------------
// Launcher — fp16 2-plane MFMA encoder + bf16 MFMA decoder, bn-fastest grids.
// ---------------------------------------------------------------------------
extern "C" void kernel_launch(void* const* d_in, const int* in_sizes, int n_in,
                              void* d_out, int out_size, void* d_ws, size_t ws_size,
                              hipStream_t stream)
{
    constexpr int B = 16384;

    const float* x = (const float*)d_in[0];
    const float* enc_w[4]; const float* enc_b[4];
    const float* dec_w[4]; const float* dec_b[4];
    for (int i = 0; i < 4; i++) {
        enc_w[i] = (const float*)d_in[1 + 4 * i];
        enc_b[i] = (const float*)d_in[2 + 4 * i];
        dec_w[i] = (const float*)d_in[3 + 4 * i];
        dec_b[i] = (const float*)d_in[4 + 4 * i];
    }
    const float* cb    = (const float*)d_in[17];
    const float* a_raw = (const float*)d_in[18];
    const float* b_raw = (const float*)d_in[19];

    // chunk size
    size_t avail = ws_size / 4;
    const size_t fixed_f = 6547008;
    int R = 16384;
    while (R > 256 && (size_t)R * 3520 + fixed_f > avail) R >>= 1;

    // carve (floats)
    float* ws    = (float*)d_ws;
    float* slotA = ws;                         // R*1024 fl
    float* slotB = slotA + (size_t)R * 1024;   // R*2048 fl
    float* zb    = slotB + (size_t)R * 2048;   // R*128
    float* zpb   = zb  + (size_t)R * 128;      // R*128
    float* xqb   = zpb + (size_t)R * 128;      // R*128
    float* zq16f = xqb + (size_t)R * 128;      // R*64 (ushort R*128)
    float* fixp  = zq16f + (size_t)R * 64;

    ushort* ew = (ushort*)fixp;
    ushort* e0h = ew;            ushort* e0m = e0h + 1572864;
    ushort* e1h = e0m + 1572864; ushort* e1m = e1h + 2097152;
    ushort* e2h = e1m + 2097152; ushort* e2m = e2h + 524288;
    ushort* e3h = e2m + 524288;  ushort* e3m = e3h + 65536;
    ushort* wt0 = e3m + 65536;
    ushort* wt1 = wt0 + 65536;
    ushort* wt2 = wt1 + 524288;
    ushort* wt3 = wt2 + 2097152;
    float* cbT   = (float*)(wt3 + 1572864);
    float* cnorm = cbT + 4 * 128 * 256;
    float* kp    = cnorm + 4 * 256;
    float* prq   = kp + 512;              // 16384
    float* pnvq  = prq + 16384;           // 8192

    ushort* zq16 = (ushort*)zq16f;

    ushort* xH  = (ushort*)slotA;  ushort* xM  = xH  + (size_t)R * 768;
    ushort* h0H = (ushort*)slotB;  ushort* h0M = h0H + (size_t)R * 2048;
    ushort* h1H = (ushort*)slotA;  ushort* h1M = h1H + (size_t)R * 1024;
    ushort* h2H = (ushort*)slotB;  ushort* h2M = h2H + (size_t)R * 512;

    ushort* dA = (ushort*)slotB;
    ushort* dB = (ushort*)(slotB + (size_t)R * 256);
    ushort* dC = (ushort*)slotA;

    float* out      = (float*)d_out;
    float* out_loss = out + (size_t)B * 768;
    float* out_idx  = out_loss + 1;

    // prep (once per launch)
    prep_cb_kernel<<<1024, 128, 0, stream>>>(cb, cbT, cnorm);
    kuma_ab_init<<<1, 128, 0, stream>>>(a_raw, b_raw, kp);
    transpose_split_f16<<<dim3( 768/32, 2048/32), 256, 0, stream>>>(enc_w[0], e0h, e0m,  768, 2048);
    transpose_split_f16<<<dim3(2048/32, 1024/32), 256, 0, stream>>>(enc_w[1], e1h, e1m, 2048, 1024);
    transpose_split_f16<<<dim3(1024/32,  512/32), 256, 0, stream>>>(enc_w[2], e2h, e2m, 1024,  512);
    transpose_split_f16<<<dim3( 512/32,  128/32), 256, 0, stream>>>(enc_w[3], e3h, e3m,  512,  128);
    transpose_to_bf16<<<dim3(128/32,  512/32), 256, 0, stream>>>(dec_w[0], wt0,  128,  512);
    transpose_to_bf16<<<dim3(512/32, 1024/32), 256, 0, stream>>>(dec_w[1], wt1,  512, 1024);
    transpose_to_bf16<<<dim3(1024/32,2048/32), 256, 0, stream>>>(dec_w[2], wt2, 1024, 2048);
    transpose_to_bf16<<<dim3(2048/32, 768/32), 256, 0, stream>>>(dec_w[3], wt3, 2048,  768);

    const int nc = B / R;
    const int nRq = B / 4;
    const int rqPerChunk = R / 4;
    const int nvqPerChunk = (R * 128) / 256;
    for (int c = 0; c < nc; c++) {
        const size_t base = (size_t)c * R;
        const float* xc = x + base * 768;
        float* outc = out + base * 768;
        float* idxc = out_idx + base * 4;

        {
            size_t n = (size_t)R * 768;
            split_plane2_kernel<<<(unsigned)((n + 255) / 256), 256, 0, stream>>>(xc, xH, xM, n);
        }

        // encoder (2-plane fp16 MFMA, fp32-grade); grid = (N-blocks, M-blocks)
        gemm_mfma_split2<true , 1><<<dim3(16, R/128), 256, 0, stream>>>(
            xH, xM, e0h, e0m, enc_b[0], h0H, h0M, R, 2048, 768);
        gemm_mfma_split2<true , 1><<<dim3( 8, R/128), 256, 0, stream>>>(
            h0H, h0M, e1h, e1m, enc_b[1], h1H, h1M, R, 1024, 2048);
        gemm_mfma_split2<true , 1><<<dim3( 4, R/128), 256, 0, stream>>>(
            h1H, h1M, e2h, e2m, enc_b[2], h2H, h2M, R,  512, 1024);
        gemm_mfma_split2<false, 0><<<dim3( 1, R/128), 256, 0, stream>>>(
            h2H, h2M, e3h, e3m, enc_b[3], zb, nullptr, R, 128, 512);

        // kuma + RQ + inverse + losses (fp32)
        kuma_h_kernel<<<(R * 128) / 256, 256, 0, stream>>>(zb, kp, zpb, R * 128);
        rq_kernel2<<<rqPerChunk, 64, 0, stream>>>(zpb, cb, cbT, cnorm, xqb, idxc,
                                                  prq, c * rqPerChunk, nRq);
        zq_nvq_kernel<<<nvqPerChunk, 256, 0, stream>>>(xqb, zpb, zb, kp, xqb, zq16,
                                                       pnvq, c * nvqPerChunk, R * 128);

        // decoder (bf16 MFMA); grid = (N-blocks, M-blocks)
        gemm_mfma_bt<true , true ><<<dim3( 4, R/128), 256, 0, stream>>>(zq16, wt0, dec_b[0], dA, R,  512,  128);
        gemm_mfma_bt<true , true ><<<dim3( 8, R/128), 256, 0, stream>>>(dA,   wt1, dec_b[1], dB, R, 1024,  512);
        gemm_mfma_bt<true , true ><<<dim3(16, R/128), 256, 0, stream>>>(dB,   wt2, dec_b[2], dC, R, 2048, 1024);
        gemm_mfma_bt<false, false><<<dim3( 6, R/128), 256, 0, stream>>>(dC,   wt3, dec_b[3], outc, R,  768, 2048);
    }

    finalize_kernel<<<1, 256, 0, stream>>>(prq, pnvq, 4 * nRq, B * 128 / 256, out_loss);
}

// Round 12
// 914.307 us; speedup vs baseline: 4.4605x; 1.0435x over previous
//
#include <hip/hip_runtime.h>
#include <math.h>

#define EPS_F 1e-6f
#define ONE_M_EPS (1.0f - 1e-6f)

typedef __attribute__((ext_vector_type(8))) short s16x8;
typedef __attribute__((ext_vector_type(8))) _Float16 f16x8;
typedef __attribute__((ext_vector_type(4))) float f32x4;

__device__ __forceinline__ ushort f2bf(float f) {
    union { float f; unsigned u; } v; v.f = f;
    unsigned u = v.u;
    return (ushort)((u + 0x7FFFu + ((u >> 16) & 1u)) >> 16);
}
__device__ __forceinline__ float bf2f(ushort h) {
    union { unsigned u; float f; } v; v.u = ((unsigned)h) << 16;
    return v.f;
}
// fp16 2-plane split: x = h + m, |x - h - m| <= 2^-22 |x|
__device__ __forceinline__ void split2h(float x, ushort& h, ushort& m) {
    union { _Float16 f; ushort u; } a, b;
    a.f = (_Float16)x;
    float r = x - (float)a.f;
    b.f = (_Float16)r;
    h = a.u; m = b.u;
}

#define GLL16(srcp, dstp)                                                     \
    __builtin_amdgcn_global_load_lds(                                         \
        (const __attribute__((address_space(1))) void*)(srcp),                \
        (__attribute__((address_space(3))) void*)(dstp), 16, 0, 0)

// Bank-conflict swizzle (16B-chunk granularity; source+read, LDS linear)
__device__ __forceinline__ int swz_k(int row, int k) { return k ^ ((row >> 1) & 3); }

// ---------------------------------------------------------------------------
// 2-plane fp16 MFMA GEMM (encoder): 3 products (hh,hm,mh), fp32 acc.
// 2-phase double-buffered pipeline: stage(t+1) issued BEFORE compute(t);
// counted vmcnt(8) keeps next-tile loads in flight across raw barriers.
// ---------------------------------------------------------------------------
template<bool RELU, int OUT2>
__global__ __launch_bounds__(256) void gemm_mfma_split2(
    const ushort* __restrict__ Ah, const ushort* __restrict__ Am,
    const ushort* __restrict__ Wh, const ushort* __restrict__ Wm,
    const float* __restrict__ bias,
    void* __restrict__ C0, void* __restrict__ C1,
    int M, int N, int K)
{
    __shared__ __align__(16) ushort As[2][2][128 * 32];   // [dbuf][plane]
    __shared__ __align__(16) ushort Bs[2][2][128 * 32];

    const int tid  = threadIdx.x;
    const int lane = tid & 63;
    const int w    = tid >> 6;
    const int wm   = (w >> 1) * 64;
    const int wn   = (w & 1) * 64;
    const int bm   = blockIdx.x * 128;
    const int bn   = blockIdx.y * 128;

    f32x4 acc[4][4];
#pragma unroll
    for (int i = 0; i < 4; i++)
#pragma unroll
        for (int j = 0; j < 4; j++) acc[i][j] = f32x4{0.f, 0.f, 0.f, 0.f};

    const int c0 = (w * 2) * 64 + lane;
    const int c1 = (w * 2 + 1) * 64 + lane;
    const int r0 = c0 >> 2, k0e = swz_k(r0, c0 & 3) * 8;
    const int r1 = c1 >> 2, k1e = swz_k(r1, c1 & 3) * 8;

    const size_t a_off0 = (size_t)(bm + r0) * K + k0e;
    const size_t a_off1 = (size_t)(bm + r1) * K + k1e;
    const size_t b_off0 = (size_t)(bn + r0) * K + k0e;
    const size_t b_off1 = (size_t)(bn + r1) * K + k1e;
    const int d0 = (w * 2) * 512;
    const int d1 = d0 + 512;

    const ushort* Ap[2] = {Ah, Am};
    const ushort* Wp[2] = {Wh, Wm};

    const int fm  = lane & 15;
    const int fkb = lane >> 4;
    const int NT  = K >> 5;

    // prologue: stage tile 0 -> buf 0
#pragma unroll
    for (int p = 0; p < 2; p++) {
        GLL16(Ap[p] + a_off0, &As[0][p][d0]);
        GLL16(Ap[p] + a_off1, &As[0][p][d1]);
        GLL16(Wp[p] + b_off0, &Bs[0][p][d0]);
        GLL16(Wp[p] + b_off1, &Bs[0][p][d1]);
    }

    int cur = 0;
    for (int kt = 0; kt < NT; kt++) {
        if (kt + 1 < NT) {
            const int kk = (kt + 1) << 5;
#pragma unroll
            for (int p = 0; p < 2; p++) {
                GLL16(Ap[p] + a_off0 + kk, &As[cur ^ 1][p][d0]);
                GLL16(Ap[p] + a_off1 + kk, &As[cur ^ 1][p][d1]);
                GLL16(Wp[p] + b_off0 + kk, &Bs[cur ^ 1][p][d0]);
                GLL16(Wp[p] + b_off1 + kk, &Bs[cur ^ 1][p][d1]);
            }
            asm volatile("s_waitcnt vmcnt(8)" ::: "memory");  // tile t complete
        } else {
            asm volatile("s_waitcnt vmcnt(0)" ::: "memory");
        }
        __builtin_amdgcn_s_barrier();
        asm volatile("" ::: "memory");

        f16x8 af[2][4];
#pragma unroll
        for (int p = 0; p < 2; p++)
#pragma unroll
            for (int i = 0; i < 4; i++) {
                const int row = wm + i * 16 + fm;
                af[p][i] = *reinterpret_cast<const f16x8*>(
                    &As[cur][p][row * 32 + swz_k(row, fkb) * 8]);
            }
        f16x8 bf0[4], bf1[4];
#pragma unroll
        for (int j = 0; j < 4; j++) {
            const int row = wn + j * 16 + fm;
            bf0[j] = *reinterpret_cast<const f16x8*>(&Bs[cur][0][row * 32 + swz_k(row, fkb) * 8]);
            bf1[j] = *reinterpret_cast<const f16x8*>(&Bs[cur][1][row * 32 + swz_k(row, fkb) * 8]);
        }

        __builtin_amdgcn_s_setprio(1);
#pragma unroll
        for (int i = 0; i < 4; i++)
#pragma unroll
            for (int j = 0; j < 4; j++) {
                acc[i][j] = __builtin_amdgcn_mfma_f32_16x16x32_f16(af[0][i], bf0[j], acc[i][j], 0, 0, 0);
                acc[i][j] = __builtin_amdgcn_mfma_f32_16x16x32_f16(af[0][i], bf1[j], acc[i][j], 0, 0, 0);
                acc[i][j] = __builtin_amdgcn_mfma_f32_16x16x32_f16(af[1][i], bf0[j], acc[i][j], 0, 0, 0);
            }
        __builtin_amdgcn_s_setprio(0);
        asm volatile("" ::: "memory");
        __builtin_amdgcn_s_barrier();   // reads of buf[cur] done before t+1 overwrites it
        cur ^= 1;
    }

#pragma unroll
    for (int j = 0; j < 4; j++) {
        const int coln = bn + wn + j * 16 + fm;
        const float bv = bias[coln];
#pragma unroll
        for (int i = 0; i < 4; i++) {
            const int row0 = bm + wm + i * 16 + (lane >> 4) * 4;
#pragma unroll
            for (int r = 0; r < 4; r++) {
                float o = acc[i][j][r] + bv;
                if (RELU) o = fmaxf(o, 0.f);
                const size_t idx = (size_t)(row0 + r) * N + coln;
                if (OUT2) {
                    ushort h, m;
                    split2h(o, h, m);
                    ((ushort*)C0)[idx] = h;
                    ((ushort*)C1)[idx] = m;
                } else {
                    ((float*)C0)[idx] = o;
                }
            }
        }
    }
}

// ---------------------------------------------------------------------------
// MFMA bf16 GEMM (decoder, single product), 2-phase pipelined, swizzled
// ---------------------------------------------------------------------------
template<bool RELU, bool OUT_BF16>
__global__ __launch_bounds__(256) void gemm_mfma_bt(
    const ushort* __restrict__ A, const ushort* __restrict__ WT,
    const float* __restrict__ bias, void* __restrict__ Cv,
    int M, int N, int K)
{
    __shared__ __align__(16) ushort As[2][128 * 32];
    __shared__ __align__(16) ushort Bs[2][128 * 32];

    const int tid  = threadIdx.x;
    const int lane = tid & 63;
    const int w    = tid >> 6;
    const int wm   = (w >> 1) * 64;
    const int wn   = (w & 1) * 64;
    const int bm   = blockIdx.x * 128;
    const int bn   = blockIdx.y * 128;

    f32x4 acc[4][4];
#pragma unroll
    for (int i = 0; i < 4; i++)
#pragma unroll
        for (int j = 0; j < 4; j++) acc[i][j] = f32x4{0.f, 0.f, 0.f, 0.f};

    const int c0 = (w * 2) * 64 + lane;
    const int c1 = (w * 2 + 1) * 64 + lane;
    const int r0 = c0 >> 2, k0e = swz_k(r0, c0 & 3) * 8;
    const int r1 = c1 >> 2, k1e = swz_k(r1, c1 & 3) * 8;

    const ushort* a_src0 = A  + (size_t)(bm + r0) * K + k0e;
    const ushort* a_src1 = A  + (size_t)(bm + r1) * K + k1e;
    const ushort* b_src0 = WT + (size_t)(bn + r0) * K + k0e;
    const ushort* b_src1 = WT + (size_t)(bn + r1) * K + k1e;
    const int d0 = (w * 2) * 512;
    const int d1 = d0 + 512;

    const int fm  = lane & 15;
    const int fkb = lane >> 4;
    const int NT  = K >> 5;

    GLL16(a_src0, &As[0][d0]);
    GLL16(a_src1, &As[0][d1]);
    GLL16(b_src0, &Bs[0][d0]);
    GLL16(b_src1, &Bs[0][d1]);

    int cur = 0;
    for (int kt = 0; kt < NT; kt++) {
        if (kt + 1 < NT) {
            const int kk = (kt + 1) << 5;
            GLL16(a_src0 + kk, &As[cur ^ 1][d0]);
            GLL16(a_src1 + kk, &As[cur ^ 1][d1]);
            GLL16(b_src0 + kk, &Bs[cur ^ 1][d0]);
            GLL16(b_src1 + kk, &Bs[cur ^ 1][d1]);
            asm volatile("s_waitcnt vmcnt(4)" ::: "memory");
        } else {
            asm volatile("s_waitcnt vmcnt(0)" ::: "memory");
        }
        __builtin_amdgcn_s_barrier();
        asm volatile("" ::: "memory");

        s16x8 af[4], bfr[4];
#pragma unroll
        for (int i = 0; i < 4; i++) {
            const int row = wm + i * 16 + fm;
            af[i] = *reinterpret_cast<const s16x8*>(&As[cur][row * 32 + swz_k(row, fkb) * 8]);
        }
#pragma unroll
        for (int j = 0; j < 4; j++) {
            const int row = wn + j * 16 + fm;
            bfr[j] = *reinterpret_cast<const s16x8*>(&Bs[cur][row * 32 + swz_k(row, fkb) * 8]);
        }

        __builtin_amdgcn_s_setprio(1);
#pragma unroll
        for (int i = 0; i < 4; i++)
#pragma unroll
            for (int j = 0; j < 4; j++)
                acc[i][j] = __builtin_amdgcn_mfma_f32_16x16x32_bf16(
                    af[i], bfr[j], acc[i][j], 0, 0, 0);
        __builtin_amdgcn_s_setprio(0);
        asm volatile("" ::: "memory");
        __builtin_amdgcn_s_barrier();
        cur ^= 1;
    }

#pragma unroll
    for (int j = 0; j < 4; j++) {
        const int coln = bn + wn + j * 16 + fm;
        const float bv = bias[coln];
#pragma unroll
        for (int i = 0; i < 4; i++) {
            const int row0 = bm + wm + i * 16 + (lane >> 4) * 4;
#pragma unroll
            for (int r = 0; r < 4; r++) {
                float o = acc[i][j][r] + bv;
                if (RELU) o = fmaxf(o, 0.f);
                if (OUT_BF16)
                    ((ushort*)Cv)[(size_t)(row0 + r) * N + coln] = f2bf(o);
                else
                    ((float*)Cv)[(size_t)(row0 + r) * N + coln] = o;
            }
        }
    }
}

// ---------------------------------------------------------------------------
// Weight prep kernels
// ---------------------------------------------------------------------------
__global__ __launch_bounds__(256) void transpose_to_bf16(
    const float* __restrict__ W, ushort* __restrict__ WT, int K, int N)
{
    __shared__ float t[32][33];
    const int kb = blockIdx.x * 32, nb = blockIdx.y * 32;
    const int tx = threadIdx.x & 31, ty = threadIdx.x >> 5;
#pragma unroll
    for (int i = ty; i < 32; i += 8)
        t[i][tx] = W[(size_t)(kb + i) * N + nb + tx];
    __syncthreads();
#pragma unroll
    for (int i = ty; i < 32; i += 8)
        WT[(size_t)(nb + i) * K + kb + tx] = f2bf(t[tx][i]);
}

__global__ __launch_bounds__(256) void transpose_split_f16(
    const float* __restrict__ W, ushort* __restrict__ TH,
    ushort* __restrict__ TM, int K, int N)
{
    __shared__ float t[32][33];
    const int kb = blockIdx.x * 32, nb = blockIdx.y * 32;
    const int tx = threadIdx.x & 31, ty = threadIdx.x >> 5;
#pragma unroll
    for (int i = ty; i < 32; i += 8)
        t[i][tx] = W[(size_t)(kb + i) * N + nb + tx];
    __syncthreads();
#pragma unroll
    for (int i = ty; i < 32; i += 8) {
        ushort h, m;
        split2h(t[tx][i], h, m);
        const size_t idx = (size_t)(nb + i) * K + kb + tx;
        TH[idx] = h; TM[idx] = m;
    }
}

__global__ __launch_bounds__(256) void split_plane2_kernel(
    const float* __restrict__ X, ushort* __restrict__ H,
    ushort* __restrict__ M, size_t n)
{
    size_t i = (size_t)blockIdx.x * 256 + threadIdx.x;
    if (i >= n) return;
    ushort h, m;
    split2h(X[i], h, m);
    H[i] = h; M[i] = m;
}

// ---------------------------------------------------------------------------
// Codebook prep
// ---------------------------------------------------------------------------
__global__ __launch_bounds__(128) void prep_cb_kernel(
    const float* __restrict__ cb, float* __restrict__ cbT, float* __restrict__ cnorm)
{
    int b = blockIdx.x;
    int d = threadIdx.x;
    float v = cb[(size_t)b * 128 + d];
    int l = b >> 8, c = b & 255;
    cbT[((size_t)l * 128 + d) * 256 + c] = v;
    float s = v * v;
#pragma unroll
    for (int off = 32; off > 0; off >>= 1) s += __shfl_down(s, off);
    __shared__ float ps[2];
    if ((d & 63) == 0) ps[d >> 6] = s;
    __syncthreads();
    if (d == 0) cnorm[b] = ps[0] + ps[1];
}

__device__ __forceinline__ float softplusf(float x) {
    return (x > 20.f) ? x : log1pf(expf(x));
}

__global__ void kuma_ab_init(const float* __restrict__ a_raw, const float* __restrict__ b_raw,
                             float* __restrict__ kp)
{
    int t = threadIdx.x;
    if (t < 128) {
        float a = softplusf(a_raw[t]) + EPS_F;
        float b = softplusf(b_raw[t]) + EPS_F;
        kp[t] = a;
        kp[128 + t] = b;
        kp[256 + t] = 1.f / a;
        kp[384 + t] = 1.f / b;
    }
}

__global__ __launch_bounds__(256) void kuma_h_kernel(
    const float* __restrict__ z, const float* __restrict__ kp,
    float* __restrict__ zp, int n)
{
    int i = blockIdx.x * 256 + threadIdx.x;
    if (i >= n) return;
    int col = i & 127;
    float a = kp[col], b = kp[128 + col];
    float zv = z[i];
    float x = 1.f / (1.f + expf(-zv));
    x = fminf(fmaxf(x, EPS_F), ONE_M_EPS);
    float inner = 1.f - powf(x, a);
    inner = fminf(fmaxf(inner, EPS_F), 1.f);
    float y = 1.f - powf(inner, b);
    y = fminf(fmaxf(y, EPS_F), ONE_M_EPS);
    zp[i] = y;
}

// ---------------------------------------------------------------------------
// Residual quantizer v2 — 1 wave/block, 4 rows, 4 codes/thread.
// ---------------------------------------------------------------------------
__global__ __launch_bounds__(64) void rq_kernel2(
    const float* __restrict__ zp, const float* __restrict__ cb,
    const float* __restrict__ cbT, const float* __restrict__ cnorm,
    float* __restrict__ xq, float* __restrict__ idx_out,
    float* __restrict__ prq, int bid0, int nRq)
{
    __shared__ float res[4][128];

    const int t = threadIdx.x;
    const int row0 = blockIdx.x * 4;

#pragma unroll
    for (int j = 0; j < 8; j++) {
        int e = t + j * 64;
        res[e >> 7][e & 127] = zp[(size_t)row0 * 128 + e];
    }

    float lsum[4];

#pragma unroll 1
    for (int l = 0; l < 4; l++) {
        const float* cT = cbT + (size_t)l * 32768;

        float acc[4][4];
#pragma unroll
        for (int r = 0; r < 4; r++)
#pragma unroll
            for (int cc = 0; cc < 4; cc++) acc[r][cc] = 0.f;

        float pc[16];
#pragma unroll
        for (int dd = 0; dd < 4; dd++)
#pragma unroll
            for (int cc = 0; cc < 4; cc++)
                pc[dd * 4 + cc] = cT[dd * 256 + cc * 64 + t];

#pragma unroll 2
        for (int d = 0; d < 128; d += 4) {
            float nc[16];
            if (d < 124) {
#pragma unroll
                for (int dd = 0; dd < 4; dd++)
#pragma unroll
                    for (int cc = 0; cc < 4; cc++)
                        nc[dd * 4 + cc] = cT[(d + 4 + dd) * 256 + cc * 64 + t];
            }
#pragma unroll
            for (int r = 0; r < 4; r++) {
                float4 rv = *reinterpret_cast<const float4*>(&res[r][d]);
#pragma unroll
                for (int cc = 0; cc < 4; cc++) {
                    acc[r][cc] += rv.x * pc[cc] + rv.y * pc[4 + cc]
                                + rv.z * pc[8 + cc] + rv.w * pc[12 + cc];
                }
            }
#pragma unroll
            for (int k = 0; k < 16; k++) pc[k] = nc[k];
        }

        float cn[4];
#pragma unroll
        for (int cc = 0; cc < 4; cc++) cn[cc] = cnorm[l * 256 + cc * 64 + t];

        int bidx0, bidx1, bidx2, bidx3;
#pragma unroll
        for (int r = 0; r < 4; r++) {
            float dmin = cn[0] - 2.f * acc[r][0];
            int imin = t;
#pragma unroll
            for (int cc = 1; cc < 4; cc++) {
                float dv = cn[cc] - 2.f * acc[r][cc];
                if (dv < dmin) { dmin = dv; imin = cc * 64 + t; }
            }
#pragma unroll
            for (int off = 1; off < 64; off <<= 1) {
                float d2 = __shfl_xor(dmin, off);
                int i2 = __shfl_xor(imin, off);
                if (d2 < dmin || (d2 == dmin && i2 < imin)) { dmin = d2; imin = i2; }
            }
            if (r == 0) bidx0 = imin;
            else if (r == 1) bidx1 = imin;
            else if (r == 2) bidx2 = imin;
            else bidx3 = imin;
            if (t == 0) idx_out[(size_t)(row0 + r) * 4 + l] = (float)imin;
        }

        float s = 0.f;
#pragma unroll
        for (int j = 0; j < 8; j++) {
            const int r = j >> 1;
            const int d = (j & 1) * 64 + t;
            const int bi = (r == 0) ? bidx0 : (r == 1) ? bidx1 : (r == 2) ? bidx2 : bidx3;
            float q = cb[((size_t)(l * 256) + bi) * 128 + d];
            float nr = res[r][d] - q;
            res[r][d] = nr;
            s += nr * nr;
        }
        lsum[l] = s;
    }

#pragma unroll
    for (int j = 0; j < 8; j++) {
        int e = t + j * 64;
        xq[(size_t)row0 * 128 + e] = zp[(size_t)row0 * 128 + e] - res[e >> 7][e & 127];
    }

#pragma unroll
    for (int l = 0; l < 4; l++) {
        float s = lsum[l];
#pragma unroll
        for (int off = 32; off > 0; off >>= 1) s += __shfl_down(s, off);
        if (t == 0) prq[(size_t)l * nRq + bid0 + blockIdx.x] = s;
    }
}

// ---------------------------------------------------------------------------
// z_q = h_inv(x_q) (+ bf16 copy);  z_recon = h_inv(z');  nvq partial store
// ---------------------------------------------------------------------------
__device__ __forceinline__ float kuma_h_inv_f(float y, float ia, float ib) {
    y = fminf(fmaxf(y, EPS_F), ONE_M_EPS);
    float omy = fminf(fmaxf(1.f - y, EPS_F), 1.f);
    float inner = fminf(fmaxf(1.f - powf(omy, ib), EPS_F), ONE_M_EPS);
    float x = fminf(fmaxf(powf(inner, ia), EPS_F), ONE_M_EPS);
    return logf(x / (1.f - x));
}

__global__ __launch_bounds__(256) void zq_nvq_kernel(
    const float* __restrict__ xq, const float* __restrict__ zp,
    const float* __restrict__ z, const float* __restrict__ kp,
    float* __restrict__ zq, ushort* __restrict__ zq16,
    float* __restrict__ pnvq, int bid0, int n)
{
    int i = blockIdx.x * 256 + threadIdx.x;
    float ds = 0.f;
    if (i < n) {
        int col = i & 127;
        float ia = kp[256 + col], ib = kp[384 + col];
        float xv = xq[i];
        float zpv = zp[i];
        float zv = z[i];
        float zr = kuma_h_inv_f(zpv, ia, ib);
        float d = zr - zv;
        ds = d * d;
        float zqv = kuma_h_inv_f(xv, ia, ib);
        zq[i] = zqv;
        zq16[i] = f2bf(zqv);
    }
#pragma unroll
    for (int off = 32; off > 0; off >>= 1) ds += __shfl_down(ds, off);
    __shared__ float ps[4];
    if ((threadIdx.x & 63) == 0) ps[threadIdx.x >> 6] = ds;
    __syncthreads();
    if (threadIdx.x == 0)
        pnvq[bid0 + blockIdx.x] = ps[0] + ps[1] + ps[2] + ps[3];
}

// ---------------------------------------------------------------------------
// Final loss
// ---------------------------------------------------------------------------
__global__ __launch_bounds__(256) void finalize_kernel(
    const float* __restrict__ prq, const float* __restrict__ pnvq,
    int nRqAll, int nNvq, float* __restrict__ out_loss)
{
    const int t = threadIdx.x;
    float srq = 0.f, snvq = 0.f;
    for (int i = t; i < nRqAll; i += 256) srq += prq[i];
    for (int i = t; i < nNvq; i += 256) snvq += pnvq[i];
#pragma unroll
    for (int off = 32; off > 0; off >>= 1) {
        srq += __shfl_down(srq, off);
        snvq += __shfl_down(snvq, off);
    }
    __shared__ float pr[4], pn[4];
    if ((t & 63) == 0) { pr[t >> 6] = srq; pn[t >> 6] = snvq; }
    __syncthreads();
    if (t == 0) {
        const float inv = 1.f / (16384.f * 128.f);
        float rq = (pr[0] + pr[1] + pr[2] + pr[3]);
        float nv = (pn[0] + pn[1] + pn[2] + pn[3]);
        out_loss[0] = 0.3125f * rq * inv + nv * inv;
    }
}

// ---------------------------------------------------------------------------
// Launcher — fp16 2-plane pipelined MFMA encoder + bf16 pipelined decoder.
// ---------------------------------------------------------------------------
extern "C" void kernel_launch(void* const* d_in, const int* in_sizes, int n_in,
                              void* d_out, int out_size, void* d_ws, size_t ws_size,
                              hipStream_t stream)
{
    constexpr int B = 16384;

    const float* x = (const float*)d_in[0];
    const float* enc_w[4]; const float* enc_b[4];
    const float* dec_w[4]; const float* dec_b[4];
    for (int i = 0; i < 4; i++) {
        enc_w[i] = (const float*)d_in[1 + 4 * i];
        enc_b[i] = (const float*)d_in[2 + 4 * i];
        dec_w[i] = (const float*)d_in[3 + 4 * i];
        dec_b[i] = (const float*)d_in[4 + 4 * i];
    }
    const float* cb    = (const float*)d_in[17];
    const float* a_raw = (const float*)d_in[18];
    const float* b_raw = (const float*)d_in[19];

    // chunk size
    size_t avail = ws_size / 4;
    const size_t fixed_f = 6547008;
    int R = 16384;
    while (R > 256 && (size_t)R * 3520 + fixed_f > avail) R >>= 1;

    // carve (floats)
    float* ws    = (float*)d_ws;
    float* slotA = ws;                         // R*1024 fl
    float* slotB = slotA + (size_t)R * 1024;   // R*2048 fl
    float* zb    = slotB + (size_t)R * 2048;   // R*128
    float* zpb   = zb  + (size_t)R * 128;      // R*128
    float* xqb   = zpb + (size_t)R * 128;      // R*128
    float* zq16f = xqb + (size_t)R * 128;      // R*64 (ushort R*128)
    float* fixp  = zq16f + (size_t)R * 64;

    ushort* ew = (ushort*)fixp;
    ushort* e0h = ew;            ushort* e0m = e0h + 1572864;
    ushort* e1h = e0m + 1572864; ushort* e1m = e1h + 2097152;
    ushort* e2h = e1m + 2097152; ushort* e2m = e2h + 524288;
    ushort* e3h = e2m + 524288;  ushort* e3m = e3h + 65536;
    ushort* wt0 = e3m + 65536;
    ushort* wt1 = wt0 + 65536;
    ushort* wt2 = wt1 + 524288;
    ushort* wt3 = wt2 + 2097152;
    float* cbT   = (float*)(wt3 + 1572864);
    float* cnorm = cbT + 4 * 128 * 256;
    float* kp    = cnorm + 4 * 256;
    float* prq   = kp + 512;              // 16384
    float* pnvq  = prq + 16384;           // 8192

    ushort* zq16 = (ushort*)zq16f;

    ushort* xH  = (ushort*)slotA;  ushort* xM  = xH  + (size_t)R * 768;
    ushort* h0H = (ushort*)slotB;  ushort* h0M = h0H + (size_t)R * 2048;
    ushort* h1H = (ushort*)slotA;  ushort* h1M = h1H + (size_t)R * 1024;
    ushort* h2H = (ushort*)slotB;  ushort* h2M = h2H + (size_t)R * 512;

    ushort* dA = (ushort*)slotB;
    ushort* dB = (ushort*)(slotB + (size_t)R * 256);
    ushort* dC = (ushort*)slotA;

    float* out      = (float*)d_out;
    float* out_loss = out + (size_t)B * 768;
    float* out_idx  = out_loss + 1;

    // prep (once per launch)
    prep_cb_kernel<<<1024, 128, 0, stream>>>(cb, cbT, cnorm);
    kuma_ab_init<<<1, 128, 0, stream>>>(a_raw, b_raw, kp);
    transpose_split_f16<<<dim3( 768/32, 2048/32), 256, 0, stream>>>(enc_w[0], e0h, e0m,  768, 2048);
    transpose_split_f16<<<dim3(2048/32, 1024/32), 256, 0, stream>>>(enc_w[1], e1h, e1m, 2048, 1024);
    transpose_split_f16<<<dim3(1024/32,  512/32), 256, 0, stream>>>(enc_w[2], e2h, e2m, 1024,  512);
    transpose_split_f16<<<dim3( 512/32,  128/32), 256, 0, stream>>>(enc_w[3], e3h, e3m,  512,  128);
    transpose_to_bf16<<<dim3(128/32,  512/32), 256, 0, stream>>>(dec_w[0], wt0,  128,  512);
    transpose_to_bf16<<<dim3(512/32, 1024/32), 256, 0, stream>>>(dec_w[1], wt1,  512, 1024);
    transpose_to_bf16<<<dim3(1024/32,2048/32), 256, 0, stream>>>(dec_w[2], wt2, 1024, 2048);
    transpose_to_bf16<<<dim3(2048/32, 768/32), 256, 0, stream>>>(dec_w[3], wt3, 2048,  768);

    const int nc = B / R;
    const int nRq = B / 4;
    const int rqPerChunk = R / 4;
    const int nvqPerChunk = (R * 128) / 256;
    for (int c = 0; c < nc; c++) {
        const size_t base = (size_t)c * R;
        const float* xc = x + base * 768;
        float* outc = out + base * 768;
        float* idxc = out_idx + base * 4;

        {
            size_t n = (size_t)R * 768;
            split_plane2_kernel<<<(unsigned)((n + 255) / 256), 256, 0, stream>>>(xc, xH, xM, n);
        }

        // encoder (2-plane fp16 MFMA, fp32-grade), bm-fastest grid
        gemm_mfma_split2<true , 1><<<dim3(R/128, 16), 256, 0, stream>>>(
            xH, xM, e0h, e0m, enc_b[0], h0H, h0M, R, 2048, 768);
        gemm_mfma_split2<true , 1><<<dim3(R/128,  8), 256, 0, stream>>>(
            h0H, h0M, e1h, e1m, enc_b[1], h1H, h1M, R, 1024, 2048);
        gemm_mfma_split2<true , 1><<<dim3(R/128,  4), 256, 0, stream>>>(
            h1H, h1M, e2h, e2m, enc_b[2], h2H, h2M, R,  512, 1024);
        gemm_mfma_split2<false, 0><<<dim3(R/128,  1), 256, 0, stream>>>(
            h2H, h2M, e3h, e3m, enc_b[3], zb, nullptr, R, 128, 512);

        // kuma + RQ + inverse + losses (fp32)
        kuma_h_kernel<<<(R * 128) / 256, 256, 0, stream>>>(zb, kp, zpb, R * 128);
        rq_kernel2<<<rqPerChunk, 64, 0, stream>>>(zpb, cb, cbT, cnorm, xqb, idxc,
                                                  prq, c * rqPerChunk, nRq);
        zq_nvq_kernel<<<nvqPerChunk, 256, 0, stream>>>(xqb, zpb, zb, kp, xqb, zq16,
                                                       pnvq, c * nvqPerChunk, R * 128);

        // decoder (bf16 MFMA), bm-fastest grid
        gemm_mfma_bt<true , true ><<<dim3(R/128,  4), 256, 0, stream>>>(zq16, wt0, dec_b[0], dA, R,  512,  128);
        gemm_mfma_bt<true , true ><<<dim3(R/128,  8), 256, 0, stream>>>(dA,   wt1, dec_b[1], dB, R, 1024,  512);
        gemm_mfma_bt<true , true ><<<dim3(R/128, 16), 256, 0, stream>>>(dB,   wt2, dec_b[2], dC, R, 2048, 1024);
        gemm_mfma_bt<false, false><<<dim3(R/128,  6), 256, 0, stream>>>(dC,   wt3, dec_b[3], outc, R,  768, 2048);
    }

    finalize_kernel<<<1, 256, 0, stream>>>(prq, pnvq, 4 * nRq, B * 128 / 256, out_loss);
}